// Round 1
// baseline (3073.176 us; speedup 1.0000x reference)
//
#include <hip/hip_runtime.h>

#define NN 50000
#define EE 40000
#define PP 4096
#define MAXR 12
#define CAPR 8448
#define GBM 64
#define GBN 64
#define GBK 16

__device__ __forceinline__ unsigned fkey(float f) {
    unsigned u = __float_as_uint(f);
    return (u & 0x80000000u) ? ~u : (u | 0x80000000u);
}
__device__ __forceinline__ float funkey(unsigned k) {
    unsigned u = (k & 0x80000000u) ? (k & 0x7fffffffu) : ~k;
    return __uint_as_float(u);
}

// rank[e] += #{ j in this y-partition : key_j < key_e }, key = (time, idx) — stable argsort
__global__ __launch_bounds__(256) void k_rank(const float* __restrict__ t, int* __restrict__ rank)
{
    const int tid = threadIdx.x;
    const int e = blockIdx.x * 256 + tid;
    const bool valid = (e < EE);
    const float myt = valid ? t[e] : 0.f;
    const int part = EE / 8;
    const int j0 = blockIdx.y * part, j1 = j0 + part;
    __shared__ float st[256];
    int cnt = 0;
    for (int tb = j0; tb < j1; tb += 256) {
        int j = tb + tid;
        st[tid] = (j < j1) ? t[j] : 0.f;
        __syncthreads();
        int tsz = j1 - tb; if (tsz > 256) tsz = 256;
        for (int jj = 0; jj < tsz; ++jj) {
            float tj = st[jj];
            cnt += (tj < myt || (tj == myt && (tb + jj) < e)) ? 1 : 0;
        }
        __syncthreads();
    }
    if (valid && cnt) atomicAdd(&rank[e], cnt);
}

__global__ void k_order(const int* __restrict__ rank, int* __restrict__ order)
{
    int e = blockIdx.x * 256 + threadIdx.x;
    if (e < EE) order[rank[e]] = e;
}

// relevant[e] = 1 iff e is the LAST edge of its (src, batch) group (batch = rank/200)
__global__ void k_relevant(const int* __restrict__ rank, const int* __restrict__ order,
                           const int* __restrict__ src, int* __restrict__ rel)
{
    int e = blockIdx.x * 256 + threadIdx.x;
    if (e >= EE) return;
    int r = rank[e];
    int end = (r / 200 + 1) * 200;
    int s = src[e];
    int v = 1;
    for (int rr = r + 1; rr < end; ++rr) {
        if (src[order[rr]] == s) { v = 0; break; }
    }
    rel[e] = v;
}

// cpos[e] += #{ relevant e' in partition : src'==src && rank' < rank }
__global__ __launch_bounds__(256) void k_chainpos(const int* __restrict__ src, const int* __restrict__ rank,
                                                  const int* __restrict__ rel, int* __restrict__ cpos)
{
    const int tid = threadIdx.x;
    const int e = blockIdx.x * 256 + tid;
    const bool valid = (e < EE);
    const int msrc = valid ? src[e] : -1;
    const int mr2 = valid ? (rank[e] << 1) : 0;
    const int part = EE / 8;
    const int j0 = blockIdx.y * part, j1 = j0 + part;
    __shared__ int ssrc[256];
    __shared__ int spr[256];
    int cnt = 0;
    for (int tb = j0; tb < j1; tb += 256) {
        int j = tb + tid;
        if (j < j1) { ssrc[tid] = src[j]; spr[tid] = (rank[j] << 1) | rel[j]; }
        __syncthreads();
        int tsz = j1 - tb; if (tsz > 256) tsz = 256;
        for (int jj = 0; jj < tsz; ++jj) {
            int pr = spr[jj];
            cnt += (ssrc[jj] == msrc && (pr & 1) && pr < mr2) ? 1 : 0;
        }
        __syncthreads();
    }
    if (valid && cnt) atomicAdd(&cpos[e], cnt);
}

__global__ void k_insert(const int* __restrict__ rel, const int* __restrict__ cpos,
                         int* __restrict__ roundcnt, int* __restrict__ roundlist)
{
    int e = blockIdx.x * 256 + threadIdx.x;
    if (e >= EE || !rel[e]) return;
    int pos = cpos[e];
    if (pos >= MAXR) return;
    int slot = atomicAdd(&roundcnt[pos], 1);
    roundlist[(size_t)pos * EE + slot] = e;
}

__global__ void k_te(const float* __restrict__ t, const float* __restrict__ w,
                     const float* __restrict__ b, float* __restrict__ te)
{
    int idx = blockIdx.x * 256 + threadIdx.x;
    if (idx >= EE * 128) return;
    int e = idx >> 7, j = idx & 127;
    te[idx] = sinf(t[e] * w[j] + b[j]);
}

// C[M,N] = ACT( A(gathered)@W + bias + (ACCUM? C : 0) ), f32, 64x64x16 tiles, 4x4 micro
template <int ACT, int ACCUM>
__global__ __launch_bounds__(256) void k_gemm(
    const float* __restrict__ A, int lda, const int* __restrict__ aidx,
    const float* __restrict__ W, int ldw,
    const float* __restrict__ bias,
    float* __restrict__ C, int ldc,
    int Mhost, const int* __restrict__ mdev, int mbase, int K)
{
    int M = Mhost;
    if (mdev) {
        int avail = *mdev - mbase;
        if (avail < 0) avail = 0;
        if (avail < M) M = avail;
    }
    const int row0 = blockIdx.x * GBM;
    if (row0 >= M) return;
    const int col0 = blockIdx.y * GBN;

    __shared__ float As[GBK][GBM + 4];
    __shared__ float Bs[GBK][GBN + 4];

    const int tid = threadIdx.x;
    const int tx = tid & 15;
    const int ty = tid >> 4;
    const int ar = tid >> 2;
    const int akq = (tid & 3) * 4;

    float acc[4][4] = {};

    for (int k0 = 0; k0 < K; k0 += GBK) {
        float4 av = make_float4(0.f, 0.f, 0.f, 0.f);
        int grow = row0 + ar;
        if (grow < M) {
            int arow = aidx ? aidx[grow] : grow;
            av = *reinterpret_cast<const float4*>(A + (size_t)arow * lda + k0 + akq);
        }
        As[akq + 0][ar] = av.x;
        As[akq + 1][ar] = av.y;
        As[akq + 2][ar] = av.z;
        As[akq + 3][ar] = av.w;
        *reinterpret_cast<float4*>(&Bs[ty][tx * 4]) =
            *reinterpret_cast<const float4*>(W + (size_t)(k0 + ty) * ldw + col0 + tx * 4);
        __syncthreads();
#pragma unroll
        for (int k = 0; k < GBK; ++k) {
            float4 a4 = *reinterpret_cast<const float4*>(&As[k][ty * 4]);
            float4 b4 = *reinterpret_cast<const float4*>(&Bs[k][tx * 4]);
            float af[4] = {a4.x, a4.y, a4.z, a4.w};
            float bf[4] = {b4.x, b4.y, b4.z, b4.w};
#pragma unroll
            for (int i = 0; i < 4; ++i)
#pragma unroll
                for (int jj = 0; jj < 4; ++jj) acc[i][jj] = fmaf(af[i], bf[jj], acc[i][jj]);
        }
        __syncthreads();
    }

#pragma unroll
    for (int i = 0; i < 4; ++i) {
        int r = row0 + ty * 4 + i;
        if (r >= M) continue;
        float* cp = C + (size_t)r * ldc + col0 + tx * 4;
#pragma unroll
        for (int jj = 0; jj < 4; ++jj) {
            float v = acc[i][jj];
            if (bias) v += bias[col0 + tx * 4 + jj];
            if (ACCUM) v += cp[jj];
            if (ACT == 1) v = fmaxf(v, 0.f);
            cp[jj] = v;
        }
    }
}

__global__ void k_gather(const int* __restrict__ rlist, const int* __restrict__ cnt, int base, int m,
                         const int* __restrict__ src, const float* __restrict__ xpart,
                         float* __restrict__ xbuf, int* __restrict__ srcrow)
{
    int i = blockIdx.x;
    int avail = *cnt - base;
    if (i >= m || i >= avail) return;
    int e = rlist[base + i];
    int c = threadIdx.x;
    xbuf[(size_t)i * 256 + c] = xpart[(size_t)e * 256 + c];
    if (c == 0) srcrow[i] = src[e];
}

__global__ void k_gru(const int* __restrict__ cnt, int base, int m, const int* __restrict__ srcrow,
                      const float* __restrict__ gi, const float* __restrict__ gh, float* __restrict__ mem)
{
    int i = blockIdx.x;
    int avail = *cnt - base;
    if (i >= m || i >= avail) return;
    int c = threadIdx.x;
    int s = srcrow[i];
    float hp = mem[(size_t)s * 256 + c];
    float ir = gi[(size_t)i * 768 + c];
    float iz = gi[(size_t)i * 768 + 256 + c];
    float in_ = gi[(size_t)i * 768 + 512 + c];
    float hr = gh[(size_t)i * 768 + c];
    float hz = gh[(size_t)i * 768 + 256 + c];
    float hn = gh[(size_t)i * 768 + 512 + c];
    float r = 1.f / (1.f + expf(-(ir + hr)));
    float z = 1.f / (1.f + expf(-(iz + hz)));
    float n = tanhf(in_ + r * hn);
    mem[(size_t)s * 256 + c] = (1.f - z) * n + z * hp;
}

__global__ void k_gvec(const float* __restrict__ t, const int* __restrict__ order,
                       const float* __restrict__ w, const float* __restrict__ b,
                       const float* __restrict__ Wg, float* __restrict__ gvec)
{
    float tmax = t[order[EE - 1]];
    int c = threadIdx.x;
    float acc = 0.f;
    for (int k = 0; k < 128; ++k) acc += sinf(tmax * w[k] + b[k]) * Wg[(size_t)(512 + k) * 256 + c];
    gvec[c] = acc;
}

__global__ __launch_bounds__(256) void k_dots2(const float* __restrict__ X, int ld, int M,
                                               const float* __restrict__ v1, const float* __restrict__ v2,
                                               float* __restrict__ o1, float* __restrict__ o2)
{
    int lane = threadIdx.x & 63;
    int row = blockIdx.x * 4 + (threadIdx.x >> 6);
    if (row >= M) return;
    const float* xr = X + (size_t)row * ld;
    float s1 = 0.f, s2 = 0.f;
    for (int c = lane; c < ld; c += 64) {
        float x = xr[c];
        s1 += x * v1[c];
        if (v2) s2 += x * v2[c];
    }
#pragma unroll
    for (int off = 32; off > 0; off >>= 1) {
        s1 += __shfl_xor(s1, off);
        if (v2) s2 += __shfl_xor(s2, off);
    }
    if (lane == 0) {
        o1[row] = s1;
        if (v2) o2[row] = s2;
    }
}

__global__ void k_logitmax(const float* __restrict__ sdot, const float* __restrict__ ddot,
                           const float* __restrict__ edot, const int* __restrict__ src,
                           const int* __restrict__ dst, float* __restrict__ logit,
                           unsigned* __restrict__ mx)
{
    int e = blockIdx.x * 256 + threadIdx.x;
    if (e >= EE) return;
    float l = sdot[src[e]] + ddot[dst[e]] + edot[e];
    l = (l > 0.f) ? l : 0.2f * l;
    logit[e] = l;
    atomicMax(&mx[dst[e]], fkey(l));
}

__global__ void k_alpha(const float* __restrict__ logit, const int* __restrict__ dst,
                        const unsigned* __restrict__ mx, float* __restrict__ alpha,
                        float* __restrict__ denom)
{
    int e = blockIdx.x * 256 + threadIdx.x;
    if (e >= EE) return;
    int d = dst[e];
    float a = expf(logit[e] - funkey(mx[d]));
    alpha[e] = a;
    atomicAdd(&denom[d], a);
}

__global__ void k_scatter(const float* __restrict__ alpha, const int* __restrict__ src,
                          const int* __restrict__ dst, const float* __restrict__ h,
                          const float* __restrict__ ef, float* __restrict__ outb)
{
    int e = blockIdx.x;
    int c = threadIdx.x;
    float a = alpha[e];
    int s = src[e], d = dst[e];
    atomicAdd(&outb[(size_t)d * 256 + c], a * (h[(size_t)s * 256 + c] + ef[(size_t)e * 256 + c]));
}

__global__ void k_pe(const int* __restrict__ pm, const float* __restrict__ outb,
                     const float* __restrict__ denom, float* __restrict__ pe)
{
    int p = blockIdx.x, c = threadIdx.x;
    int n = pm[p];
    pe[(size_t)p * 256 + c] = outb[(size_t)n * 256 + c] / (denom[n] + 1e-16f);
}

__global__ __launch_bounds__(256) void k_final(const float* __restrict__ c1, const float* __restrict__ Wc2,
                                               const float* __restrict__ bc2, float* __restrict__ out)
{
    int lane = threadIdx.x & 63;
    int row = blockIdx.x * 4 + (threadIdx.x >> 6);
    if (row >= PP) return;
    float s = 0.f;
    for (int c = lane; c < 128; c += 64) s += c1[(size_t)row * 128 + c] * Wc2[c];
#pragma unroll
    for (int off = 32; off > 0; off >>= 1) s += __shfl_xor(s, off);
    if (lane == 0) out[row] = 1.f / (1.f + expf(-(s + bc2[0])));
}

extern "C" void kernel_launch(void* const* d_in, const int* in_sizes, int n_in,
                              void* d_out, int out_size, void* d_ws, size_t ws_size,
                              hipStream_t stream)
{
    (void)in_sizes; (void)n_in; (void)out_size;
    const float* nf    = (const float*)d_in[0];
    const int*   ei    = (const int*)  d_in[1];
    const float* ea    = (const float*)d_in[2];
    const float* t     = (const float*)d_in[3];
    const int*   pm    = (const int*)  d_in[4];
    const float* wt    = (const float*)d_in[5];
    const float* bt    = (const float*)d_in[6];
    const float* Wm1   = (const float*)d_in[7];
    const float* bm1   = (const float*)d_in[8];
    const float* Wm2   = (const float*)d_in[9];
    const float* bm2   = (const float*)d_in[10];
    const float* Wi    = (const float*)d_in[11];
    const float* Wh    = (const float*)d_in[12];
    const float* bi    = (const float*)d_in[13];
    const float* bh    = (const float*)d_in[14];
    const float* Wg    = (const float*)d_in[15];
    const float* We    = (const float*)d_in[16];
    const float* a_src = (const float*)d_in[17];
    const float* a_dst = (const float*)d_in[18];
    const float* a_e   = (const float*)d_in[19];
    const float* Wc1   = (const float*)d_in[20];
    const float* bc1   = (const float*)d_in[21];
    const float* Wc2   = (const float*)d_in[22];
    const float* bc2   = (const float*)d_in[23];
    float* outp = (float*)d_out;
    const int* src = ei;
    const int* dst = ei + EE;

    char* base = (char*)d_ws;
    size_t off = 0;
    auto alloc = [&](size_t bytes) -> void* {
        void* p = base + off;
        off = (off + bytes + 255) & ~(size_t)255;
        return p;
    };
    int* rank      = (int*)alloc((size_t)EE * 4);
    int* order     = (int*)alloc((size_t)EE * 4);
    int* rel       = (int*)alloc((size_t)EE * 4);
    int* cpos      = (int*)alloc((size_t)EE * 4);
    int* roundcnt  = (int*)alloc(64 * 4);
    int* roundlist = (int*)alloc((size_t)MAXR * EE * 4);
    int* srcrow    = (int*)alloc((size_t)CAPR * 4);
    float* te    = (float*)alloc((size_t)EE * 128 * 4);
    float* xpart = (float*)alloc((size_t)EE * 256 * 4);
    float* memb  = (float*)alloc((size_t)NN * 256 * 4);
    float* xbuf  = (float*)alloc((size_t)CAPR * 256 * 4);
    float* msgb  = (float*)alloc((size_t)CAPR * 256 * 4);
    float* gih   = (float*)alloc((size_t)2 * CAPR * 768 * 4);   // gi|gh during scan; h after
    float* gvec  = (float*)alloc(256 * 4);
    float* sdot  = (float*)alloc((size_t)NN * 4);
    float* ddot  = (float*)alloc((size_t)NN * 4);
    float* edot  = (float*)alloc((size_t)EE * 4);
    float* logit = (float*)alloc((size_t)EE * 4);
    float* alpha = (float*)alloc((size_t)EE * 4);
    unsigned* mx = (unsigned*)alloc((size_t)NN * 4);
    float* denom = (float*)alloc((size_t)NN * 4);
    if (off > ws_size) return;  // workspace too small: leave output untouched (visible failure)

    float* gi   = gih;
    float* gh   = gih + (size_t)CAPR * 768;
    float* h    = gih;    // alias: gi/gh dead after scan; NN*256 <= 2*CAPR*768
    float* efb  = xpart;  // alias: xpart dead after scan
    float* outb = memb;   // alias: mem dead after h-GEMMs (zeroed below before scatter)
    float* pe   = xbuf;   // alias
    float* c1   = msgb;   // alias

    hipMemsetAsync(rank, 0, (size_t)EE * 4, stream);
    hipMemsetAsync(cpos, 0, (size_t)EE * 4, stream);
    hipMemsetAsync(roundcnt, 0, 64 * 4, stream);
    hipMemsetAsync(memb, 0, (size_t)NN * 256 * 4, stream);
    hipMemsetAsync(mx, 0, (size_t)NN * 4, stream);
    hipMemsetAsync(denom, 0, (size_t)NN * 4, stream);

    const dim3 B(256);
    const int gE = (EE + 255) / 256;

    k_rank<<<dim3(gE, 8), B, 0, stream>>>(t, rank);
    k_order<<<gE, B, 0, stream>>>(rank, order);
    k_relevant<<<gE, B, 0, stream>>>(rank, order, src, rel);
    k_te<<<(EE * 128) / 256, B, 0, stream>>>(t, wt, bt, te);
    k_chainpos<<<dim3(gE, 8), B, 0, stream>>>(src, rank, rel, cpos);
    k_insert<<<gE, B, 0, stream>>>(rel, cpos, roundcnt, roundlist);

    // xpart = bm1 + nf[src]@Wm1[0:256] + ea@Wm1[512:640] + te@Wm1[640:768]
    const int gxE = (EE + GBM - 1) / GBM;
    k_gemm<0,0><<<dim3(gxE, 4), B, 0, stream>>>(nf, 256, src, Wm1, 256, bm1, xpart, 256, EE, nullptr, 0, 256);
    k_gemm<0,1><<<dim3(gxE, 4), B, 0, stream>>>(ea, 128, nullptr, Wm1 + 512 * 256, 256, nullptr, xpart, 256, EE, nullptr, 0, 128);
    k_gemm<0,1><<<dim3(gxE, 4), B, 0, stream>>>(te, 128, nullptr, Wm1 + 640 * 256, 256, nullptr, xpart, 256, EE, nullptr, 0, 128);

    // level-synchronous chain rounds (round j rows <= EE/(j+1))
    for (int j = 0; j < MAXR; ++j) {
        int bound = (EE + j) / (j + 1);
        for (int cb = 0; cb < bound; cb += CAPR) {
            int m = bound - cb; if (m > CAPR) m = CAPR;
            int gx = (m + GBM - 1) / GBM;
            k_gather<<<m, B, 0, stream>>>(roundlist + (size_t)j * EE, roundcnt + j, cb, m, src, xpart, xbuf, srcrow);
            k_gemm<1,1><<<dim3(gx, 4), B, 0, stream>>>(memb, 256, srcrow, Wm1 + 256 * 256, 256, nullptr, xbuf, 256, m, roundcnt + j, cb, 256);
            k_gemm<1,0><<<dim3(gx, 4), B, 0, stream>>>(xbuf, 256, nullptr, Wm2, 256, bm2, msgb, 256, m, roundcnt + j, cb, 256);
            k_gemm<0,0><<<dim3(gx, 12), B, 0, stream>>>(msgb, 256, nullptr, Wi, 768, bi, gi, 768, m, roundcnt + j, cb, 256);
            k_gemm<0,0><<<dim3(gx, 12), B, 0, stream>>>(memb, 256, srcrow, Wh, 768, bh, gh, 768, m, roundcnt + j, cb, 256);
            k_gru<<<m, B, 0, stream>>>(roundcnt + j, cb, m, srcrow, gi, gh, memb);
        }
    }

    // h = nf@Wg[0:256] + mem@Wg[256:512] + gte@Wg[512:640] (constant row -> gvec as bias)
    k_gvec<<<1, B, 0, stream>>>(t, order, wt, bt, Wg, gvec);
    const int gxN = (NN + GBM - 1) / GBM;
    k_gemm<0,0><<<dim3(gxN, 4), B, 0, stream>>>(nf, 256, nullptr, Wg, 256, gvec, h, 256, NN, nullptr, 0, 256);
    k_gemm<0,1><<<dim3(gxN, 4), B, 0, stream>>>(memb, 256, nullptr, Wg + 256 * 256, 256, nullptr, h, 256, NN, nullptr, 0, 256);

    hipMemsetAsync(outb, 0, (size_t)NN * 256 * 4, stream);  // memb dead -> becomes attention output accumulator

    // ef = ea@We[0:128] + te@We[128:256]
    k_gemm<0,0><<<dim3(gxE, 4), B, 0, stream>>>(ea, 128, nullptr, We, 256, nullptr, efb, 256, EE, nullptr, 0, 128);
    k_gemm<0,1><<<dim3(gxE, 4), B, 0, stream>>>(te, 128, nullptr, We + 128 * 256, 256, nullptr, efb, 256, EE, nullptr, 0, 128);

    k_dots2<<<(NN + 3) / 4, B, 0, stream>>>(h, 256, NN, a_src, a_dst, sdot, ddot);
    k_dots2<<<(EE + 3) / 4, B, 0, stream>>>(efb, 256, EE, a_e, nullptr, edot, nullptr);

    k_logitmax<<<gE, B, 0, stream>>>(sdot, ddot, edot, src, dst, logit, mx);
    k_alpha<<<gE, B, 0, stream>>>(logit, dst, mx, alpha, denom);
    k_scatter<<<EE, B, 0, stream>>>(alpha, src, dst, h, efb, outb);

    k_pe<<<PP, B, 0, stream>>>(pm, outb, denom, pe);
    k_gemm<1,0><<<dim3((PP + GBM - 1) / GBM, 2), B, 0, stream>>>(pe, 256, nullptr, Wc1, 128, bc1, c1, 128, PP, nullptr, 0, 256);
    k_final<<<(PP + 3) / 4, B, 0, stream>>>(c1, Wc2, bc2, outp);
}

// Round 2
// 1745.215 us; speedup vs baseline: 1.7609x; 1.7609x over previous
//
#include <hip/hip_runtime.h>

#define NN 50000
#define EE 40000
#define PP 4096
#define MAXR 12

typedef unsigned short ushort_t;
typedef __attribute__((ext_vector_type(8))) short bf8v;
typedef __attribute__((ext_vector_type(4))) float f4v;

__device__ __forceinline__ unsigned short f2b(float x) {
    unsigned u = __float_as_uint(x);
    u = (u + 0x7fffu + ((u >> 16) & 1u)) >> 16;
    return (unsigned short)u;
}
__device__ __forceinline__ float b2f(unsigned short h) {
    return __uint_as_float(((unsigned)h) << 16);
}
__device__ __forceinline__ unsigned fkey(float f) {
    unsigned u = __float_as_uint(f);
    return (u & 0x80000000u) ? ~u : (u | 0x80000000u);
}
__device__ __forceinline__ float funkey(unsigned k) {
    unsigned u = (k & 0x80000000u) ? (k & 0x7fffffffu) : ~k;
    return __uint_as_float(u);
}

// ---------------- ordering / chain decomposition ----------------

__global__ __launch_bounds__(256) void k_rank(const float* __restrict__ t, int* __restrict__ rank)
{
    const int tid = threadIdx.x;
    const int e = blockIdx.x * 256 + tid;
    const bool valid = (e < EE);
    const float myt = valid ? t[e] : 0.f;
    const int part = EE / 8;
    const int j0 = blockIdx.y * part, j1 = j0 + part;
    __shared__ float st[256];
    int cnt = 0;
    for (int tb = j0; tb < j1; tb += 256) {
        int j = tb + tid;
        st[tid] = (j < j1) ? t[j] : 0.f;
        __syncthreads();
        int tsz = j1 - tb; if (tsz > 256) tsz = 256;
        for (int jj = 0; jj < tsz; ++jj) {
            float tj = st[jj];
            cnt += (tj < myt || (tj == myt && (tb + jj) < e)) ? 1 : 0;
        }
        __syncthreads();
    }
    if (valid && cnt) atomicAdd(&rank[e], cnt);
}

__global__ void k_order(const int* __restrict__ rank, int* __restrict__ order)
{
    int e = blockIdx.x * 256 + threadIdx.x;
    if (e < EE) order[rank[e]] = e;
}

__global__ void k_relevant(const int* __restrict__ rank, const int* __restrict__ order,
                           const int* __restrict__ src, int* __restrict__ rel)
{
    int e = blockIdx.x * 256 + threadIdx.x;
    if (e >= EE) return;
    int r = rank[e];
    int end = (r / 200 + 1) * 200;
    int s = src[e];
    int v = 1;
    for (int rr = r + 1; rr < end; ++rr) {
        if (src[order[rr]] == s) { v = 0; break; }
    }
    rel[e] = v;
}

__global__ __launch_bounds__(256) void k_chainpos(const int* __restrict__ src, const int* __restrict__ rank,
                                                  const int* __restrict__ rel, int* __restrict__ cpos)
{
    const int tid = threadIdx.x;
    const int e = blockIdx.x * 256 + tid;
    const bool valid = (e < EE);
    const int msrc = valid ? src[e] : -1;
    const int mr2 = valid ? (rank[e] << 1) : 0;
    const int part = EE / 8;
    const int j0 = blockIdx.y * part, j1 = j0 + part;
    __shared__ int ssrc[256];
    __shared__ int spr[256];
    int cnt = 0;
    for (int tb = j0; tb < j1; tb += 256) {
        int j = tb + tid;
        if (j < j1) { ssrc[tid] = src[j]; spr[tid] = (rank[j] << 1) | rel[j]; }
        __syncthreads();
        int tsz = j1 - tb; if (tsz > 256) tsz = 256;
        for (int jj = 0; jj < tsz; ++jj) {
            int pr = spr[jj];
            cnt += (ssrc[jj] == msrc && (pr & 1) && pr < mr2) ? 1 : 0;
        }
        __syncthreads();
    }
    if (valid && cnt) atomicAdd(&cpos[e], cnt);
}

// LDS-aggregated insert: one global atomic per (block, round) instead of per edge
__global__ void k_insert(const int* __restrict__ rel, const int* __restrict__ cpos,
                         int* __restrict__ roundcnt, int* __restrict__ roundlist)
{
    __shared__ int lcnt[MAXR];
    __shared__ int lbase[MAXR];
    int tid = threadIdx.x;
    if (tid < MAXR) lcnt[tid] = 0;
    __syncthreads();
    int e = blockIdx.x * 256 + tid;
    int pos = -1, slot = 0;
    if (e < EE && rel[e]) {
        int p = cpos[e];
        if (p < MAXR) { pos = p; slot = atomicAdd(&lcnt[p], 1); }
    }
    __syncthreads();
    if (tid < MAXR && lcnt[tid]) lbase[tid] = atomicAdd(&roundcnt[tid], lcnt[tid]);
    __syncthreads();
    if (pos >= 0) roundlist[(size_t)pos * EE + lbase[pos] + slot] = e;
}

// ---------------- conversions ----------------

__global__ void k_te(const float* __restrict__ t, const float* __restrict__ w,
                     const float* __restrict__ b, unsigned short* __restrict__ te)
{
    int idx = blockIdx.x * 256 + threadIdx.x;
    if (idx >= EE * 128) return;
    int e = idx >> 7, j = idx & 127;
    te[idx] = f2b(sinf(t[e] * w[j] + b[j]));
}

__global__ void k_cvt(const float* __restrict__ x, unsigned short* __restrict__ y, int n4)
{
    int i = blockIdx.x * 256 + threadIdx.x;
    if (i >= n4) return;
    float4 v = reinterpret_cast<const float4*>(x)[i];
    ushort4 o;
    o.x = f2b(v.x); o.y = f2b(v.y); o.z = f2b(v.z); o.w = f2b(v.w);
    reinterpret_cast<ushort4*>(y)[i] = o;
}

// Wt[n][koff+k] = bf16(W[k][n]); W is K x N row-major f32
__global__ void k_wt(const float* __restrict__ W, unsigned short* __restrict__ Wt,
                     int K, int N, int koff, int Ktot)
{
    int idx = blockIdx.x * 256 + threadIdx.x;
    if (idx >= K * N) return;
    int n = idx / K, k = idx % K;
    Wt[(size_t)n * Ktot + koff + k] = f2b(W[(size_t)k * N + n]);
}

// ---------------- MFMA GEMM ----------------
// out = ACT( [A1|A2|A3](rows, gathered on A1 via idx1) @ Wt^T + bias + Cin )
// Wt is [N][Ktot] bf16 (pre-transposed).  BM=128 BN=64 BK=64, 4 waves.
__global__ __launch_bounds__(256) void k_mgemm(
    const unsigned short* __restrict__ A1, int K1, const int* __restrict__ idx1,
    const unsigned short* __restrict__ A2, int K2,
    const unsigned short* __restrict__ A3, int K3,
    const unsigned short* __restrict__ Wt, int Ktot,
    const float* __restrict__ bias,
    const unsigned short* __restrict__ Cin, const int* __restrict__ cidx,
    float* __restrict__ outF, unsigned short* __restrict__ outB, int ldc,
    int Mhost, const int* __restrict__ mdev, int mbase, int relu)
{
    int M = Mhost;
    if (mdev) {
        int avail = *mdev - mbase;
        if (avail < 0) avail = 0;
        if (avail < M) M = avail;
    }
    const int row0 = blockIdx.x * 128;
    if (row0 >= M) return;
    const int col0 = blockIdx.y * 64;

    __shared__ unsigned short As[128 * 64];
    __shared__ unsigned short Bs[64 * 64];

    const int tid = threadIdx.x;
    const int l = tid & 63;
    const int wv = tid >> 6;

    f4v acc[2][4];
#pragma unroll
    for (int i = 0; i < 2; ++i)
#pragma unroll
        for (int j = 0; j < 4; ++j) acc[i][j] = (f4v){0.f, 0.f, 0.f, 0.f};

    for (int k0 = 0; k0 < Ktot; k0 += 64) {
        // stage A: 128 rows x 64 k, 16B per (row,quad), quad swizzled by row&7
#pragma unroll
        for (int it = 0; it < 4; ++it) {
            int idx = tid + it * 256;
            int r = idx >> 3, q = idx & 7;
            int gk = k0 + q * 8;
            int grow = row0 + r;
            uint4 v = make_uint4(0u, 0u, 0u, 0u);
            if (grow < M) {
                const unsigned short* sp; int st, krel, ar = grow;
                if (gk < K1) { sp = A1; st = K1; krel = gk; if (idx1) ar = idx1[grow]; }
                else if (gk < K1 + K2) { sp = A2; st = K2; krel = gk - K1; }
                else { sp = A3; st = K3; krel = gk - K1 - K2; }
                v = *reinterpret_cast<const uint4*>(sp + (size_t)ar * st + krel);
            }
            *reinterpret_cast<uint4*>(As + r * 64 + ((q ^ (r & 7)) << 3)) = v;
        }
        // stage B: 64 cols x 64 k from Wt
#pragma unroll
        for (int it = 0; it < 2; ++it) {
            int idx = tid + it * 256;
            int c = idx >> 3, q = idx & 7;
            uint4 v = *reinterpret_cast<const uint4*>(Wt + (size_t)(col0 + c) * Ktot + k0 + q * 8);
            *reinterpret_cast<uint4*>(Bs + c * 64 + ((q ^ (c & 7)) << 3)) = v;
        }
        __syncthreads();
#pragma unroll
        for (int ks = 0; ks < 2; ++ks) {
            bf8v af[2], bf[4];
#pragma unroll
            for (int mf = 0; mf < 2; ++mf) {
                int r = wv * 32 + mf * 16 + (l & 15);
                int q = ks * 4 + (l >> 4);
                af[mf] = *reinterpret_cast<const bf8v*>(As + r * 64 + ((q ^ (r & 7)) << 3));
            }
#pragma unroll
            for (int nf = 0; nf < 4; ++nf) {
                int c = nf * 16 + (l & 15);
                int q = ks * 4 + (l >> 4);
                bf[nf] = *reinterpret_cast<const bf8v*>(Bs + c * 64 + ((q ^ (c & 7)) << 3));
            }
#pragma unroll
            for (int mf = 0; mf < 2; ++mf)
#pragma unroll
                for (int nf = 0; nf < 4; ++nf)
                    acc[mf][nf] = __builtin_amdgcn_mfma_f32_16x16x32_bf16(af[mf], bf[nf], acc[mf][nf], 0, 0, 0);
        }
        __syncthreads();
    }

    // epilogue: row = row0 + wv*32 + mf*16 + (l>>4)*4 + rr ; col = col0 + nf*16 + (l&15)
#pragma unroll
    for (int mf = 0; mf < 2; ++mf) {
#pragma unroll
        for (int rr = 0; rr < 4; ++rr) {
            int row = row0 + wv * 32 + mf * 16 + ((l >> 4) * 4) + rr;
            if (row >= M) continue;
            size_t crow = 0;
            if (Cin) crow = (size_t)(cidx ? cidx[row] : row) * ldc;
#pragma unroll
            for (int nf = 0; nf < 4; ++nf) {
                int col = col0 + nf * 16 + (l & 15);
                float v = acc[mf][nf][rr];
                if (bias) v += bias[col];
                if (Cin) v += b2f(Cin[crow + col]);
                if (relu) v = fmaxf(v, 0.f);
                if (outF) outF[(size_t)row * ldc + col] = v;
                if (outB) outB[(size_t)row * ldc + col] = f2b(v);
            }
        }
    }
}

// ---------------- scan helpers ----------------

__global__ void k_srcfill(int j, int base, int m, const int* __restrict__ roundlist,
                          const int* __restrict__ roundcnt, const int* __restrict__ src,
                          int* __restrict__ srcrow)
{
    int i = blockIdx.x * 256 + threadIdx.x;
    if (i >= m) return;
    if (base + i >= roundcnt[j]) return;
    srcrow[i] = src[roundlist[(size_t)j * EE + base + i]];
}

__global__ void k_gru(const int* __restrict__ cnt, int base, int m, const int* __restrict__ srcrow,
                      const unsigned short* __restrict__ gi, const unsigned short* __restrict__ gh,
                      float* __restrict__ mem, unsigned short* __restrict__ mem_bf)
{
    int i = blockIdx.x;
    int avail = *cnt - base;
    if (i >= m || i >= avail) return;
    int c = threadIdx.x;
    int s = srcrow[i];
    float hp = mem[(size_t)s * 256 + c];
    float ir = b2f(gi[(size_t)i * 768 + c]);
    float iz = b2f(gi[(size_t)i * 768 + 256 + c]);
    float in_ = b2f(gi[(size_t)i * 768 + 512 + c]);
    float hr = b2f(gh[(size_t)i * 768 + c]);
    float hz = b2f(gh[(size_t)i * 768 + 256 + c]);
    float hn = b2f(gh[(size_t)i * 768 + 512 + c]);
    float r = 1.f / (1.f + expf(-(ir + hr)));
    float z = 1.f / (1.f + expf(-(iz + hz)));
    float n = tanhf(in_ + r * hn);
    float hnew = (1.f - z) * n + z * hp;
    mem[(size_t)s * 256 + c] = hnew;
    mem_bf[(size_t)s * 256 + c] = f2b(hnew);
}

// fused per-row pipeline for small rounds (j >= 2): one block per row
__global__ void k_tail(int j, const int* __restrict__ roundcnt, const int* __restrict__ roundlist,
                       const int* __restrict__ src, const unsigned short* __restrict__ xpart_bf,
                       float* __restrict__ mem, unsigned short* __restrict__ mem_bf,
                       const float* __restrict__ Wm1, const float* __restrict__ Wm2,
                       const float* __restrict__ bm2, const float* __restrict__ Wi,
                       const float* __restrict__ Wh, const float* __restrict__ bi,
                       const float* __restrict__ bh)
{
    int i = blockIdx.x;
    if (i >= roundcnt[j]) return;
    int e = roundlist[(size_t)j * EE + i];
    int s = src[e];
    int c = threadIdx.x;
    __shared__ float hs[256];
    __shared__ float xv[256];
    __shared__ float msgv[256];
    __shared__ float giv[768];
    __shared__ float ghv[768];
    hs[c] = mem[(size_t)s * 256 + c];
    __syncthreads();
    float a = b2f(xpart_bf[(size_t)e * 256 + c]);
    for (int k = 0; k < 256; ++k) a += hs[k] * Wm1[(size_t)(256 + k) * 256 + c];
    xv[c] = fmaxf(a, 0.f);
    __syncthreads();
    float m = bm2[c];
    for (int k = 0; k < 256; ++k) m += xv[k] * Wm2[(size_t)k * 256 + c];
    msgv[c] = fmaxf(m, 0.f);
    __syncthreads();
#pragma unroll
    for (int tpart = 0; tpart < 3; ++tpart) {
        int cc = c + tpart * 256;
        float gi_ = bi[cc], gh_ = bh[cc];
        for (int k = 0; k < 256; ++k) {
            gi_ += msgv[k] * Wi[(size_t)k * 768 + cc];
            gh_ += hs[k] * Wh[(size_t)k * 768 + cc];
        }
        giv[cc] = gi_;
        ghv[cc] = gh_;
    }
    __syncthreads();
    float r = 1.f / (1.f + expf(-(giv[c] + ghv[c])));
    float z = 1.f / (1.f + expf(-(giv[256 + c] + ghv[256 + c])));
    float n = tanhf(giv[512 + c] + r * ghv[512 + c]);
    float hnew = (1.f - z) * n + z * hs[c];
    mem[(size_t)s * 256 + c] = hnew;
    mem_bf[(size_t)s * 256 + c] = f2b(hnew);
}

// ---------------- attention / head ----------------

__global__ void k_gvec(const float* __restrict__ t, const int* __restrict__ order,
                       const float* __restrict__ w, const float* __restrict__ b,
                       const float* __restrict__ Wg, float* __restrict__ gvec)
{
    float tmax = t[order[EE - 1]];
    int c = threadIdx.x;
    float acc = 0.f;
    for (int k = 0; k < 128; ++k) acc += sinf(tmax * w[k] + b[k]) * Wg[(size_t)(512 + k) * 256 + c];
    gvec[c] = acc;
}

__global__ __launch_bounds__(256) void k_dots2(const unsigned short* __restrict__ X, int M,
                                               const float* __restrict__ v1, const float* __restrict__ v2,
                                               float* __restrict__ o1, float* __restrict__ o2)
{
    int lane = threadIdx.x & 63;
    int row = blockIdx.x * 4 + (threadIdx.x >> 6);
    if (row >= M) return;
    ushort4 q = reinterpret_cast<const ushort4*>(X + (size_t)row * 256)[lane];
    int c = lane * 4;
    float x0 = b2f(q.x), x1 = b2f(q.y), x2 = b2f(q.z), x3 = b2f(q.w);
    float s1 = x0 * v1[c] + x1 * v1[c + 1] + x2 * v1[c + 2] + x3 * v1[c + 3];
    float s2 = 0.f;
    if (v2) s2 = x0 * v2[c] + x1 * v2[c + 1] + x2 * v2[c + 2] + x3 * v2[c + 3];
#pragma unroll
    for (int off = 32; off > 0; off >>= 1) {
        s1 += __shfl_xor(s1, off);
        if (v2) s2 += __shfl_xor(s2, off);
    }
    if (lane == 0) {
        o1[row] = s1;
        if (v2) o2[row] = s2;
    }
}

__global__ void k_logitmax(const float* __restrict__ sdot, const float* __restrict__ ddot,
                           const float* __restrict__ edot, const int* __restrict__ src,
                           const int* __restrict__ dst, float* __restrict__ logit,
                           unsigned* __restrict__ mx)
{
    int e = blockIdx.x * 256 + threadIdx.x;
    if (e >= EE) return;
    float l = sdot[src[e]] + ddot[dst[e]] + edot[e];
    l = (l > 0.f) ? l : 0.2f * l;
    logit[e] = l;
    atomicMax(&mx[dst[e]], fkey(l));
}

__global__ void k_alpha(const float* __restrict__ logit, const int* __restrict__ dst,
                        const unsigned* __restrict__ mx, float* __restrict__ alpha,
                        float* __restrict__ denom)
{
    int e = blockIdx.x * 256 + threadIdx.x;
    if (e >= EE) return;
    int d = dst[e];
    float a = expf(logit[e] - funkey(mx[d]));
    alpha[e] = a;
    atomicAdd(&denom[d], a);
}

__global__ void k_scatter(const float* __restrict__ alpha, const int* __restrict__ src,
                          const int* __restrict__ dst, const unsigned short* __restrict__ h,
                          const unsigned short* __restrict__ ef, float* __restrict__ outb)
{
    int e = blockIdx.x;
    int c4 = threadIdx.x;  // 64 threads, 4 cols each
    float a = alpha[e];
    int s = src[e], d = dst[e];
    ushort4 hv = reinterpret_cast<const ushort4*>(h + (size_t)s * 256)[c4];
    ushort4 ev = reinterpret_cast<const ushort4*>(ef + (size_t)e * 256)[c4];
    float* op = outb + (size_t)d * 256 + c4 * 4;
    atomicAdd(op + 0, a * (b2f(hv.x) + b2f(ev.x)));
    atomicAdd(op + 1, a * (b2f(hv.y) + b2f(ev.y)));
    atomicAdd(op + 2, a * (b2f(hv.z) + b2f(ev.z)));
    atomicAdd(op + 3, a * (b2f(hv.w) + b2f(ev.w)));
}

__global__ void k_pe(const int* __restrict__ pm, const float* __restrict__ outb,
                     const float* __restrict__ denom, unsigned short* __restrict__ pe)
{
    int p = blockIdx.x, c = threadIdx.x;
    int n = pm[p];
    pe[(size_t)p * 256 + c] = f2b(outb[(size_t)n * 256 + c] / (denom[n] + 1e-16f));
}

__global__ __launch_bounds__(256) void k_final(const float* __restrict__ c1, const float* __restrict__ Wc2,
                                               const float* __restrict__ bc2, float* __restrict__ out)
{
    int lane = threadIdx.x & 63;
    int row = blockIdx.x * 4 + (threadIdx.x >> 6);
    if (row >= PP) return;
    float s = 0.f;
    for (int c = lane; c < 128; c += 64) s += c1[(size_t)row * 128 + c] * Wc2[c];
#pragma unroll
    for (int off = 32; off > 0; off >>= 1) s += __shfl_xor(s, off);
    if (lane == 0) out[row] = 1.f / (1.f + expf(-(s + bc2[0])));
}

// ---------------- host ----------------

extern "C" void kernel_launch(void* const* d_in, const int* in_sizes, int n_in,
                              void* d_out, int out_size, void* d_ws, size_t ws_size,
                              hipStream_t stream)
{
    (void)in_sizes; (void)n_in; (void)out_size;
    const float* nf    = (const float*)d_in[0];
    const int*   ei    = (const int*)  d_in[1];
    const float* ea    = (const float*)d_in[2];
    const float* t     = (const float*)d_in[3];
    const int*   pm    = (const int*)  d_in[4];
    const float* wt    = (const float*)d_in[5];
    const float* bt    = (const float*)d_in[6];
    const float* Wm1   = (const float*)d_in[7];
    const float* bm1   = (const float*)d_in[8];
    const float* Wm2   = (const float*)d_in[9];
    const float* bm2   = (const float*)d_in[10];
    const float* Wi    = (const float*)d_in[11];
    const float* Wh    = (const float*)d_in[12];
    const float* bi    = (const float*)d_in[13];
    const float* bh    = (const float*)d_in[14];
    const float* Wg    = (const float*)d_in[15];
    const float* We    = (const float*)d_in[16];
    const float* a_src = (const float*)d_in[17];
    const float* a_dst = (const float*)d_in[18];
    const float* a_e   = (const float*)d_in[19];
    const float* Wc1   = (const float*)d_in[20];
    const float* bc1   = (const float*)d_in[21];
    const float* Wc2   = (const float*)d_in[22];
    const float* bc2   = (const float*)d_in[23];
    float* outp = (float*)d_out;
    const int* src = ei;
    const int* dst = ei + EE;

    char* base = (char*)d_ws;
    size_t off = 0;
    auto alloc = [&](size_t bytes) -> void* {
        void* p = base + off;
        off = (off + bytes + 255) & ~(size_t)255;
        return p;
    };
    typedef unsigned short us;
    int* rank      = (int*)alloc((size_t)EE * 4);
    int* order     = (int*)alloc((size_t)EE * 4);
    int* rel       = (int*)alloc((size_t)EE * 4);
    int* cpos      = (int*)alloc((size_t)EE * 4);
    int* roundcnt  = (int*)alloc(64 * 4);
    int* roundlist = (int*)alloc((size_t)MAXR * EE * 4);
    us* te_bf    = (us*)alloc((size_t)EE * 128 * 2);
    us* nf_bf    = (us*)alloc((size_t)NN * 256 * 2);
    us* ea_bf    = (us*)alloc((size_t)EE * 128 * 2);
    us* xpart_bf = (us*)alloc((size_t)EE * 256 * 2);
    float* memb  = (float*)alloc((size_t)NN * 256 * 4);
    us* memb_bf  = (us*)alloc((size_t)NN * 256 * 2);
    us* Wt_x = (us*)alloc((size_t)256 * 512 * 2);
    us* Wt_a = (us*)alloc((size_t)256 * 256 * 2);
    us* Wt_m2= (us*)alloc((size_t)256 * 256 * 2);
    us* Wt_i = (us*)alloc((size_t)768 * 256 * 2);
    us* Wt_h = (us*)alloc((size_t)768 * 256 * 2);
    us* Wt_g = (us*)alloc((size_t)256 * 512 * 2);
    us* Wt_e = (us*)alloc((size_t)256 * 256 * 2);
    us* Wt_c = (us*)alloc((size_t)128 * 256 * 2);
    float* gvec  = (float*)alloc(256 * 4);
    float* sdot  = (float*)alloc((size_t)NN * 4);
    float* ddot  = (float*)alloc((size_t)NN * 4);
    float* edot  = (float*)alloc((size_t)EE * 4);
    float* logit = (float*)alloc((size_t)EE * 4);
    float* alpha = (float*)alloc((size_t)EE * 4);
    unsigned* mx = (unsigned*)alloc((size_t)NN * 4);
    float* denom = (float*)alloc((size_t)NN * 4);

    // dynamic chunk region
    size_t region = (ws_size > off + 4096) ? (ws_size - off - 4096) : 0;
    long capL = (long)(region / 4104);
    int CAPR = (int)(capL < 0 ? 0 : capL);
    CAPR = (CAPR / 128) * 128;
    if (CAPR > 20480) CAPR = 20480;
    if (CAPR < 6400) return;  // ws too small (not expected; proven >= 185MB)
    us* xbuf_bf = (us*)alloc((size_t)CAPR * 256 * 2);
    us* msg_bf  = (us*)alloc((size_t)CAPR * 256 * 2);
    us* gi_bf   = (us*)alloc((size_t)CAPR * 768 * 2);
    us* gh_bf   = (us*)alloc((size_t)CAPR * 768 * 2);
    int* srcrow = (int*)alloc((size_t)CAPR * 4);
    if (off > ws_size) return;

    us* h_bf  = xbuf_bf;             // alias: chunk region dead post-scan (needs 25.6MB <= CAPR*4.1KB)
    us* ef_bf = xpart_bf;            // alias: xpart dead post-scan (same size)
    float* outb = memb;              // alias: f32 mem dead post-scan
    us* pe_bf = te_bf;               // alias: te dead after ef GEMM
    float* c1 = (float*)(te_bf + (size_t)PP * 256);

    hipMemsetAsync(rank, 0, (size_t)EE * 4, stream);
    hipMemsetAsync(cpos, 0, (size_t)EE * 4, stream);
    hipMemsetAsync(roundcnt, 0, 64 * 4, stream);
    hipMemsetAsync(memb, 0, (size_t)NN * 256 * 4, stream);
    hipMemsetAsync(memb_bf, 0, (size_t)NN * 256 * 2, stream);
    hipMemsetAsync(mx, 0, (size_t)NN * 4, stream);
    hipMemsetAsync(denom, 0, (size_t)NN * 4, stream);

    const dim3 B(256);
    const int gE = (EE + 255) / 256;

    k_rank<<<dim3(gE, 8), B, 0, stream>>>(t, rank);
    k_order<<<gE, B, 0, stream>>>(rank, order);
    k_relevant<<<gE, B, 0, stream>>>(rank, order, src, rel);
    k_chainpos<<<dim3(gE, 8), B, 0, stream>>>(src, rank, rel, cpos);
    k_insert<<<gE, B, 0, stream>>>(rel, cpos, roundcnt, roundlist);

    k_te<<<(EE * 128) / 256, B, 0, stream>>>(t, wt, bt, te_bf);
    k_cvt<<<(NN * 256 / 4 + 255) / 256, B, 0, stream>>>(nf, nf_bf, NN * 256 / 4);
    k_cvt<<<(EE * 128 / 4 + 255) / 256, B, 0, stream>>>(ea, ea_bf, EE * 128 / 4);

    auto wtl = [&](const float* W, us* Wt, int K, int N, int koff, int Ktot) {
        k_wt<<<(K * N + 255) / 256, B, 0, stream>>>(W, Wt, K, N, koff, Ktot);
    };
    wtl(Wm1, Wt_x, 256, 256, 0, 512);
    wtl(Wm1 + (size_t)512 * 256, Wt_x, 128, 256, 256, 512);
    wtl(Wm1 + (size_t)640 * 256, Wt_x, 128, 256, 384, 512);
    wtl(Wm1 + (size_t)256 * 256, Wt_a, 256, 256, 0, 256);
    wtl(Wm2, Wt_m2, 256, 256, 0, 256);
    wtl(Wi, Wt_i, 256, 768, 0, 256);
    wtl(Wh, Wt_h, 256, 768, 0, 256);
    wtl(Wg, Wt_g, 512, 256, 0, 512);
    wtl(We, Wt_e, 256, 256, 0, 256);
    wtl(Wc1, Wt_c, 256, 128, 0, 256);

    // xpart = bm1 + nf[src]@Wm1[0:256] + ea@Wm1[512:640] + te@Wm1[640:768]  (bf16 out)
    const int gxE = (EE + 127) / 128;
    k_mgemm<<<dim3(gxE, 4), B, 0, stream>>>(nf_bf, 256, src, ea_bf, 128, te_bf, 128,
        Wt_x, 512, bm1, nullptr, nullptr, nullptr, xpart_bf, 256, EE, nullptr, 0, 0);

    // chain rounds 0,1 via MFMA GEMMs; rounds >=2 fused per-row
    for (int j = 0; j < 2; ++j) {
        int bound = EE / (j + 1);
        for (int cb = 0; cb < bound; cb += CAPR) {
            int m = bound - cb; if (m > CAPR) m = CAPR;
            int gx = (m + 127) / 128;
            k_srcfill<<<(m + 255) / 256, B, 0, stream>>>(j, cb, m, roundlist, roundcnt, src, srcrow);
            k_mgemm<<<dim3(gx, 4), B, 0, stream>>>(memb_bf, 256, srcrow, nullptr, 0, nullptr, 0,
                Wt_a, 256, nullptr, xpart_bf, roundlist + (size_t)j * EE + cb,
                nullptr, xbuf_bf, 256, m, roundcnt + j, cb, 1);
            k_mgemm<<<dim3(gx, 4), B, 0, stream>>>(xbuf_bf, 256, nullptr, nullptr, 0, nullptr, 0,
                Wt_m2, 256, bm2, nullptr, nullptr, nullptr, msg_bf, 256, m, roundcnt + j, cb, 1);
            k_mgemm<<<dim3(gx, 12), B, 0, stream>>>(msg_bf, 256, nullptr, nullptr, 0, nullptr, 0,
                Wt_i, 256, bi, nullptr, nullptr, nullptr, gi_bf, 768, m, roundcnt + j, cb, 0);
            k_mgemm<<<dim3(gx, 12), B, 0, stream>>>(memb_bf, 256, srcrow, nullptr, 0, nullptr, 0,
                Wt_h, 256, bh, nullptr, nullptr, nullptr, gh_bf, 768, m, roundcnt + j, cb, 0);
            k_gru<<<m, B, 0, stream>>>(roundcnt + j, cb, m, srcrow, gi_bf, gh_bf, memb, memb_bf);
        }
    }
    for (int j = 2; j < MAXR; ++j) {
        int bound = (EE + j) / (j + 1);
        k_tail<<<bound, B, 0, stream>>>(j, roundcnt, roundlist, src, xpart_bf, memb, memb_bf,
                                        Wm1, Wm2, bm2, Wi, Wh, bi, bh);
    }

    // h = [nf | mem]@Wg[0:512] + gte@Wg[512:640]
    k_gvec<<<1, B, 0, stream>>>(t, order, wt, bt, Wg, gvec);
    const int gxN = (NN + 127) / 128;
    k_mgemm<<<dim3(gxN, 4), B, 0, stream>>>(nf_bf, 256, nullptr, memb_bf, 256, nullptr, 0,
        Wt_g, 512, gvec, nullptr, nullptr, nullptr, h_bf, 256, NN, nullptr, 0, 0);

    // ef = [ea | te]@We
    k_mgemm<<<dim3(gxE, 4), B, 0, stream>>>(ea_bf, 128, nullptr, te_bf, 128, nullptr, 0,
        Wt_e, 256, nullptr, nullptr, nullptr, nullptr, ef_bf, 256, EE, nullptr, 0, 0);

    hipMemsetAsync(outb, 0, (size_t)NN * 256 * 4, stream);

    k_dots2<<<(NN + 3) / 4, B, 0, stream>>>(h_bf, NN, a_src, a_dst, sdot, ddot);
    k_dots2<<<(EE + 3) / 4, B, 0, stream>>>(ef_bf, EE, a_e, nullptr, edot, nullptr);

    k_logitmax<<<gE, B, 0, stream>>>(sdot, ddot, edot, src, dst, logit, mx);
    k_alpha<<<gE, B, 0, stream>>>(logit, dst, mx, alpha, denom);
    k_scatter<<<EE, dim3(64), 0, stream>>>(alpha, src, dst, h_bf, ef_bf, outb);

    k_pe<<<PP, B, 0, stream>>>(pm, outb, denom, pe_bf);
    k_mgemm<<<dim3((PP + 127) / 128, 2), B, 0, stream>>>(pe_bf, 256, nullptr, nullptr, 0, nullptr, 0,
        Wt_c, 256, bc1, nullptr, nullptr, c1, nullptr, 128, PP, nullptr, 0, 1);
    k_final<<<(PP + 3) / 4, B, 0, stream>>>(c1, Wc2, bc2, outp);
}

// Round 3
// 1210.994 us; speedup vs baseline: 2.5377x; 1.4411x over previous
//
#include <hip/hip_runtime.h>

#define NN 50000
#define EE 40000
#define PP 4096
#define MAXR 12
#define SCAP 16
#define NB 65536

typedef __attribute__((ext_vector_type(8))) short bf8v;
typedef __attribute__((ext_vector_type(4))) float f4v;

__device__ __forceinline__ unsigned short f2b(float x) {
    unsigned u = __float_as_uint(x);
    u = (u + 0x7fffu + ((u >> 16) & 1u)) >> 16;
    return (unsigned short)u;
}
__device__ __forceinline__ float b2f(unsigned short h) {
    return __uint_as_float(((unsigned)h) << 16);
}
__device__ __forceinline__ unsigned fkey(float f) {
    unsigned u = __float_as_uint(f);
    return (u & 0x80000000u) ? ~u : (u | 0x80000000u);
}
__device__ __forceinline__ float funkey(unsigned k) {
    unsigned u = (k & 0x80000000u) ? (k & 0x7fffffffu) : ~k;
    return __uint_as_float(u);
}
__device__ __forceinline__ int bucket_of(float tv) {
    int b = (int)(tv * 65536.0f);
    if (b < 0) b = 0;
    if (b > 65535) b = 65535;
    return b;
}

// ---------------- ordering: bucket counting-sort rank ----------------

__global__ void k_hist(const float* __restrict__ t, int* __restrict__ hist)
{
    int e = blockIdx.x * 256 + threadIdx.x;
    if (e >= EE) return;
    atomicAdd(&hist[bucket_of(t[e])], 1);
}

__global__ void k_scan1(const int* __restrict__ hist, int* __restrict__ hbase, int* __restrict__ bsum)
{
    __shared__ int s[256];
    int i = blockIdx.x * 256 + threadIdx.x;
    int v = hist[i];
    s[threadIdx.x] = v;
    __syncthreads();
    for (int o = 1; o < 256; o <<= 1) {
        int x = (threadIdx.x >= o) ? s[threadIdx.x - o] : 0;
        __syncthreads();
        s[threadIdx.x] += x;
        __syncthreads();
    }
    hbase[i] = s[threadIdx.x] - v;
    if (threadIdx.x == 255) bsum[blockIdx.x] = s[255];
}

__global__ void k_scan2(int* __restrict__ bsum)
{
    __shared__ int s[256];
    int v = bsum[threadIdx.x];
    s[threadIdx.x] = v;
    __syncthreads();
    for (int o = 1; o < 256; o <<= 1) {
        int x = (threadIdx.x >= o) ? s[threadIdx.x - o] : 0;
        __syncthreads();
        s[threadIdx.x] += x;
        __syncthreads();
    }
    bsum[threadIdx.x] = s[threadIdx.x] - v;
}

__global__ void k_scan3(int* __restrict__ hbase, const int* __restrict__ bsum)
{
    int i = blockIdx.x * 256 + threadIdx.x;
    hbase[i] += bsum[blockIdx.x];
}

__global__ void k_bscatter(const float* __restrict__ t, const int* __restrict__ hbase,
                           int* __restrict__ hcur, int* __restrict__ blist)
{
    int e = blockIdx.x * 256 + threadIdx.x;
    if (e >= EE) return;
    int b = bucket_of(t[e]);
    int p = hbase[b] + atomicAdd(&hcur[b], 1);
    blist[p] = e;
}

// rank = bucket base + #{j in bucket: (t_j, j) < (t_e, e)}  == stable argsort position
__global__ void k_rank2(const float* __restrict__ t, const int* __restrict__ hbase,
                        const int* __restrict__ hist, const int* __restrict__ blist,
                        int* __restrict__ rank)
{
    int e = blockIdx.x * 256 + threadIdx.x;
    if (e >= EE) return;
    float te_ = t[e];
    int b = bucket_of(te_);
    int base = hbase[b], cnt = hist[b];
    int r = base;
    for (int i = 0; i < cnt; ++i) {
        int j = blist[base + i];
        float tj = t[j];
        r += (tj < te_ || (tj == te_ && j < e)) ? 1 : 0;
    }
    rank[e] = r;
}

__global__ void k_tmax(const float* __restrict__ t, unsigned* __restrict__ tm)
{
    int i = blockIdx.x * 256 + threadIdx.x;
    float v = (i < EE) ? t[i] : 0.f;
#pragma unroll
    for (int o = 32; o > 0; o >>= 1) v = fmaxf(v, __shfl_xor(v, o));
    if ((threadIdx.x & 63) == 0) atomicMax(tm, fkey(v));
}

// ---------------- chain decomposition via per-src lists ----------------

__global__ void k_slist(const int* __restrict__ src, int* __restrict__ scnt, int* __restrict__ slist)
{
    int e = blockIdx.x * 256 + threadIdx.x;
    if (e >= EE) return;
    int s = src[e];
    int slot = atomicAdd(&scnt[s], 1);
    if (slot < SCAP) slist[s * SCAP + slot] = e;
}

// rel[e]=1 iff no same-src edge in same batch with larger rank; cpos = # relevant same-src edges with smaller rank
__global__ void k_chain2(const int* __restrict__ src, const int* __restrict__ rank,
                         const int* __restrict__ scnt, const int* __restrict__ slist,
                         int* __restrict__ rel, int* __restrict__ cpos)
{
    int e = blockIdx.x * 256 + threadIdx.x;
    if (e >= EE) return;
    int s = src[e];
    int c = scnt[s]; if (c > SCAP) c = SCAP;
    int re = rank[e], be = re / 200;
    bool r_e = true;
    for (int i = 0; i < c; ++i) {
        int rj = rank[slist[s * SCAP + i]];
        if (rj / 200 == be && rj > re) { r_e = false; break; }
    }
    if (!r_e) { rel[e] = 0; return; }
    rel[e] = 1;
    int pos = 0;
    for (int i = 0; i < c; ++i) {
        int rj = rank[slist[s * SCAP + i]];
        if (rj >= re) continue;
        int bj = rj / 200;
        bool r_j = true;
        for (int k2 = 0; k2 < c; ++k2) {
            int rj2 = rank[slist[s * SCAP + k2]];
            if (rj2 / 200 == bj && rj2 > rj) { r_j = false; break; }
        }
        pos += r_j ? 1 : 0;
    }
    cpos[e] = pos;
}

// LDS-aggregated insert: one global atomic per (block, round)
__global__ void k_insert(const int* __restrict__ rel, const int* __restrict__ cpos,
                         int* __restrict__ roundcnt, int* __restrict__ roundlist)
{
    __shared__ int lcnt[MAXR];
    __shared__ int lbase[MAXR];
    int tid = threadIdx.x;
    if (tid < MAXR) lcnt[tid] = 0;
    __syncthreads();
    int e = blockIdx.x * 256 + tid;
    int pos = -1, slot = 0;
    if (e < EE && rel[e]) {
        int p = cpos[e];
        if (p < MAXR) { pos = p; slot = atomicAdd(&lcnt[p], 1); }
    }
    __syncthreads();
    if (tid < MAXR && lcnt[tid]) lbase[tid] = atomicAdd(&roundcnt[tid], lcnt[tid]);
    __syncthreads();
    if (pos >= 0) roundlist[(size_t)pos * EE + lbase[pos] + slot] = e;
}

// ---------------- conversions ----------------

__global__ void k_te(const float* __restrict__ t, const float* __restrict__ w,
                     const float* __restrict__ b, unsigned short* __restrict__ te)
{
    int idx = blockIdx.x * 256 + threadIdx.x;
    if (idx >= EE * 128) return;
    int e = idx >> 7, j = idx & 127;
    te[idx] = f2b(sinf(t[e] * w[j] + b[j]));
}

__global__ void k_cvt(const float* __restrict__ x, unsigned short* __restrict__ y, int n4)
{
    int i = blockIdx.x * 256 + threadIdx.x;
    if (i >= n4) return;
    float4 v = reinterpret_cast<const float4*>(x)[i];
    ushort4 o;
    o.x = f2b(v.x); o.y = f2b(v.y); o.z = f2b(v.z); o.w = f2b(v.w);
    reinterpret_cast<ushort4*>(y)[i] = o;
}

// Wt[n][koff+k] = bf16(W[k][n]); W is K x N row-major f32
__global__ void k_wt(const float* __restrict__ W, unsigned short* __restrict__ Wt,
                     int K, int N, int koff, int Ktot)
{
    int idx = blockIdx.x * 256 + threadIdx.x;
    if (idx >= K * N) return;
    int n = idx / K, k = idx % K;
    Wt[(size_t)n * Ktot + koff + k] = f2b(W[(size_t)k * N + n]);
}

// ---------------- MFMA GEMM ----------------
// out = ACT( [A1|A2|A3](rows, gathered on A1 via idx1) @ Wt^T + bias + Cin )
__global__ __launch_bounds__(256) void k_mgemm(
    const unsigned short* __restrict__ A1, int K1, const int* __restrict__ idx1,
    const unsigned short* __restrict__ A2, int K2,
    const unsigned short* __restrict__ A3, int K3,
    const unsigned short* __restrict__ Wt, int Ktot,
    const float* __restrict__ bias,
    const unsigned short* __restrict__ Cin, const int* __restrict__ cidx,
    float* __restrict__ outF, unsigned short* __restrict__ outB, int ldc,
    int Mhost, const int* __restrict__ mdev, int mbase, int relu)
{
    int M = Mhost;
    if (mdev) {
        int avail = *mdev - mbase;
        if (avail < 0) avail = 0;
        if (avail < M) M = avail;
    }
    const int row0 = blockIdx.x * 128;
    if (row0 >= M) return;
    const int col0 = blockIdx.y * 64;

    __shared__ unsigned short As[128 * 64];
    __shared__ unsigned short Bs[64 * 64];

    const int tid = threadIdx.x;
    const int l = tid & 63;
    const int wv = tid >> 6;

    f4v acc[2][4];
#pragma unroll
    for (int i = 0; i < 2; ++i)
#pragma unroll
        for (int j = 0; j < 4; ++j) acc[i][j] = (f4v){0.f, 0.f, 0.f, 0.f};

    for (int k0 = 0; k0 < Ktot; k0 += 64) {
#pragma unroll
        for (int it = 0; it < 4; ++it) {
            int idx = tid + it * 256;
            int r = idx >> 3, q = idx & 7;
            int gk = k0 + q * 8;
            int grow = row0 + r;
            uint4 v = make_uint4(0u, 0u, 0u, 0u);
            if (grow < M) {
                const unsigned short* sp; int st, krel, ar = grow;
                if (gk < K1) { sp = A1; st = K1; krel = gk; if (idx1) ar = idx1[grow]; }
                else if (gk < K1 + K2) { sp = A2; st = K2; krel = gk - K1; }
                else { sp = A3; st = K3; krel = gk - K1 - K2; }
                v = *reinterpret_cast<const uint4*>(sp + (size_t)ar * st + krel);
            }
            *reinterpret_cast<uint4*>(As + r * 64 + ((q ^ (r & 7)) << 3)) = v;
        }
#pragma unroll
        for (int it = 0; it < 2; ++it) {
            int idx = tid + it * 256;
            int c = idx >> 3, q = idx & 7;
            uint4 v = *reinterpret_cast<const uint4*>(Wt + (size_t)(col0 + c) * Ktot + k0 + q * 8);
            *reinterpret_cast<uint4*>(Bs + c * 64 + ((q ^ (c & 7)) << 3)) = v;
        }
        __syncthreads();
#pragma unroll
        for (int ks = 0; ks < 2; ++ks) {
            bf8v af[2], bf[4];
#pragma unroll
            for (int mf = 0; mf < 2; ++mf) {
                int r = wv * 32 + mf * 16 + (l & 15);
                int q = ks * 4 + (l >> 4);
                af[mf] = *reinterpret_cast<const bf8v*>(As + r * 64 + ((q ^ (r & 7)) << 3));
            }
#pragma unroll
            for (int nf = 0; nf < 4; ++nf) {
                int c = nf * 16 + (l & 15);
                int q = ks * 4 + (l >> 4);
                bf[nf] = *reinterpret_cast<const bf8v*>(Bs + c * 64 + ((q ^ (c & 7)) << 3));
            }
#pragma unroll
            for (int mf = 0; mf < 2; ++mf)
#pragma unroll
                for (int nf = 0; nf < 4; ++nf)
                    acc[mf][nf] = __builtin_amdgcn_mfma_f32_16x16x32_bf16(af[mf], bf[nf], acc[mf][nf], 0, 0, 0);
        }
        __syncthreads();
    }

#pragma unroll
    for (int mf = 0; mf < 2; ++mf) {
#pragma unroll
        for (int rr = 0; rr < 4; ++rr) {
            int row = row0 + wv * 32 + mf * 16 + ((l >> 4) * 4) + rr;
            if (row >= M) continue;
            size_t crow = 0;
            if (Cin) crow = (size_t)(cidx ? cidx[row] : row) * ldc;
#pragma unroll
            for (int nf = 0; nf < 4; ++nf) {
                int col = col0 + nf * 16 + (l & 15);
                float v = acc[mf][nf][rr];
                if (bias) v += bias[col];
                if (Cin) v += b2f(Cin[crow + col]);
                if (relu) v = fmaxf(v, 0.f);
                if (outF) outF[(size_t)row * ldc + col] = v;
                if (outB) outB[(size_t)row * ldc + col] = f2b(v);
            }
        }
    }
}

// ---------------- scan helpers ----------------

__global__ void k_srcfill(int j, int base, int m, const int* __restrict__ roundlist,
                          const int* __restrict__ roundcnt, const int* __restrict__ src,
                          int* __restrict__ srcrow)
{
    int i = blockIdx.x * 256 + threadIdx.x;
    if (i >= m) return;
    if (base + i >= roundcnt[j]) return;
    srcrow[i] = src[roundlist[(size_t)j * EE + base + i]];
}

__global__ void k_gru(const int* __restrict__ cnt, int base, int m, const int* __restrict__ srcrow,
                      const unsigned short* __restrict__ gi, const unsigned short* __restrict__ gh,
                      float* __restrict__ mem, unsigned short* __restrict__ mem_bf)
{
    int i = blockIdx.x;
    int avail = *cnt - base;
    if (i >= m || i >= avail) return;
    int c = threadIdx.x;
    int s = srcrow[i];
    float hp = mem[(size_t)s * 256 + c];
    float ir = b2f(gi[(size_t)i * 768 + c]);
    float iz = b2f(gi[(size_t)i * 768 + 256 + c]);
    float in_ = b2f(gi[(size_t)i * 768 + 512 + c]);
    float hr = b2f(gh[(size_t)i * 768 + c]);
    float hz = b2f(gh[(size_t)i * 768 + 256 + c]);
    float hn = b2f(gh[(size_t)i * 768 + 512 + c]);
    float r = 1.f / (1.f + expf(-(ir + hr)));
    float z = 1.f / (1.f + expf(-(iz + hz)));
    float n = tanhf(in_ + r * hn);
    float hnew = (1.f - z) * n + z * hp;
    mem[(size_t)s * 256 + c] = hnew;
    mem_bf[(size_t)s * 256 + c] = f2b(hnew);
}

// fused per-row pipeline for small rounds (j >= 2)
__global__ void k_tail(int j, const int* __restrict__ roundcnt, const int* __restrict__ roundlist,
                       const int* __restrict__ src, const unsigned short* __restrict__ xpart_bf,
                       float* __restrict__ mem, unsigned short* __restrict__ mem_bf,
                       const float* __restrict__ Wm1, const float* __restrict__ Wm2,
                       const float* __restrict__ bm2, const float* __restrict__ Wi,
                       const float* __restrict__ Wh, const float* __restrict__ bi,
                       const float* __restrict__ bh)
{
    int i = blockIdx.x;
    if (i >= roundcnt[j]) return;
    int e = roundlist[(size_t)j * EE + i];
    int s = src[e];
    int c = threadIdx.x;
    __shared__ float hs[256];
    __shared__ float xv[256];
    __shared__ float msgv[256];
    __shared__ float giv[768];
    __shared__ float ghv[768];
    hs[c] = mem[(size_t)s * 256 + c];
    __syncthreads();
    float a = b2f(xpart_bf[(size_t)e * 256 + c]);
    for (int k = 0; k < 256; ++k) a += hs[k] * Wm1[(size_t)(256 + k) * 256 + c];
    xv[c] = fmaxf(a, 0.f);
    __syncthreads();
    float m = bm2[c];
    for (int k = 0; k < 256; ++k) m += xv[k] * Wm2[(size_t)k * 256 + c];
    msgv[c] = fmaxf(m, 0.f);
    __syncthreads();
#pragma unroll
    for (int tpart = 0; tpart < 3; ++tpart) {
        int cc = c + tpart * 256;
        float gi_ = bi[cc], gh_ = bh[cc];
        for (int k = 0; k < 256; ++k) {
            gi_ += msgv[k] * Wi[(size_t)k * 768 + cc];
            gh_ += hs[k] * Wh[(size_t)k * 768 + cc];
        }
        giv[cc] = gi_;
        ghv[cc] = gh_;
    }
    __syncthreads();
    float r = 1.f / (1.f + expf(-(giv[c] + ghv[c])));
    float z = 1.f / (1.f + expf(-(giv[256 + c] + ghv[256 + c])));
    float n = tanhf(giv[512 + c] + r * ghv[512 + c]);
    float hnew = (1.f - z) * n + z * hs[c];
    mem[(size_t)s * 256 + c] = hnew;
    mem_bf[(size_t)s * 256 + c] = f2b(hnew);
}

// ---------------- attention / head ----------------

__global__ void k_gvec(const unsigned* __restrict__ tm, const float* __restrict__ w,
                       const float* __restrict__ b, const float* __restrict__ Wg,
                       float* __restrict__ gvec)
{
    float tmax = funkey(*tm);
    int c = threadIdx.x;
    float acc = 0.f;
    for (int k = 0; k < 128; ++k) acc += sinf(tmax * w[k] + b[k]) * Wg[(size_t)(512 + k) * 256 + c];
    gvec[c] = acc;
}

__global__ __launch_bounds__(256) void k_dots2(const unsigned short* __restrict__ X, int M,
                                               const float* __restrict__ v1, const float* __restrict__ v2,
                                               float* __restrict__ o1, float* __restrict__ o2)
{
    int lane = threadIdx.x & 63;
    int row = blockIdx.x * 4 + (threadIdx.x >> 6);
    if (row >= M) return;
    ushort4 q = reinterpret_cast<const ushort4*>(X + (size_t)row * 256)[lane];
    int c = lane * 4;
    float x0 = b2f(q.x), x1 = b2f(q.y), x2 = b2f(q.z), x3 = b2f(q.w);
    float s1 = x0 * v1[c] + x1 * v1[c + 1] + x2 * v1[c + 2] + x3 * v1[c + 3];
    float s2 = 0.f;
    if (v2) s2 = x0 * v2[c] + x1 * v2[c + 1] + x2 * v2[c + 2] + x3 * v2[c + 3];
#pragma unroll
    for (int off = 32; off > 0; off >>= 1) {
        s1 += __shfl_xor(s1, off);
        if (v2) s2 += __shfl_xor(s2, off);
    }
    if (lane == 0) {
        o1[row] = s1;
        if (v2) o2[row] = s2;
    }
}

__global__ void k_logitmax(const float* __restrict__ sdot, const float* __restrict__ ddot,
                           const float* __restrict__ edot, const int* __restrict__ src,
                           const int* __restrict__ dst, float* __restrict__ logit,
                           unsigned* __restrict__ mx)
{
    int e = blockIdx.x * 256 + threadIdx.x;
    if (e >= EE) return;
    float l = sdot[src[e]] + ddot[dst[e]] + edot[e];
    l = (l > 0.f) ? l : 0.2f * l;
    logit[e] = l;
    atomicMax(&mx[dst[e]], fkey(l));
}

__global__ void k_alpha(const float* __restrict__ logit, const int* __restrict__ dst,
                        const unsigned* __restrict__ mx, float* __restrict__ alpha,
                        float* __restrict__ denom)
{
    int e = blockIdx.x * 256 + threadIdx.x;
    if (e >= EE) return;
    int d = dst[e];
    float a = expf(logit[e] - funkey(mx[d]));
    alpha[e] = a;
    atomicAdd(&denom[d], a);
}

__global__ void k_scatter(const float* __restrict__ alpha, const int* __restrict__ src,
                          const int* __restrict__ dst, const unsigned short* __restrict__ h,
                          const unsigned short* __restrict__ ef, float* __restrict__ outb)
{
    int e = blockIdx.x;
    int c4 = threadIdx.x;
    float a = alpha[e];
    int s = src[e], d = dst[e];
    ushort4 hv = reinterpret_cast<const ushort4*>(h + (size_t)s * 256)[c4];
    ushort4 ev = reinterpret_cast<const ushort4*>(ef + (size_t)e * 256)[c4];
    float* op = outb + (size_t)d * 256 + c4 * 4;
    atomicAdd(op + 0, a * (b2f(hv.x) + b2f(ev.x)));
    atomicAdd(op + 1, a * (b2f(hv.y) + b2f(ev.y)));
    atomicAdd(op + 2, a * (b2f(hv.z) + b2f(ev.z)));
    atomicAdd(op + 3, a * (b2f(hv.w) + b2f(ev.w)));
}

__global__ void k_pe(const int* __restrict__ pm, const float* __restrict__ outb,
                     const float* __restrict__ denom, unsigned short* __restrict__ pe)
{
    int p = blockIdx.x, c = threadIdx.x;
    int n = pm[p];
    pe[(size_t)p * 256 + c] = f2b(outb[(size_t)n * 256 + c] / (denom[n] + 1e-16f));
}

__global__ __launch_bounds__(256) void k_final(const float* __restrict__ c1, const float* __restrict__ Wc2,
                                               const float* __restrict__ bc2, float* __restrict__ out)
{
    int lane = threadIdx.x & 63;
    int row = blockIdx.x * 4 + (threadIdx.x >> 6);
    if (row >= PP) return;
    float s = 0.f;
    for (int c = lane; c < 128; c += 64) s += c1[(size_t)row * 128 + c] * Wc2[c];
#pragma unroll
    for (int off = 32; off > 0; off >>= 1) s += __shfl_xor(s, off);
    if (lane == 0) out[row] = 1.f / (1.f + expf(-(s + bc2[0])));
}

// ---------------- host ----------------

extern "C" void kernel_launch(void* const* d_in, const int* in_sizes, int n_in,
                              void* d_out, int out_size, void* d_ws, size_t ws_size,
                              hipStream_t stream)
{
    (void)in_sizes; (void)n_in; (void)out_size;
    const float* nf    = (const float*)d_in[0];
    const int*   ei    = (const int*)  d_in[1];
    const float* ea    = (const float*)d_in[2];
    const float* t     = (const float*)d_in[3];
    const int*   pm    = (const int*)  d_in[4];
    const float* wt    = (const float*)d_in[5];
    const float* bt    = (const float*)d_in[6];
    const float* Wm1   = (const float*)d_in[7];
    const float* bm1   = (const float*)d_in[8];
    const float* Wm2   = (const float*)d_in[9];
    const float* bm2   = (const float*)d_in[10];
    const float* Wi    = (const float*)d_in[11];
    const float* Wh    = (const float*)d_in[12];
    const float* bi    = (const float*)d_in[13];
    const float* bh    = (const float*)d_in[14];
    const float* Wg    = (const float*)d_in[15];
    const float* We    = (const float*)d_in[16];
    const float* a_src = (const float*)d_in[17];
    const float* a_dst = (const float*)d_in[18];
    const float* a_e   = (const float*)d_in[19];
    const float* Wc1   = (const float*)d_in[20];
    const float* bc1   = (const float*)d_in[21];
    const float* Wc2   = (const float*)d_in[22];
    const float* bc2   = (const float*)d_in[23];
    float* outp = (float*)d_out;
    const int* src = ei;
    const int* dst = ei + EE;

    char* base = (char*)d_ws;
    size_t off = 0;
    auto alloc = [&](size_t bytes) -> void* {
        void* p = base + off;
        off = (off + bytes + 255) & ~(size_t)255;
        return p;
    };
    typedef unsigned short us;
    int* rank      = (int*)alloc((size_t)EE * 4);
    int* rel       = (int*)alloc((size_t)EE * 4);
    int* cpos      = (int*)alloc((size_t)EE * 4);
    int* roundcnt  = (int*)alloc(64 * 4);
    int* roundlist = (int*)alloc((size_t)MAXR * EE * 4);
    int* bsum      = (int*)alloc(256 * 4);
    unsigned* tm   = (unsigned*)alloc(256);
    us* te_bf    = (us*)alloc((size_t)EE * 128 * 2);
    us* nf_bf    = (us*)alloc((size_t)NN * 256 * 2);
    us* ea_bf    = (us*)alloc((size_t)EE * 128 * 2);
    us* xpart_bf = (us*)alloc((size_t)EE * 256 * 2);
    float* memb  = (float*)alloc((size_t)NN * 256 * 4);
    us* memb_bf  = (us*)alloc((size_t)NN * 256 * 2);
    us* Wt_x = (us*)alloc((size_t)256 * 512 * 2);
    us* Wt_a = (us*)alloc((size_t)256 * 256 * 2);
    us* Wt_m2= (us*)alloc((size_t)256 * 256 * 2);
    us* Wt_i = (us*)alloc((size_t)768 * 256 * 2);
    us* Wt_h = (us*)alloc((size_t)768 * 256 * 2);
    us* Wt_g = (us*)alloc((size_t)256 * 512 * 2);
    us* Wt_e = (us*)alloc((size_t)256 * 256 * 2);
    us* Wt_c = (us*)alloc((size_t)128 * 256 * 2);
    float* gvec  = (float*)alloc(256 * 4);
    float* sdot  = (float*)alloc((size_t)NN * 4);
    float* ddot  = (float*)alloc((size_t)NN * 4);
    float* edot  = (float*)alloc((size_t)EE * 4);
    float* logit = (float*)alloc((size_t)EE * 4);
    float* alpha = (float*)alloc((size_t)EE * 4);
    unsigned* mx = (unsigned*)alloc((size_t)NN * 4);
    float* denom = (float*)alloc((size_t)NN * 4);

    size_t region = (ws_size > off + 4096) ? (ws_size - off - 4096) : 0;
    long capL = (long)(region / 4104);
    int CAPR = (int)(capL < 0 ? 0 : capL);
    CAPR = (CAPR / 128) * 128;
    if (CAPR > 20480) CAPR = 20480;
    if (CAPR < 6400) return;  // ws too small (h_bf alias needs CAPR*4104 >= NN*512)
    us* xbuf_bf = (us*)alloc((size_t)CAPR * 256 * 2);
    us* msg_bf  = (us*)alloc((size_t)CAPR * 256 * 2);
    us* gi_bf   = (us*)alloc((size_t)CAPR * 768 * 2);
    us* gh_bf   = (us*)alloc((size_t)CAPR * 768 * 2);
    int* srcrow = (int*)alloc((size_t)CAPR * 4);
    if (off > ws_size) return;

    // bucket-sort scratch aliases roundlist (dead until k_insert runs)
    int* hist  = roundlist;            // NB ints
    int* hbase = roundlist + NB;       // NB ints
    int* hcur  = roundlist + 2 * NB;   // NB ints
    int* blist = roundlist + 3 * NB;   // EE ints  (3*65536+40000 < 12*EE)
    // per-src lists alias gi/gh chunk region (dead until first scan GEMM)
    int* slist = (int*)gi_bf;          // NN*SCAP ints = 3.2MB <= CAPR*1536B
    int* scnt  = (int*)gh_bf;          // NN ints

    us* h_bf  = xbuf_bf;               // alias: chunk region dead post-scan
    us* ef_bf = xpart_bf;              // alias: xpart dead post-scan
    float* outb = memb;                // alias: f32 mem dead post-scan
    us* pe_bf = te_bf;                 // alias: te dead after ef GEMM
    float* c1 = (float*)(te_bf + (size_t)PP * 256);

    hipMemsetAsync(roundcnt, 0, 64 * 4, stream);
    hipMemsetAsync(hist, 0, (size_t)NB * 4, stream);
    hipMemsetAsync(hcur, 0, (size_t)NB * 4, stream);
    hipMemsetAsync(scnt, 0, (size_t)NN * 4, stream);
    hipMemsetAsync(tm, 0, 4, stream);
    hipMemsetAsync(memb, 0, (size_t)NN * 256 * 4, stream);
    hipMemsetAsync(memb_bf, 0, (size_t)NN * 256 * 2, stream);
    hipMemsetAsync(mx, 0, (size_t)NN * 4, stream);
    hipMemsetAsync(denom, 0, (size_t)NN * 4, stream);

    const dim3 B(256);
    const int gE = (EE + 255) / 256;

    // ---- ordering (bucket counting-sort) ----
    k_hist<<<gE, B, 0, stream>>>(t, hist);
    k_scan1<<<256, B, 0, stream>>>(hist, hbase, bsum);
    k_scan2<<<1, B, 0, stream>>>(bsum);
    k_scan3<<<256, B, 0, stream>>>(hbase, bsum);
    k_bscatter<<<gE, B, 0, stream>>>(t, hbase, hcur, blist);
    k_rank2<<<gE, B, 0, stream>>>(t, hbase, hist, blist, rank);
    k_tmax<<<gE, B, 0, stream>>>(t, tm);

    // ---- chain decomposition (per-src lists) ----
    k_slist<<<gE, B, 0, stream>>>(src, scnt, slist);
    k_chain2<<<gE, B, 0, stream>>>(src, rank, scnt, slist, rel, cpos);
    k_insert<<<gE, B, 0, stream>>>(rel, cpos, roundcnt, roundlist);

    k_te<<<(EE * 128) / 256, B, 0, stream>>>(t, wt, bt, te_bf);
    k_cvt<<<(NN * 256 / 4 + 255) / 256, B, 0, stream>>>(nf, nf_bf, NN * 256 / 4);
    k_cvt<<<(EE * 128 / 4 + 255) / 256, B, 0, stream>>>(ea, ea_bf, EE * 128 / 4);

    auto wtl = [&](const float* W, us* Wt, int K, int N, int koff, int Ktot) {
        k_wt<<<(K * N + 255) / 256, B, 0, stream>>>(W, Wt, K, N, koff, Ktot);
    };
    wtl(Wm1, Wt_x, 256, 256, 0, 512);
    wtl(Wm1 + (size_t)512 * 256, Wt_x, 128, 256, 256, 512);
    wtl(Wm1 + (size_t)640 * 256, Wt_x, 128, 256, 384, 512);
    wtl(Wm1 + (size_t)256 * 256, Wt_a, 256, 256, 0, 256);
    wtl(Wm2, Wt_m2, 256, 256, 0, 256);
    wtl(Wi, Wt_i, 256, 768, 0, 256);
    wtl(Wh, Wt_h, 256, 768, 0, 256);
    wtl(Wg, Wt_g, 512, 256, 0, 512);
    wtl(We, Wt_e, 256, 256, 0, 256);
    wtl(Wc1, Wt_c, 256, 128, 0, 256);

    const int gxE = (EE + 127) / 128;
    k_mgemm<<<dim3(gxE, 4), B, 0, stream>>>(nf_bf, 256, src, ea_bf, 128, te_bf, 128,
        Wt_x, 512, bm1, nullptr, nullptr, nullptr, xpart_bf, 256, EE, nullptr, 0, 0);

    for (int j = 0; j < 2; ++j) {
        int bound = EE / (j + 1);
        for (int cb = 0; cb < bound; cb += CAPR) {
            int m = bound - cb; if (m > CAPR) m = CAPR;
            int gx = (m + 127) / 128;
            k_srcfill<<<(m + 255) / 256, B, 0, stream>>>(j, cb, m, roundlist, roundcnt, src, srcrow);
            k_mgemm<<<dim3(gx, 4), B, 0, stream>>>(memb_bf, 256, srcrow, nullptr, 0, nullptr, 0,
                Wt_a, 256, nullptr, xpart_bf, roundlist + (size_t)j * EE + cb,
                nullptr, xbuf_bf, 256, m, roundcnt + j, cb, 1);
            k_mgemm<<<dim3(gx, 4), B, 0, stream>>>(xbuf_bf, 256, nullptr, nullptr, 0, nullptr, 0,
                Wt_m2, 256, bm2, nullptr, nullptr, nullptr, msg_bf, 256, m, roundcnt + j, cb, 1);
            k_mgemm<<<dim3(gx, 12), B, 0, stream>>>(msg_bf, 256, nullptr, nullptr, 0, nullptr, 0,
                Wt_i, 256, bi, nullptr, nullptr, nullptr, gi_bf, 768, m, roundcnt + j, cb, 0);
            k_mgemm<<<dim3(gx, 12), B, 0, stream>>>(memb_bf, 256, srcrow, nullptr, 0, nullptr, 0,
                Wt_h, 256, bh, nullptr, nullptr, nullptr, gh_bf, 768, m, roundcnt + j, cb, 0);
            k_gru<<<m, B, 0, stream>>>(roundcnt + j, cb, m, srcrow, gi_bf, gh_bf, memb, memb_bf);
        }
    }
    for (int j = 2; j < MAXR; ++j) {
        int bound = (EE + j) / (j + 1);
        k_tail<<<bound, B, 0, stream>>>(j, roundcnt, roundlist, src, xpart_bf, memb, memb_bf,
                                        Wm1, Wm2, bm2, Wi, Wh, bi, bh);
    }

    k_gvec<<<1, B, 0, stream>>>(tm, wt, bt, Wg, gvec);
    const int gxN = (NN + 127) / 128;
    k_mgemm<<<dim3(gxN, 4), B, 0, stream>>>(nf_bf, 256, nullptr, memb_bf, 256, nullptr, 0,
        Wt_g, 512, gvec, nullptr, nullptr, nullptr, h_bf, 256, NN, nullptr, 0, 0);

    k_mgemm<<<dim3(gxE, 4), B, 0, stream>>>(ea_bf, 128, nullptr, te_bf, 128, nullptr, 0,
        Wt_e, 256, nullptr, nullptr, nullptr, nullptr, ef_bf, 256, EE, nullptr, 0, 0);

    hipMemsetAsync(outb, 0, (size_t)NN * 256 * 4, stream);

    k_dots2<<<(NN + 3) / 4, B, 0, stream>>>(h_bf, NN, a_src, a_dst, sdot, ddot);
    k_dots2<<<(EE + 3) / 4, B, 0, stream>>>(ef_bf, EE, a_e, nullptr, edot, nullptr);

    k_logitmax<<<gE, B, 0, stream>>>(sdot, ddot, edot, src, dst, logit, mx);
    k_alpha<<<gE, B, 0, stream>>>(logit, dst, mx, alpha, denom);
    k_scatter<<<EE, dim3(64), 0, stream>>>(alpha, src, dst, h_bf, ef_bf, outb);

    k_pe<<<PP, B, 0, stream>>>(pm, outb, denom, pe_bf);
    k_mgemm<<<dim3((PP + 127) / 128, 2), B, 0, stream>>>(pe_bf, 256, nullptr, nullptr, 0, nullptr, 0,
        Wt_c, 256, bc1, nullptr, nullptr, c1, nullptr, 128, PP, nullptr, 0, 1);
    k_final<<<(PP + 3) / 4, B, 0, stream>>>(c1, Wc2, bc2, outp);
}

// Round 4
// 1032.520 us; speedup vs baseline: 2.9764x; 1.1729x over previous
//
#include <hip/hip_runtime.h>

#define NN 50000
#define EE 40000
#define PP 4096
#define MAXR 12
#define SCAP 16
#define NB 65536

typedef __attribute__((ext_vector_type(8))) short bf8v;
typedef __attribute__((ext_vector_type(4))) float f4v;

__device__ __forceinline__ unsigned short f2b(float x) {
    unsigned u = __float_as_uint(x);
    u = (u + 0x7fffu + ((u >> 16) & 1u)) >> 16;
    return (unsigned short)u;
}
__device__ __forceinline__ float b2f(unsigned short h) {
    return __uint_as_float(((unsigned)h) << 16);
}
__device__ __forceinline__ unsigned fkey(float f) {
    unsigned u = __float_as_uint(f);
    return (u & 0x80000000u) ? ~u : (u | 0x80000000u);
}
__device__ __forceinline__ float funkey(unsigned k) {
    unsigned u = (k & 0x80000000u) ? (k & 0x7fffffffu) : ~k;
    return __uint_as_float(u);
}
__device__ __forceinline__ int bucket_of(float tv) {
    int b = (int)(tv * 65536.0f);
    if (b < 0) b = 0;
    if (b > 65535) b = 65535;
    return b;
}
// relu on 2 packed bf16
__device__ __forceinline__ unsigned relu2bf(unsigned u) {
    unsigned lo = (u & 0x8000u) ? 0u : (u & 0xFFFFu);
    unsigned hi = (u & 0x80000000u) ? 0u : (u & 0xFFFF0000u);
    return lo | hi;
}

// ---------------- ordering: bucket counting-sort rank ----------------

__global__ void k_hist(const float* __restrict__ t, int* __restrict__ hist)
{
    int e = blockIdx.x * 256 + threadIdx.x;
    if (e >= EE) return;
    atomicAdd(&hist[bucket_of(t[e])], 1);
}

__global__ void k_scan1(const int* __restrict__ hist, int* __restrict__ hbase, int* __restrict__ bsum)
{
    __shared__ int s[256];
    int i = blockIdx.x * 256 + threadIdx.x;
    int v = hist[i];
    s[threadIdx.x] = v;
    __syncthreads();
    for (int o = 1; o < 256; o <<= 1) {
        int x = (threadIdx.x >= o) ? s[threadIdx.x - o] : 0;
        __syncthreads();
        s[threadIdx.x] += x;
        __syncthreads();
    }
    hbase[i] = s[threadIdx.x] - v;
    if (threadIdx.x == 255) bsum[blockIdx.x] = s[255];
}

__global__ void k_scan2(int* __restrict__ bsum)
{
    __shared__ int s[256];
    int v = bsum[threadIdx.x];
    s[threadIdx.x] = v;
    __syncthreads();
    for (int o = 1; o < 256; o <<= 1) {
        int x = (threadIdx.x >= o) ? s[threadIdx.x - o] : 0;
        __syncthreads();
        s[threadIdx.x] += x;
        __syncthreads();
    }
    bsum[threadIdx.x] = s[threadIdx.x] - v;
}

__global__ void k_scan3(int* __restrict__ hbase, const int* __restrict__ bsum)
{
    int i = blockIdx.x * 256 + threadIdx.x;
    hbase[i] += bsum[blockIdx.x];
}

__global__ void k_bscatter(const float* __restrict__ t, const int* __restrict__ hbase,
                           int* __restrict__ hcur, int* __restrict__ blist)
{
    int e = blockIdx.x * 256 + threadIdx.x;
    if (e >= EE) return;
    int b = bucket_of(t[e]);
    int p = hbase[b] + atomicAdd(&hcur[b], 1);
    blist[p] = e;
}

__global__ void k_rank2(const float* __restrict__ t, const int* __restrict__ hbase,
                        const int* __restrict__ hist, const int* __restrict__ blist,
                        int* __restrict__ rank)
{
    int e = blockIdx.x * 256 + threadIdx.x;
    if (e >= EE) return;
    float te_ = t[e];
    int b = bucket_of(te_);
    int base = hbase[b], cnt = hist[b];
    int r = base;
    for (int i = 0; i < cnt; ++i) {
        int j = blist[base + i];
        float tj = t[j];
        r += (tj < te_ || (tj == te_ && j < e)) ? 1 : 0;
    }
    rank[e] = r;
}

__global__ void k_tmax(const float* __restrict__ t, unsigned* __restrict__ tm)
{
    int i = blockIdx.x * 256 + threadIdx.x;
    float v = (i < EE) ? t[i] : 0.f;
#pragma unroll
    for (int o = 32; o > 0; o >>= 1) v = fmaxf(v, __shfl_xor(v, o));
    if ((threadIdx.x & 63) == 0) atomicMax(tm, fkey(v));
}

// ---------------- chain decomposition via per-src lists ----------------

__global__ void k_slist(const int* __restrict__ src, int* __restrict__ scnt, int* __restrict__ slist)
{
    int e = blockIdx.x * 256 + threadIdx.x;
    if (e >= EE) return;
    int s = src[e];
    int slot = atomicAdd(&scnt[s], 1);
    if (slot < SCAP) slist[s * SCAP + slot] = e;
}

__global__ void k_chain2(const int* __restrict__ src, const int* __restrict__ rank,
                         const int* __restrict__ scnt, const int* __restrict__ slist,
                         int* __restrict__ rel, int* __restrict__ cpos)
{
    int e = blockIdx.x * 256 + threadIdx.x;
    if (e >= EE) return;
    int s = src[e];
    int c = scnt[s]; if (c > SCAP) c = SCAP;
    int re = rank[e], be = re / 200;
    bool r_e = true;
    for (int i = 0; i < c; ++i) {
        int rj = rank[slist[s * SCAP + i]];
        if (rj / 200 == be && rj > re) { r_e = false; break; }
    }
    if (!r_e) { rel[e] = 0; return; }
    rel[e] = 1;
    int pos = 0;
    for (int i = 0; i < c; ++i) {
        int rj = rank[slist[s * SCAP + i]];
        if (rj >= re) continue;
        int bj = rj / 200;
        bool r_j = true;
        for (int k2 = 0; k2 < c; ++k2) {
            int rj2 = rank[slist[s * SCAP + k2]];
            if (rj2 / 200 == bj && rj2 > rj) { r_j = false; break; }
        }
        pos += r_j ? 1 : 0;
    }
    cpos[e] = pos;
}

__global__ void k_insert(const int* __restrict__ rel, const int* __restrict__ cpos,
                         int* __restrict__ roundcnt, int* __restrict__ roundlist)
{
    __shared__ int lcnt[MAXR];
    __shared__ int lbase[MAXR];
    int tid = threadIdx.x;
    if (tid < MAXR) lcnt[tid] = 0;
    __syncthreads();
    int e = blockIdx.x * 256 + tid;
    int pos = -1, slot = 0;
    if (e < EE && rel[e]) {
        int p = cpos[e];
        if (p < MAXR) { pos = p; slot = atomicAdd(&lcnt[p], 1); }
    }
    __syncthreads();
    if (tid < MAXR && lcnt[tid]) lbase[tid] = atomicAdd(&roundcnt[tid], lcnt[tid]);
    __syncthreads();
    if (pos >= 0) roundlist[(size_t)pos * EE + lbase[pos] + slot] = e;
}

// ---------------- conversions ----------------

__global__ void k_te(const float* __restrict__ t, const float* __restrict__ w,
                     const float* __restrict__ b, unsigned short* __restrict__ te)
{
    int idx = blockIdx.x * 256 + threadIdx.x;
    if (idx >= EE * 128) return;
    int e = idx >> 7, j = idx & 127;
    te[idx] = f2b(sinf(t[e] * w[j] + b[j]));
}

__global__ void k_cvt(const float* __restrict__ x, unsigned short* __restrict__ y, int n4)
{
    int i = blockIdx.x * 256 + threadIdx.x;
    if (i >= n4) return;
    float4 v = reinterpret_cast<const float4*>(x)[i];
    ushort4 o;
    o.x = f2b(v.x); o.y = f2b(v.y); o.z = f2b(v.z); o.w = f2b(v.w);
    reinterpret_cast<ushort4*>(y)[i] = o;
}

// fused weight transpose: Wt[n][koff+k] = bf16(W[k][n]) for 10 weight blocks
struct WtDesc { const float* W; unsigned short* dst; int K, N, koff, Ktot, off; };
struct WtAll { WtDesc d[10]; int total; };

__global__ void k_wtall(WtAll wa)
{
    int idx = blockIdx.x * 256 + threadIdx.x;
    if (idx >= wa.total) return;
#pragma unroll
    for (int i = 0; i < 10; ++i) {
        int lo = wa.d[i].off;
        int hi = lo + wa.d[i].K * wa.d[i].N;
        if (idx >= lo && idx < hi) {
            int local = idx - lo;
            int K = wa.d[i].K;
            int n = local / K, k = local % K;
            wa.d[i].dst[(size_t)n * wa.d[i].Ktot + wa.d[i].koff + k] =
                f2b(wa.d[i].W[(size_t)k * wa.d[i].N + n]);
            return;
        }
    }
}

// ---------------- MFMA GEMM ----------------
// out = ACT( [A1|A2|A3](rows, gathered on A1 via idx1, optional relu-on-load) @ Wt^T + bias + Cin )
__global__ __launch_bounds__(256) void k_mgemm(
    const unsigned short* __restrict__ A1, int K1, const int* __restrict__ idx1,
    const unsigned short* __restrict__ A2, int K2,
    const unsigned short* __restrict__ A3, int K3,
    const unsigned short* __restrict__ Wt, int Ktot,
    const float* __restrict__ bias,
    const unsigned short* __restrict__ Cin, const int* __restrict__ cidx,
    float* __restrict__ outF, unsigned short* __restrict__ outB, int ldc,
    int Mhost, const int* __restrict__ mdev, int mbase, int relu, int relua)
{
    int M = Mhost;
    if (mdev) {
        int avail = *mdev - mbase;
        if (avail < 0) avail = 0;
        if (avail < M) M = avail;
    }
    const int row0 = blockIdx.x * 128;
    if (row0 >= M) return;
    const int col0 = blockIdx.y * 64;

    __shared__ unsigned short As[128 * 64];
    __shared__ unsigned short Bs[64 * 64];

    const int tid = threadIdx.x;
    const int l = tid & 63;
    const int wv = tid >> 6;

    f4v acc[2][4];
#pragma unroll
    for (int i = 0; i < 2; ++i)
#pragma unroll
        for (int j = 0; j < 4; ++j) acc[i][j] = (f4v){0.f, 0.f, 0.f, 0.f};

    for (int k0 = 0; k0 < Ktot; k0 += 64) {
#pragma unroll
        for (int it = 0; it < 4; ++it) {
            int idx = tid + it * 256;
            int r = idx >> 3, q = idx & 7;
            int gk = k0 + q * 8;
            int grow = row0 + r;
            uint4 v = make_uint4(0u, 0u, 0u, 0u);
            if (grow < M) {
                const unsigned short* sp; int st, krel, ar = grow;
                if (gk < K1) { sp = A1; st = K1; krel = gk; if (idx1) ar = idx1[grow]; }
                else if (gk < K1 + K2) { sp = A2; st = K2; krel = gk - K1; }
                else { sp = A3; st = K3; krel = gk - K1 - K2; }
                v = *reinterpret_cast<const uint4*>(sp + (size_t)ar * st + krel);
                if (relua) { v.x = relu2bf(v.x); v.y = relu2bf(v.y); v.z = relu2bf(v.z); v.w = relu2bf(v.w); }
            }
            *reinterpret_cast<uint4*>(As + r * 64 + ((q ^ (r & 7)) << 3)) = v;
        }
#pragma unroll
        for (int it = 0; it < 2; ++it) {
            int idx = tid + it * 256;
            int c = idx >> 3, q = idx & 7;
            uint4 v = *reinterpret_cast<const uint4*>(Wt + (size_t)(col0 + c) * Ktot + k0 + q * 8);
            *reinterpret_cast<uint4*>(Bs + c * 64 + ((q ^ (c & 7)) << 3)) = v;
        }
        __syncthreads();
#pragma unroll
        for (int ks = 0; ks < 2; ++ks) {
            bf8v af[2], bf[4];
#pragma unroll
            for (int mf = 0; mf < 2; ++mf) {
                int r = wv * 32 + mf * 16 + (l & 15);
                int q = ks * 4 + (l >> 4);
                af[mf] = *reinterpret_cast<const bf8v*>(As + r * 64 + ((q ^ (r & 7)) << 3));
            }
#pragma unroll
            for (int nf = 0; nf < 4; ++nf) {
                int c = nf * 16 + (l & 15);
                int q = ks * 4 + (l >> 4);
                bf[nf] = *reinterpret_cast<const bf8v*>(Bs + c * 64 + ((q ^ (c & 7)) << 3));
            }
#pragma unroll
            for (int mf = 0; mf < 2; ++mf)
#pragma unroll
                for (int nf = 0; nf < 4; ++nf)
                    acc[mf][nf] = __builtin_amdgcn_mfma_f32_16x16x32_bf16(af[mf], bf[nf], acc[mf][nf], 0, 0, 0);
        }
        __syncthreads();
    }

#pragma unroll
    for (int mf = 0; mf < 2; ++mf) {
#pragma unroll
        for (int rr = 0; rr < 4; ++rr) {
            int row = row0 + wv * 32 + mf * 16 + ((l >> 4) * 4) + rr;
            if (row >= M) continue;
            size_t crow = 0;
            if (Cin) crow = (size_t)(cidx ? cidx[row] : row) * ldc;
#pragma unroll
            for (int nf = 0; nf < 4; ++nf) {
                int col = col0 + nf * 16 + (l & 15);
                float v = acc[mf][nf][rr];
                if (bias) v += bias[col];
                if (Cin) v += b2f(Cin[crow + col]);
                if (relu) v = fmaxf(v, 0.f);
                if (outF) outF[(size_t)row * ldc + col] = v;
                if (outB) outB[(size_t)row * ldc + col] = f2b(v);
            }
        }
    }
}

// ---------------- scan helpers ----------------

__global__ void k_srcfill(int j, int base, int m, const int* __restrict__ roundlist,
                          const int* __restrict__ roundcnt, const int* __restrict__ src,
                          int* __restrict__ srcrow)
{
    int i = blockIdx.x * 256 + threadIdx.x;
    if (i >= m) return;
    if (base + i >= roundcnt[j]) return;
    srcrow[i] = src[roundlist[(size_t)j * EE + base + i]];
}

// gh==nullptr -> round 0 (h_prev == 0): use bhv directly
__global__ void k_gru(const int* __restrict__ cnt, int base, int m, const int* __restrict__ srcrow,
                      const unsigned short* __restrict__ gi, const unsigned short* __restrict__ gh,
                      const float* __restrict__ bhv,
                      float* __restrict__ mem, unsigned short* __restrict__ mem_bf)
{
    int i = blockIdx.x;
    int avail = *cnt - base;
    if (i >= m || i >= avail) return;
    int c = threadIdx.x;
    int s = srcrow[i];
    float hp = mem[(size_t)s * 256 + c];
    float ir = b2f(gi[(size_t)i * 768 + c]);
    float iz = b2f(gi[(size_t)i * 768 + 256 + c]);
    float in_ = b2f(gi[(size_t)i * 768 + 512 + c]);
    float hr, hz, hn;
    if (gh) {
        hr = b2f(gh[(size_t)i * 768 + c]);
        hz = b2f(gh[(size_t)i * 768 + 256 + c]);
        hn = b2f(gh[(size_t)i * 768 + 512 + c]);
    } else {
        hr = bhv[c]; hz = bhv[256 + c]; hn = bhv[512 + c];
    }
    float r = 1.f / (1.f + expf(-(ir + hr)));
    float z = 1.f / (1.f + expf(-(iz + hz)));
    float n = tanhf(in_ + r * hn);
    float hnew = (1.f - z) * n + z * hp;
    mem[(size_t)s * 256 + c] = hnew;
    mem_bf[(size_t)s * 256 + c] = f2b(hnew);
}

// fused per-row pipeline for tiny rounds (j >= 4)
__global__ void k_tail(int j, const int* __restrict__ roundcnt, const int* __restrict__ roundlist,
                       const int* __restrict__ src, const unsigned short* __restrict__ xpart_bf,
                       float* __restrict__ mem, unsigned short* __restrict__ mem_bf,
                       const float* __restrict__ Wm1, const float* __restrict__ Wm2,
                       const float* __restrict__ bm2, const float* __restrict__ Wi,
                       const float* __restrict__ Wh, const float* __restrict__ bi,
                       const float* __restrict__ bh)
{
    int i = blockIdx.x;
    if (i >= roundcnt[j]) return;
    int e = roundlist[(size_t)j * EE + i];
    int s = src[e];
    int c = threadIdx.x;
    __shared__ float hs[256];
    __shared__ float xv[256];
    __shared__ float msgv[256];
    __shared__ float giv[768];
    __shared__ float ghv[768];
    hs[c] = mem[(size_t)s * 256 + c];
    __syncthreads();
    float a = b2f(xpart_bf[(size_t)e * 256 + c]);
    for (int k = 0; k < 256; ++k) a += hs[k] * Wm1[(size_t)(256 + k) * 256 + c];
    xv[c] = fmaxf(a, 0.f);
    __syncthreads();
    float m = bm2[c];
    for (int k = 0; k < 256; ++k) m += xv[k] * Wm2[(size_t)k * 256 + c];
    msgv[c] = fmaxf(m, 0.f);
    __syncthreads();
#pragma unroll
    for (int tpart = 0; tpart < 3; ++tpart) {
        int cc = c + tpart * 256;
        float gi_ = bi[cc], gh_ = bh[cc];
        for (int k = 0; k < 256; ++k) {
            gi_ += msgv[k] * Wi[(size_t)k * 768 + cc];
            gh_ += hs[k] * Wh[(size_t)k * 768 + cc];
        }
        giv[cc] = gi_;
        ghv[cc] = gh_;
    }
    __syncthreads();
    float r = 1.f / (1.f + expf(-(giv[c] + ghv[c])));
    float z = 1.f / (1.f + expf(-(giv[256 + c] + ghv[256 + c])));
    float n = tanhf(giv[512 + c] + r * ghv[512 + c]);
    float hnew = (1.f - z) * n + z * hs[c];
    mem[(size_t)s * 256 + c] = hnew;
    mem_bf[(size_t)s * 256 + c] = f2b(hnew);
}

// ---------------- attention / head ----------------

__global__ void k_gvec(const unsigned* __restrict__ tm, const float* __restrict__ w,
                       const float* __restrict__ b, const float* __restrict__ Wg,
                       float* __restrict__ gvec)
{
    float tmax = funkey(*tm);
    int c = threadIdx.x;
    float acc = 0.f;
    for (int k = 0; k < 128; ++k) acc += sinf(tmax * w[k] + b[k]) * Wg[(size_t)(512 + k) * 256 + c];
    gvec[c] = acc;
}

__global__ __launch_bounds__(256) void k_dots2(const unsigned short* __restrict__ X, int M,
                                               const float* __restrict__ v1, const float* __restrict__ v2,
                                               float* __restrict__ o1, float* __restrict__ o2)
{
    int lane = threadIdx.x & 63;
    int row = blockIdx.x * 4 + (threadIdx.x >> 6);
    if (row >= M) return;
    ushort4 q = reinterpret_cast<const ushort4*>(X + (size_t)row * 256)[lane];
    int c = lane * 4;
    float x0 = b2f(q.x), x1 = b2f(q.y), x2 = b2f(q.z), x3 = b2f(q.w);
    float s1 = x0 * v1[c] + x1 * v1[c + 1] + x2 * v1[c + 2] + x3 * v1[c + 3];
    float s2 = 0.f;
    if (v2) s2 = x0 * v2[c] + x1 * v2[c + 1] + x2 * v2[c + 2] + x3 * v2[c + 3];
#pragma unroll
    for (int off = 32; off > 0; off >>= 1) {
        s1 += __shfl_xor(s1, off);
        if (v2) s2 += __shfl_xor(s2, off);
    }
    if (lane == 0) {
        o1[row] = s1;
        if (v2) o2[row] = s2;
    }
}

__global__ void k_logitmax(const float* __restrict__ sdot, const float* __restrict__ ddot,
                           const float* __restrict__ edot, const int* __restrict__ src,
                           const int* __restrict__ dst, float* __restrict__ logit,
                           unsigned* __restrict__ mx)
{
    int e = blockIdx.x * 256 + threadIdx.x;
    if (e >= EE) return;
    float l = sdot[src[e]] + ddot[dst[e]] + edot[e];
    l = (l > 0.f) ? l : 0.2f * l;
    logit[e] = l;
    atomicMax(&mx[dst[e]], fkey(l));
}

__global__ void k_alpha(const float* __restrict__ logit, const int* __restrict__ dst,
                        const unsigned* __restrict__ mx, float* __restrict__ alpha,
                        float* __restrict__ denom)
{
    int e = blockIdx.x * 256 + threadIdx.x;
    if (e >= EE) return;
    int d = dst[e];
    float a = expf(logit[e] - funkey(mx[d]));
    alpha[e] = a;
    atomicAdd(&denom[d], a);
}

__global__ void k_scatter(const float* __restrict__ alpha, const int* __restrict__ src,
                          const int* __restrict__ dst, const unsigned short* __restrict__ h,
                          const unsigned short* __restrict__ ef, float* __restrict__ outb)
{
    int e = blockIdx.x;
    int c4 = threadIdx.x;
    float a = alpha[e];
    int s = src[e], d = dst[e];
    ushort4 hv = reinterpret_cast<const ushort4*>(h + (size_t)s * 256)[c4];
    ushort4 ev = reinterpret_cast<const ushort4*>(ef + (size_t)e * 256)[c4];
    float* op = outb + (size_t)d * 256 + c4 * 4;
    atomicAdd(op + 0, a * (b2f(hv.x) + b2f(ev.x)));
    atomicAdd(op + 1, a * (b2f(hv.y) + b2f(ev.y)));
    atomicAdd(op + 2, a * (b2f(hv.z) + b2f(ev.z)));
    atomicAdd(op + 3, a * (b2f(hv.w) + b2f(ev.w)));
}

__global__ void k_pe(const int* __restrict__ pm, const float* __restrict__ outb,
                     const float* __restrict__ denom, unsigned short* __restrict__ pe)
{
    int p = blockIdx.x, c = threadIdx.x;
    int n = pm[p];
    pe[(size_t)p * 256 + c] = f2b(outb[(size_t)n * 256 + c] / (denom[n] + 1e-16f));
}

__global__ __launch_bounds__(256) void k_final(const float* __restrict__ c1, const float* __restrict__ Wc2,
                                               const float* __restrict__ bc2, float* __restrict__ out)
{
    int lane = threadIdx.x & 63;
    int row = blockIdx.x * 4 + (threadIdx.x >> 6);
    if (row >= PP) return;
    float s = 0.f;
    for (int c = lane; c < 128; c += 64) s += c1[(size_t)row * 128 + c] * Wc2[c];
#pragma unroll
    for (int off = 32; off > 0; off >>= 1) s += __shfl_xor(s, off);
    if (lane == 0) out[row] = 1.f / (1.f + expf(-(s + bc2[0])));
}

// ---------------- host ----------------

extern "C" void kernel_launch(void* const* d_in, const int* in_sizes, int n_in,
                              void* d_out, int out_size, void* d_ws, size_t ws_size,
                              hipStream_t stream)
{
    (void)in_sizes; (void)n_in; (void)out_size;
    const float* nf    = (const float*)d_in[0];
    const int*   ei    = (const int*)  d_in[1];
    const float* ea    = (const float*)d_in[2];
    const float* t     = (const float*)d_in[3];
    const int*   pm    = (const int*)  d_in[4];
    const float* wt    = (const float*)d_in[5];
    const float* bt    = (const float*)d_in[6];
    const float* Wm1   = (const float*)d_in[7];
    const float* bm1   = (const float*)d_in[8];
    const float* Wm2   = (const float*)d_in[9];
    const float* bm2   = (const float*)d_in[10];
    const float* Wi    = (const float*)d_in[11];
    const float* Wh    = (const float*)d_in[12];
    const float* bi    = (const float*)d_in[13];
    const float* bh    = (const float*)d_in[14];
    const float* Wg    = (const float*)d_in[15];
    const float* We    = (const float*)d_in[16];
    const float* a_src = (const float*)d_in[17];
    const float* a_dst = (const float*)d_in[18];
    const float* a_e   = (const float*)d_in[19];
    const float* Wc1   = (const float*)d_in[20];
    const float* bc1   = (const float*)d_in[21];
    const float* Wc2   = (const float*)d_in[22];
    const float* bc2   = (const float*)d_in[23];
    float* outp = (float*)d_out;
    const int* src = ei;
    const int* dst = ei + EE;

    char* base = (char*)d_ws;
    size_t off = 0;
    auto alloc = [&](size_t bytes) -> void* {
        void* p = base + off;
        off = (off + bytes + 255) & ~(size_t)255;
        return p;
    };
    typedef unsigned short us;
    int* rank      = (int*)alloc((size_t)EE * 4);
    int* rel       = (int*)alloc((size_t)EE * 4);
    int* cpos      = (int*)alloc((size_t)EE * 4);
    int* roundcnt  = (int*)alloc(64 * 4);
    int* roundlist = (int*)alloc((size_t)MAXR * EE * 4);
    int* bsum      = (int*)alloc(256 * 4);
    unsigned* tm   = (unsigned*)alloc(256);
    us* te_bf    = (us*)alloc((size_t)EE * 128 * 2);
    us* nf_bf    = (us*)alloc((size_t)NN * 256 * 2);
    us* ea_bf    = (us*)alloc((size_t)EE * 128 * 2);
    us* xpart_bf = (us*)alloc((size_t)EE * 256 * 2);
    float* memb  = (float*)alloc((size_t)NN * 256 * 4);
    us* memb_bf  = (us*)alloc((size_t)NN * 256 * 2);
    us* Wt_x = (us*)alloc((size_t)256 * 512 * 2);
    us* Wt_a = (us*)alloc((size_t)256 * 256 * 2);
    us* Wt_m2= (us*)alloc((size_t)256 * 256 * 2);
    us* Wt_i = (us*)alloc((size_t)768 * 256 * 2);
    us* Wt_h = (us*)alloc((size_t)768 * 256 * 2);
    us* Wt_g = (us*)alloc((size_t)256 * 512 * 2);
    us* Wt_e = (us*)alloc((size_t)256 * 256 * 2);
    us* Wt_c = (us*)alloc((size_t)128 * 256 * 2);
    float* gvec  = (float*)alloc(256 * 4);
    float* sdot  = (float*)alloc((size_t)NN * 4);
    float* ddot  = (float*)alloc((size_t)NN * 4);
    float* edot  = (float*)alloc((size_t)EE * 4);
    float* logit = (float*)alloc((size_t)EE * 4);
    float* alpha = (float*)alloc((size_t)EE * 4);
    unsigned* mx = (unsigned*)alloc((size_t)NN * 4);
    float* denom = (float*)alloc((size_t)NN * 4);

    size_t region = (ws_size > off + 4096) ? (ws_size - off - 4096) : 0;
    long capL = (long)(region / 4104);
    int CAPR = (int)(capL < 0 ? 0 : capL);
    CAPR = (CAPR / 128) * 128;
    if (CAPR > 28160) CAPR = 28160;   // covers round 0 (<= ~27.6k rows) in one chunk
    if (CAPR < 6400) return;          // ws too small (h_bf alias needs CAPR*4104 >= NN*512)
    us* xbuf_bf = (us*)alloc((size_t)CAPR * 256 * 2);
    us* msg_bf  = (us*)alloc((size_t)CAPR * 256 * 2);
    us* gi_bf   = (us*)alloc((size_t)CAPR * 768 * 2);
    us* gh_bf   = (us*)alloc((size_t)CAPR * 768 * 2);
    int* srcrow = (int*)alloc((size_t)CAPR * 4);
    if (off > ws_size) return;

    // bucket-sort scratch aliases roundlist (dead until k_insert runs)
    int* hist  = roundlist;            // NB ints
    int* hbase = roundlist + NB;       // NB ints
    int* hcur  = roundlist + 2 * NB;   // NB ints
    int* blist = roundlist + 3 * NB;   // EE ints  (3*65536+40000 < 12*EE)
    // per-src lists alias gi/gh chunk region (dead until first gi GEMM)
    int* slist = (int*)gi_bf;          // NN*SCAP ints = 3.2MB
    int* scnt  = (int*)gh_bf;          // NN ints

    us* h_bf  = xbuf_bf;               // alias: chunk region dead post-scan
    us* ef_bf = xpart_bf;              // alias: xpart dead post-scan
    float* outb = memb;                // alias: f32 mem dead post-scan
    us* pe_bf = te_bf;                 // alias: te dead after ef GEMM
    float* c1 = (float*)(te_bf + (size_t)PP * 256);

    hipMemsetAsync(roundcnt, 0, 64 * 4, stream);
    hipMemsetAsync(hist, 0, (size_t)NB * 4, stream);
    hipMemsetAsync(hcur, 0, (size_t)NB * 4, stream);
    hipMemsetAsync(scnt, 0, (size_t)NN * 4, stream);
    hipMemsetAsync(tm, 0, 4, stream);
    hipMemsetAsync(memb, 0, (size_t)NN * 256 * 4, stream);
    hipMemsetAsync(memb_bf, 0, (size_t)NN * 256 * 2, stream);
    hipMemsetAsync(mx, 0, (size_t)NN * 4, stream);
    hipMemsetAsync(denom, 0, (size_t)NN * 4, stream);

    const dim3 B(256);
    const int gE = (EE + 255) / 256;

    // ---- ordering (bucket counting-sort) ----
    k_hist<<<gE, B, 0, stream>>>(t, hist);
    k_scan1<<<256, B, 0, stream>>>(hist, hbase, bsum);
    k_scan2<<<1, B, 0, stream>>>(bsum);
    k_scan3<<<256, B, 0, stream>>>(hbase, bsum);
    k_bscatter<<<gE, B, 0, stream>>>(t, hbase, hcur, blist);
    k_rank2<<<gE, B, 0, stream>>>(t, hbase, hist, blist, rank);
    k_tmax<<<gE, B, 0, stream>>>(t, tm);

    // ---- chain decomposition (per-src lists) ----
    k_slist<<<gE, B, 0, stream>>>(src, scnt, slist);
    k_chain2<<<gE, B, 0, stream>>>(src, rank, scnt, slist, rel, cpos);
    k_insert<<<gE, B, 0, stream>>>(rel, cpos, roundcnt, roundlist);

    k_te<<<(EE * 128) / 256, B, 0, stream>>>(t, wt, bt, te_bf);
    k_cvt<<<(NN * 256 / 4 + 255) / 256, B, 0, stream>>>(nf, nf_bf, NN * 256 / 4);
    k_cvt<<<(EE * 128 / 4 + 255) / 256, B, 0, stream>>>(ea, ea_bf, EE * 128 / 4);

    // ---- fused weight transposes (10 blocks, 1 launch) ----
    {
        WtAll wa;
        int o = 0;
        auto set = [&](int i, const float* W, us* dst, int K, int N, int koff, int Ktot) {
            wa.d[i] = WtDesc{W, dst, K, N, koff, Ktot, o};
            o += K * N;
        };
        set(0, Wm1, Wt_x, 256, 256, 0, 512);
        set(1, Wm1 + (size_t)512 * 256, Wt_x, 128, 256, 256, 512);
        set(2, Wm1 + (size_t)640 * 256, Wt_x, 128, 256, 384, 512);
        set(3, Wm1 + (size_t)256 * 256, Wt_a, 256, 256, 0, 256);
        set(4, Wm2, Wt_m2, 256, 256, 0, 256);
        set(5, Wi, Wt_i, 256, 768, 0, 256);
        set(6, Wh, Wt_h, 256, 768, 0, 256);
        set(7, Wg, Wt_g, 512, 256, 0, 512);
        set(8, We, Wt_e, 256, 256, 0, 256);
        set(9, Wc1, Wt_c, 256, 128, 0, 256);
        wa.total = o;
        k_wtall<<<(o + 255) / 256, B, 0, stream>>>(wa);
    }

    const int gxE = (EE + 127) / 128;
    k_mgemm<<<dim3(gxE, 4), B, 0, stream>>>(nf_bf, 256, src, ea_bf, 128, te_bf, 128,
        Wt_x, 512, bm1, nullptr, nullptr, nullptr, xpart_bf, 256, EE, nullptr, 0, 0, 0);

    // ---- chain rounds 0..3 via MFMA GEMMs ----
    for (int j = 0; j < 4; ++j) {
        int bound = EE / (j + 1);
        for (int cb = 0; cb < bound; cb += CAPR) {
            int m = bound - cb; if (m > CAPR) m = CAPR;
            int gx = (m + 127) / 128;
            const int* rl = roundlist + (size_t)j * EE + cb;
            k_srcfill<<<(m + 255) / 256, B, 0, stream>>>(j, cb, m, roundlist, roundcnt, src, srcrow);
            if (j == 0) {
                // h_prev == 0: msg = relu(relu(xpart[e]) @ Wm2 + bm2); gh = bh
                k_mgemm<<<dim3(gx, 4), B, 0, stream>>>(xpart_bf, 256, rl, nullptr, 0, nullptr, 0,
                    Wt_m2, 256, bm2, nullptr, nullptr, nullptr, msg_bf, 256, m, roundcnt + j, cb, 1, 1);
                k_mgemm<<<dim3(gx, 12), B, 0, stream>>>(msg_bf, 256, nullptr, nullptr, 0, nullptr, 0,
                    Wt_i, 256, bi, nullptr, nullptr, nullptr, gi_bf, 768, m, roundcnt + j, cb, 0, 0);
                k_gru<<<m, B, 0, stream>>>(roundcnt + j, cb, m, srcrow, gi_bf, nullptr, bh, memb, memb_bf);
            } else {
                k_mgemm<<<dim3(gx, 4), B, 0, stream>>>(memb_bf, 256, srcrow, nullptr, 0, nullptr, 0,
                    Wt_a, 256, nullptr, xpart_bf, rl, nullptr, xbuf_bf, 256, m, roundcnt + j, cb, 1, 0);
                k_mgemm<<<dim3(gx, 4), B, 0, stream>>>(xbuf_bf, 256, nullptr, nullptr, 0, nullptr, 0,
                    Wt_m2, 256, bm2, nullptr, nullptr, nullptr, msg_bf, 256, m, roundcnt + j, cb, 1, 0);
                k_mgemm<<<dim3(gx, 12), B, 0, stream>>>(msg_bf, 256, nullptr, nullptr, 0, nullptr, 0,
                    Wt_i, 256, bi, nullptr, nullptr, nullptr, gi_bf, 768, m, roundcnt + j, cb, 0, 0);
                k_mgemm<<<dim3(gx, 12), B, 0, stream>>>(memb_bf, 256, srcrow, nullptr, 0, nullptr, 0,
                    Wt_h, 256, bh, nullptr, nullptr, nullptr, gh_bf, 768, m, roundcnt + j, cb, 0, 0);
                k_gru<<<m, B, 0, stream>>>(roundcnt + j, cb, m, srcrow, gi_bf, gh_bf, bh, memb, memb_bf);
            }
        }
    }
    // tiny rounds: scalar per-row tail
    for (int j = 4; j < MAXR; ++j) {
        int bound = (EE + j) / (j + 1);
        k_tail<<<bound, B, 0, stream>>>(j, roundcnt, roundlist, src, xpart_bf, memb, memb_bf,
                                        Wm1, Wm2, bm2, Wi, Wh, bi, bh);
    }

    k_gvec<<<1, B, 0, stream>>>(tm, wt, bt, Wg, gvec);
    const int gxN = (NN + 127) / 128;
    k_mgemm<<<dim3(gxN, 4), B, 0, stream>>>(nf_bf, 256, nullptr, memb_bf, 256, nullptr, 0,
        Wt_g, 512, gvec, nullptr, nullptr, nullptr, h_bf, 256, NN, nullptr, 0, 0, 0);

    k_mgemm<<<dim3(gxE, 4), B, 0, stream>>>(ea_bf, 128, nullptr, te_bf, 128, nullptr, 0,
        Wt_e, 256, nullptr, nullptr, nullptr, nullptr, ef_bf, 256, EE, nullptr, 0, 0, 0);

    hipMemsetAsync(outb, 0, (size_t)NN * 256 * 4, stream);

    k_dots2<<<(NN + 3) / 4, B, 0, stream>>>(h_bf, NN, a_src, a_dst, sdot, ddot);
    k_dots2<<<(EE + 3) / 4, B, 0, stream>>>(ef_bf, EE, a_e, nullptr, edot, nullptr);

    k_logitmax<<<gE, B, 0, stream>>>(sdot, ddot, edot, src, dst, logit, mx);
    k_alpha<<<gE, B, 0, stream>>>(logit, dst, mx, alpha, denom);
    k_scatter<<<EE, dim3(64), 0, stream>>>(alpha, src, dst, h_bf, ef_bf, outb);

    k_pe<<<PP, B, 0, stream>>>(pm, outb, denom, pe_bf);
    k_mgemm<<<dim3((PP + 127) / 128, 2), B, 0, stream>>>(pe_bf, 256, nullptr, nullptr, 0, nullptr, 0,
        Wt_c, 256, bc1, nullptr, nullptr, c1, nullptr, 128, PP, nullptr, 0, 1, 0);
    k_final<<<(PP + 3) / 4, B, 0, stream>>>(c1, Wc2, bc2, outp);
}

// Round 5
// 834.588 us; speedup vs baseline: 3.6823x; 1.2372x over previous
//
#include <hip/hip_runtime.h>

#define NN 50000
#define EE 40000
#define PP 4096
#define MAXR 12
#define SCAP 16
#define NB 65536

typedef unsigned short us;
typedef __attribute__((ext_vector_type(8))) short bf8v;
typedef __attribute__((ext_vector_type(4))) float f4v;

__device__ __forceinline__ us f2b(float x) {
    unsigned u = __float_as_uint(x);
    u = (u + 0x7fffu + ((u >> 16) & 1u)) >> 16;
    return (us)u;
}
__device__ __forceinline__ float b2f(us h) {
    return __uint_as_float(((unsigned)h) << 16);
}
__device__ __forceinline__ unsigned fkey(float f) {
    unsigned u = __float_as_uint(f);
    return (u & 0x80000000u) ? ~u : (u | 0x80000000u);
}
__device__ __forceinline__ float funkey(unsigned k) {
    unsigned u = (k & 0x80000000u) ? (k & 0x7fffffffu) : ~k;
    return __uint_as_float(u);
}
__device__ __forceinline__ int bucket_of(float tv) {
    int b = (int)(tv * 65536.0f);
    if (b < 0) b = 0;
    if (b > 65535) b = 65535;
    return b;
}
__device__ __forceinline__ unsigned relu2bf(unsigned u) {
    unsigned lo = (u & 0x8000u) ? 0u : (u & 0xFFFFu);
    unsigned hi = (u & 0x80000000u) ? 0u : (u & 0xFFFF0000u);
    return lo | hi;
}

// ---------------- needed-node mask / edge compaction ----------------

__global__ void k_need(const int* __restrict__ pm, int* __restrict__ needed)
{
    int i = blockIdx.x * 256 + threadIdx.x;
    if (i < PP) needed[pm[i]] = 1;
}

__global__ void k_elist(const int* __restrict__ dst, const int* __restrict__ needed,
                        int* __restrict__ necnt, int* __restrict__ eidx)
{
    int e = blockIdx.x * 256 + threadIdx.x;
    if (e >= EE) return;
    if (!needed[dst[e]]) return;
    eidx[atomicAdd(necnt, 1)] = e;
}

// ---------------- ordering prep: hist + per-src lists + tmax ----------------

__global__ __launch_bounds__(256) void k_prep(const float* __restrict__ t, const int* __restrict__ src,
                                              int* __restrict__ hist, int* __restrict__ scnt,
                                              int* __restrict__ slist, unsigned* __restrict__ tm)
{
    int e = blockIdx.x * 256 + threadIdx.x;
    float v = 0.f;
    if (e < EE) {
        float tv = t[e];
        v = tv;
        atomicAdd(&hist[bucket_of(tv)], 1);
        int s = src[e];
        int slot = atomicAdd(&scnt[s], 1);
        if (slot < SCAP) slist[s * SCAP + slot] = e;
    }
#pragma unroll
    for (int o = 32; o > 0; o >>= 1) v = fmaxf(v, __shfl_xor(v, o));
    if ((threadIdx.x & 63) == 0) atomicMax(tm, fkey(v));
}

__global__ void k_scan1(const int* __restrict__ hist, int* __restrict__ hbase, int* __restrict__ bsum)
{
    __shared__ int s[256];
    int i = blockIdx.x * 256 + threadIdx.x;
    int v = hist[i];
    s[threadIdx.x] = v;
    __syncthreads();
    for (int o = 1; o < 256; o <<= 1) {
        int x = (threadIdx.x >= o) ? s[threadIdx.x - o] : 0;
        __syncthreads();
        s[threadIdx.x] += x;
        __syncthreads();
    }
    hbase[i] = s[threadIdx.x] - v;
    if (threadIdx.x == 255) bsum[blockIdx.x] = s[255];
}

__global__ void k_scan2(int* __restrict__ bsum)
{
    __shared__ int s[256];
    int v = bsum[threadIdx.x];
    s[threadIdx.x] = v;
    __syncthreads();
    for (int o = 1; o < 256; o <<= 1) {
        int x = (threadIdx.x >= o) ? s[threadIdx.x - o] : 0;
        __syncthreads();
        s[threadIdx.x] += x;
        __syncthreads();
    }
    bsum[threadIdx.x] = s[threadIdx.x] - v;
}

__global__ void k_scan3(int* __restrict__ hbase, const int* __restrict__ bsum)
{
    int i = blockIdx.x * 256 + threadIdx.x;
    hbase[i] += bsum[blockIdx.x];
}

__global__ void k_bscatter(const float* __restrict__ t, const int* __restrict__ hbase,
                           int* __restrict__ hcur, int* __restrict__ blist)
{
    int e = blockIdx.x * 256 + threadIdx.x;
    if (e >= EE) return;
    int b = bucket_of(t[e]);
    int p = hbase[b] + atomicAdd(&hcur[b], 1);
    blist[p] = e;
}

__global__ void k_rank2(const float* __restrict__ t, const int* __restrict__ hbase,
                        const int* __restrict__ hist, const int* __restrict__ blist,
                        int* __restrict__ rank)
{
    int e = blockIdx.x * 256 + threadIdx.x;
    if (e >= EE) return;
    float te_ = t[e];
    int b = bucket_of(te_);
    int base = hbase[b], cnt = hist[b];
    int r = base;
    for (int i = 0; i < cnt; ++i) {
        int j = blist[base + i];
        float tj = t[j];
        r += (tj < te_ || (tj == te_ && j < e)) ? 1 : 0;
    }
    rank[e] = r;
}

// chain decomposition + round insert, fused
__global__ void k_chain(const int* __restrict__ src, const int* __restrict__ rank,
                        const int* __restrict__ scnt, const int* __restrict__ slist,
                        int* __restrict__ roundcnt, int* __restrict__ roundlist)
{
    __shared__ int lcnt[MAXR];
    __shared__ int lbase[MAXR];
    int tid = threadIdx.x;
    if (tid < MAXR) lcnt[tid] = 0;
    __syncthreads();
    int e = blockIdx.x * 256 + tid;
    int pos = -1, slot = 0;
    if (e < EE) {
        int s = src[e];
        int c = scnt[s]; if (c > SCAP) c = SCAP;
        int re = rank[e], be = re / 200;
        bool r_e = true;
        for (int i = 0; i < c; ++i) {
            int rj = rank[slist[s * SCAP + i]];
            if (rj / 200 == be && rj > re) { r_e = false; break; }
        }
        if (r_e) {
            int p = 0;
            for (int i = 0; i < c; ++i) {
                int rj = rank[slist[s * SCAP + i]];
                if (rj >= re) continue;
                int bj = rj / 200;
                bool r_j = true;
                for (int k2 = 0; k2 < c; ++k2) {
                    int rj2 = rank[slist[s * SCAP + k2]];
                    if (rj2 / 200 == bj && rj2 > rj) { r_j = false; break; }
                }
                p += r_j ? 1 : 0;
            }
            if (p < MAXR) { pos = p; slot = atomicAdd(&lcnt[p], 1); }
        }
    }
    __syncthreads();
    if (tid < MAXR && lcnt[tid]) lbase[tid] = atomicAdd(&roundcnt[tid], lcnt[tid]);
    __syncthreads();
    if (pos >= 0) roundlist[(size_t)pos * EE + lbase[pos] + slot] = e;
}

// ---------------- fused conversions: te(sin) + nf cvt + ea cvt ----------------

__global__ void k_conv(const float* __restrict__ t, const float* __restrict__ w,
                       const float* __restrict__ b, us* __restrict__ te,
                       const float* __restrict__ nf, us* __restrict__ nf_bf,
                       const float* __restrict__ ea, us* __restrict__ ea_bf)
{
    int idx = blockIdx.x * 256 + threadIdx.x;
    const int TEN = EE * 128, NF4 = NN * 64, EA4 = EE * 32;
    if (idx < TEN) {
        int e = idx >> 7, j = idx & 127;
        te[idx] = f2b(sinf(t[e] * w[j] + b[j]));
        return;
    }
    idx -= TEN;
    if (idx < NF4) {
        float4 v = reinterpret_cast<const float4*>(nf)[idx];
        ushort4 o; o.x = f2b(v.x); o.y = f2b(v.y); o.z = f2b(v.z); o.w = f2b(v.w);
        reinterpret_cast<ushort4*>(nf_bf)[idx] = o;
        return;
    }
    idx -= NF4;
    if (idx < EA4) {
        float4 v = reinterpret_cast<const float4*>(ea)[idx];
        ushort4 o; o.x = f2b(v.x); o.y = f2b(v.y); o.z = f2b(v.z); o.w = f2b(v.w);
        reinterpret_cast<ushort4*>(ea_bf)[idx] = o;
    }
}

// ---------------- fused weight transposes (+ gvec tail block) ----------------

struct WtDesc { const float* W; us* dst; int K, N, koff, Ktot, off; };
struct WtAll { WtDesc d[10]; int total; };

__global__ void k_wtall(WtAll wa, int nb, const unsigned* __restrict__ tm,
                        const float* __restrict__ wt, const float* __restrict__ bt,
                        const float* __restrict__ Wg, float* __restrict__ gvec)
{
    if ((int)blockIdx.x == nb) {
        __shared__ float sv[128];
        int c = threadIdx.x;
        float tmax = funkey(*tm);
        if (c < 128) sv[c] = sinf(tmax * wt[c] + bt[c]);
        __syncthreads();
        float acc = 0.f;
        for (int k = 0; k < 128; ++k) acc += sv[k] * Wg[(size_t)(512 + k) * 256 + c];
        gvec[c] = acc;
        return;
    }
    int idx = blockIdx.x * 256 + threadIdx.x;
    if (idx >= wa.total) return;
#pragma unroll
    for (int i = 0; i < 10; ++i) {
        int lo = wa.d[i].off;
        int hi = lo + wa.d[i].K * wa.d[i].N;
        if (idx >= lo && idx < hi) {
            int local = idx - lo;
            int K = wa.d[i].K;
            int n = local / K, k = local % K;
            wa.d[i].dst[(size_t)n * wa.d[i].Ktot + wa.d[i].koff + k] =
                f2b(wa.d[i].W[(size_t)k * wa.d[i].N + n]);
            return;
        }
    }
}

// ---------------- MFMA GEMM ----------------
// out = ACT( [A1|A2|A3](rows; A1/A2 with optional 1- or 2-level gather) @ Wt^T + bias + Cin )
__global__ __launch_bounds__(256) void k_mgemm(
    const us* __restrict__ A1, int K1, const int* __restrict__ idx1, const int* __restrict__ idx1b,
    const us* __restrict__ A2, int K2, const int* __restrict__ idx2,
    const us* __restrict__ A3, int K3,
    const us* __restrict__ Wt, int Kloop, int ldw,
    const float* __restrict__ bias,
    const us* __restrict__ Cin, const int* __restrict__ cidx,
    float* __restrict__ outF, us* __restrict__ outB, int ldc,
    int Mhost, const int* __restrict__ mdev, int mbase, int relu, int relua)
{
    int M = Mhost;
    if (mdev) {
        int avail = *mdev - mbase;
        if (avail < 0) avail = 0;
        if (avail < M) M = avail;
    }
    const int row0 = blockIdx.x * 128;
    if (row0 >= M) return;
    const int col0 = blockIdx.y * 64;

    __shared__ us As[128 * 64];
    __shared__ us Bs[64 * 64];

    const int tid = threadIdx.x;
    const int l = tid & 63;
    const int wv = tid >> 6;

    f4v acc[2][4];
#pragma unroll
    for (int i = 0; i < 2; ++i)
#pragma unroll
        for (int j = 0; j < 4; ++j) acc[i][j] = (f4v){0.f, 0.f, 0.f, 0.f};

    for (int k0 = 0; k0 < Kloop; k0 += 64) {
#pragma unroll
        for (int it = 0; it < 4; ++it) {
            int idx = tid + it * 256;
            int r = idx >> 3, q = idx & 7;
            int gk = k0 + q * 8;
            int grow = row0 + r;
            uint4 v = make_uint4(0u, 0u, 0u, 0u);
            if (grow < M) {
                const us* sp; int st, krel, ar = grow;
                if (gk < K1) {
                    sp = A1; st = K1; krel = gk;
                    if (idx1) { ar = idx1[ar]; if (idx1b) ar = idx1b[ar]; }
                } else if (gk < K1 + K2) {
                    sp = A2; st = K2; krel = gk - K1;
                    if (idx2) ar = idx2[ar];
                } else {
                    sp = A3; st = K3; krel = gk - K1 - K2;
                }
                v = *reinterpret_cast<const uint4*>(sp + (size_t)ar * st + krel);
                if (relua) { v.x = relu2bf(v.x); v.y = relu2bf(v.y); v.z = relu2bf(v.z); v.w = relu2bf(v.w); }
            }
            *reinterpret_cast<uint4*>(As + r * 64 + ((q ^ (r & 7)) << 3)) = v;
        }
#pragma unroll
        for (int it = 0; it < 2; ++it) {
            int idx = tid + it * 256;
            int c = idx >> 3, q = idx & 7;
            uint4 v = *reinterpret_cast<const uint4*>(Wt + (size_t)(col0 + c) * ldw + k0 + q * 8);
            *reinterpret_cast<uint4*>(Bs + c * 64 + ((q ^ (c & 7)) << 3)) = v;
        }
        __syncthreads();
#pragma unroll
        for (int ks = 0; ks < 2; ++ks) {
            bf8v af[2], bf[4];
#pragma unroll
            for (int mf = 0; mf < 2; ++mf) {
                int r = wv * 32 + mf * 16 + (l & 15);
                int q = ks * 4 + (l >> 4);
                af[mf] = *reinterpret_cast<const bf8v*>(As + r * 64 + ((q ^ (r & 7)) << 3));
            }
#pragma unroll
            for (int nf = 0; nf < 4; ++nf) {
                int c = nf * 16 + (l & 15);
                int q = ks * 4 + (l >> 4);
                bf[nf] = *reinterpret_cast<const bf8v*>(Bs + c * 64 + ((q ^ (c & 7)) << 3));
            }
#pragma unroll
            for (int mf = 0; mf < 2; ++mf)
#pragma unroll
                for (int nf = 0; nf < 4; ++nf)
                    acc[mf][nf] = __builtin_amdgcn_mfma_f32_16x16x32_bf16(af[mf], bf[nf], acc[mf][nf], 0, 0, 0);
        }
        __syncthreads();
    }

#pragma unroll
    for (int mf = 0; mf < 2; ++mf) {
#pragma unroll
        for (int rr = 0; rr < 4; ++rr) {
            int row = row0 + wv * 32 + mf * 16 + ((l >> 4) * 4) + rr;
            if (row >= M) continue;
            size_t crow = 0;
            if (Cin) crow = (size_t)(cidx ? cidx[row] : row) * ldc;
#pragma unroll
            for (int nf = 0; nf < 4; ++nf) {
                int col = col0 + nf * 16 + (l & 15);
                float v = acc[mf][nf][rr];
                if (bias) v += bias[col];
                if (Cin) v += b2f(Cin[crow + col]);
                if (relu) v = fmaxf(v, 0.f);
                if (outF) outF[(size_t)row * ldc + col] = v;
                if (outB) outB[(size_t)row * ldc + col] = f2b(v);
            }
        }
    }
}

// ---------------- scan helpers ----------------

// gh==nullptr -> round 0 (h_prev == 0): use bhv directly
__global__ void k_gru(const int* __restrict__ cnt, int base, int m,
                      const int* __restrict__ rl, const int* __restrict__ src,
                      const us* __restrict__ gi, const us* __restrict__ gh,
                      const float* __restrict__ bhv,
                      float* __restrict__ mem, us* __restrict__ mem_bf)
{
    int i = blockIdx.x;
    int avail = *cnt - base;
    if (i >= m || i >= avail) return;
    int c = threadIdx.x;
    int s = src[rl[i]];
    float hp = mem[(size_t)s * 256 + c];
    float ir = b2f(gi[(size_t)i * 768 + c]);
    float iz = b2f(gi[(size_t)i * 768 + 256 + c]);
    float in_ = b2f(gi[(size_t)i * 768 + 512 + c]);
    float hr, hz, hn;
    if (gh) {
        hr = b2f(gh[(size_t)i * 768 + c]);
        hz = b2f(gh[(size_t)i * 768 + 256 + c]);
        hn = b2f(gh[(size_t)i * 768 + 512 + c]);
    } else {
        hr = bhv[c]; hz = bhv[256 + c]; hn = bhv[512 + c];
    }
    float r = 1.f / (1.f + expf(-(ir + hr)));
    float z = 1.f / (1.f + expf(-(iz + hz)));
    float n = tanhf(in_ + r * hn);
    float hnew = (1.f - z) * n + z * hp;
    mem[(size_t)s * 256 + c] = hnew;
    mem_bf[(size_t)s * 256 + c] = f2b(hnew);
}

// fused per-row pipeline for tiny rounds (j >= 4)
__global__ void k_tail(int j, const int* __restrict__ roundcnt, const int* __restrict__ roundlist,
                       const int* __restrict__ src, const us* __restrict__ xpart_bf,
                       float* __restrict__ mem, us* __restrict__ mem_bf,
                       const float* __restrict__ Wm1, const float* __restrict__ Wm2,
                       const float* __restrict__ bm2, const float* __restrict__ Wi,
                       const float* __restrict__ Wh, const float* __restrict__ bi,
                       const float* __restrict__ bh)
{
    int i = blockIdx.x;
    if (i >= roundcnt[j]) return;
    int e = roundlist[(size_t)j * EE + i];
    int s = src[e];
    int c = threadIdx.x;
    __shared__ float hs[256];
    __shared__ float xv[256];
    __shared__ float msgv[256];
    __shared__ float giv[768];
    __shared__ float ghv[768];
    hs[c] = mem[(size_t)s * 256 + c];
    __syncthreads();
    float a = b2f(xpart_bf[(size_t)e * 256 + c]);
    for (int k = 0; k < 256; ++k) a += hs[k] * Wm1[(size_t)(256 + k) * 256 + c];
    xv[c] = fmaxf(a, 0.f);
    __syncthreads();
    float m = bm2[c];
    for (int k = 0; k < 256; ++k) m += xv[k] * Wm2[(size_t)k * 256 + c];
    msgv[c] = fmaxf(m, 0.f);
    __syncthreads();
#pragma unroll
    for (int tpart = 0; tpart < 3; ++tpart) {
        int cc = c + tpart * 256;
        float gi_ = bi[cc], gh_ = bh[cc];
        for (int k = 0; k < 256; ++k) {
            gi_ += msgv[k] * Wi[(size_t)k * 768 + cc];
            gh_ += hs[k] * Wh[(size_t)k * 768 + cc];
        }
        giv[cc] = gi_;
        ghv[cc] = gh_;
    }
    __syncthreads();
    float r = 1.f / (1.f + expf(-(giv[c] + ghv[c])));
    float z = 1.f / (1.f + expf(-(giv[256 + c] + ghv[256 + c])));
    float n = tanhf(giv[512 + c] + r * ghv[512 + c]);
    float hnew = (1.f - z) * n + z * hs[c];
    mem[(size_t)s * 256 + c] = hnew;
    mem_bf[(size_t)s * 256 + c] = f2b(hnew);
}

// ---------------- attention / head ----------------

// rows [0,NN): sdot/ddot from h; rows [NN, NN+necnt): edot from compact ef
__global__ __launch_bounds__(256) void k_dots(const us* __restrict__ h, const us* __restrict__ efc,
                                              const int* __restrict__ necnt,
                                              const float* __restrict__ v_s, const float* __restrict__ v_d,
                                              const float* __restrict__ v_e,
                                              float* __restrict__ sdot, float* __restrict__ ddot,
                                              float* __restrict__ edot)
{
    int lane = threadIdx.x & 63;
    int row = blockIdx.x * 4 + (threadIdx.x >> 6);
    if (row < NN) {
        ushort4 q = reinterpret_cast<const ushort4*>(h + (size_t)row * 256)[lane];
        int c = lane * 4;
        float x0 = b2f(q.x), x1 = b2f(q.y), x2 = b2f(q.z), x3 = b2f(q.w);
        float s1 = x0 * v_s[c] + x1 * v_s[c + 1] + x2 * v_s[c + 2] + x3 * v_s[c + 3];
        float s2 = x0 * v_d[c] + x1 * v_d[c + 1] + x2 * v_d[c + 2] + x3 * v_d[c + 3];
#pragma unroll
        for (int o = 32; o > 0; o >>= 1) { s1 += __shfl_xor(s1, o); s2 += __shfl_xor(s2, o); }
        if (lane == 0) { sdot[row] = s1; ddot[row] = s2; }
    } else {
        int i = row - NN;
        if (i >= *necnt) return;
        ushort4 q = reinterpret_cast<const ushort4*>(efc + (size_t)i * 256)[lane];
        int c = lane * 4;
        float s1 = b2f(q.x) * v_e[c] + b2f(q.y) * v_e[c + 1] + b2f(q.z) * v_e[c + 2] + b2f(q.w) * v_e[c + 3];
#pragma unroll
        for (int o = 32; o > 0; o >>= 1) s1 += __shfl_xor(s1, o);
        if (lane == 0) edot[i] = s1;
    }
}

__global__ void k_logitc(const int* __restrict__ necnt, const int* __restrict__ eidx,
                         const float* __restrict__ sdot, const float* __restrict__ ddot,
                         const float* __restrict__ edot, const int* __restrict__ src,
                         const int* __restrict__ dst, float* __restrict__ logit,
                         unsigned* __restrict__ mx)
{
    int i = blockIdx.x * 256 + threadIdx.x;
    if (i >= *necnt) return;
    int e = eidx[i];
    float l = sdot[src[e]] + ddot[dst[e]] + edot[i];
    l = (l > 0.f) ? l : 0.2f * l;
    logit[i] = l;
    atomicMax(&mx[dst[e]], fkey(l));
}

__global__ void k_alphac(const int* __restrict__ necnt, const int* __restrict__ eidx,
                         const float* __restrict__ logit, const int* __restrict__ dst,
                         const unsigned* __restrict__ mx, float* __restrict__ alpha,
                         float* __restrict__ denom)
{
    int i = blockIdx.x * 256 + threadIdx.x;
    if (i >= *necnt) return;
    int d = dst[eidx[i]];
    float a = expf(logit[i] - funkey(mx[d]));
    alpha[i] = a;
    atomicAdd(&denom[d], a);
}

__global__ void k_scatc(const int* __restrict__ necnt, const int* __restrict__ eidx,
                        const float* __restrict__ alpha, const int* __restrict__ src,
                        const int* __restrict__ dst, const us* __restrict__ h,
                        const us* __restrict__ efc, float* __restrict__ outb)
{
    int i = blockIdx.x * 4 + (threadIdx.x >> 6);
    if (i >= *necnt) return;
    int c4 = threadIdx.x & 63;
    int e = eidx[i];
    float a = alpha[i];
    ushort4 hv = reinterpret_cast<const ushort4*>(h + (size_t)src[e] * 256)[c4];
    ushort4 ev = reinterpret_cast<const ushort4*>(efc + (size_t)i * 256)[c4];
    float* op = outb + (size_t)dst[e] * 256 + c4 * 4;
    atomicAdd(op + 0, a * (b2f(hv.x) + b2f(ev.x)));
    atomicAdd(op + 1, a * (b2f(hv.y) + b2f(ev.y)));
    atomicAdd(op + 2, a * (b2f(hv.z) + b2f(ev.z)));
    atomicAdd(op + 3, a * (b2f(hv.w) + b2f(ev.w)));
}

__global__ void k_pe(const int* __restrict__ pm, const float* __restrict__ outb,
                     const float* __restrict__ denom, us* __restrict__ pe)
{
    int p = blockIdx.x, c = threadIdx.x;
    int n = pm[p];
    pe[(size_t)p * 256 + c] = f2b(outb[(size_t)n * 256 + c] / (denom[n] + 1e-16f));
}

__global__ __launch_bounds__(256) void k_final(const float* __restrict__ c1, const float* __restrict__ Wc2,
                                               const float* __restrict__ bc2, float* __restrict__ out)
{
    int lane = threadIdx.x & 63;
    int row = blockIdx.x * 4 + (threadIdx.x >> 6);
    if (row >= PP) return;
    float s = 0.f;
    for (int c = lane; c < 128; c += 64) s += c1[(size_t)row * 128 + c] * Wc2[c];
#pragma unroll
    for (int off = 32; off > 0; off >>= 1) s += __shfl_xor(s, off);
    if (lane == 0) out[row] = 1.f / (1.f + expf(-(s + bc2[0])));
}

// ---------------- host ----------------

extern "C" void kernel_launch(void* const* d_in, const int* in_sizes, int n_in,
                              void* d_out, int out_size, void* d_ws, size_t ws_size,
                              hipStream_t stream)
{
    (void)in_sizes; (void)n_in; (void)out_size;
    const float* nf    = (const float*)d_in[0];
    const int*   ei    = (const int*)  d_in[1];
    const float* ea    = (const float*)d_in[2];
    const float* t     = (const float*)d_in[3];
    const int*   pm    = (const int*)  d_in[4];
    const float* wt    = (const float*)d_in[5];
    const float* bt    = (const float*)d_in[6];
    const float* Wm1   = (const float*)d_in[7];
    const float* bm1   = (const float*)d_in[8];
    const float* Wm2   = (const float*)d_in[9];
    const float* bm2   = (const float*)d_in[10];
    const float* Wi    = (const float*)d_in[11];
    const float* Wh    = (const float*)d_in[12];
    const float* bi    = (const float*)d_in[13];
    const float* bh    = (const float*)d_in[14];
    const float* Wg    = (const float*)d_in[15];
    const float* We    = (const float*)d_in[16];
    const float* a_src = (const float*)d_in[17];
    const float* a_dst = (const float*)d_in[18];
    const float* a_e   = (const float*)d_in[19];
    const float* Wc1   = (const float*)d_in[20];
    const float* bc1   = (const float*)d_in[21];
    const float* Wc2   = (const float*)d_in[22];
    const float* bc2   = (const float*)d_in[23];
    float* outp = (float*)d_out;
    const int* src = ei;
    const int* dst = ei + EE;

    char* base = (char*)d_ws;
    size_t off = 0;
    auto alloc = [&](size_t bytes) -> void* {
        void* p = base + off;
        off = (off + bytes + 255) & ~(size_t)255;
        return p;
    };
    int* rank      = (int*)alloc((size_t)EE * 4);
    int* roundcnt  = (int*)alloc(64 * 4);          // [0..11] rounds, [32]=tm, [33]=necnt
    int* roundlist = (int*)alloc((size_t)MAXR * EE * 4);
    int* bsum      = (int*)alloc(256 * 4);
    int* eidx      = (int*)alloc((size_t)EE * 4);
    us* te_bf    = (us*)alloc((size_t)EE * 128 * 2);
    us* nf_bf    = (us*)alloc((size_t)NN * 256 * 2);
    us* ea_bf    = (us*)alloc((size_t)EE * 128 * 2);
    us* xpart_bf = (us*)alloc((size_t)EE * 256 * 2);
    float* memb  = (float*)alloc((size_t)NN * 256 * 4);   // NOTE: memb_bf must follow (zone memset)
    us* memb_bf  = (us*)alloc((size_t)NN * 256 * 2);
    us* Wt_x = (us*)alloc((size_t)256 * 512 * 2);
    us* Wt_a = (us*)alloc((size_t)256 * 256 * 2);
    us* Wt_m2= (us*)alloc((size_t)256 * 256 * 2);
    us* Wt_i = (us*)alloc((size_t)768 * 256 * 2);
    us* Wt_h = (us*)alloc((size_t)768 * 256 * 2);
    us* Wt_g = (us*)alloc((size_t)256 * 512 * 2);
    us* Wt_e = (us*)alloc((size_t)256 * 256 * 2);
    us* Wt_c = (us*)alloc((size_t)128 * 256 * 2);
    float* gvec  = (float*)alloc(256 * 4);
    float* sdot  = (float*)alloc((size_t)NN * 4);
    float* ddot  = (float*)alloc((size_t)NN * 4);
    float* edot  = (float*)alloc((size_t)EE * 4);
    float* logit = (float*)alloc((size_t)EE * 4);
    float* alpha = (float*)alloc((size_t)EE * 4);
    // zeroed node zone (one memset): mx | denom | needed | scnt
    unsigned* mx = (unsigned*)alloc((size_t)NN * 4);
    float* denom = (float*)alloc((size_t)NN * 4);
    int* needed  = (int*)alloc((size_t)NN * 4);
    int* scnt    = (int*)alloc((size_t)NN * 4);
    char* zone_end = base + off;

    size_t region = (ws_size > off + 4096) ? (ws_size - off - 4096) : 0;
    long capL = (long)(region / 4096);
    int CAPR = (int)(capL < 0 ? 0 : capL);
    CAPR = (CAPR / 128) * 128;
    if (CAPR > 28160) CAPR = 28160;
    if (CAPR < 6400) return;   // h_bf alias needs CAPR*4096 >= NN*512
    us* xbuf_bf = (us*)alloc((size_t)CAPR * 256 * 2);
    us* msg_bf  = (us*)alloc((size_t)CAPR * 256 * 2);
    us* gi_bf   = (us*)alloc((size_t)CAPR * 768 * 2);
    us* gh_bf   = (us*)alloc((size_t)CAPR * 768 * 2);
    if (off > ws_size) return;

    unsigned* tm = (unsigned*)&roundcnt[32];
    int* necnt   = &roundcnt[33];
    // bucket-sort scratch aliases roundlist (dead until k_chain)
    int* hist  = roundlist;
    int* hbase = roundlist + NB;
    int* hcur  = roundlist + 2 * NB;
    int* blist = roundlist + 3 * NB;
    // per-src lists alias gi_bf (dead until first gi GEMM)
    int* slist = (int*)gi_bf;          // NN*SCAP*4 = 3.2MB <= CAPR*1536

    us* h_bf  = xbuf_bf;               // alias: chunk region dead post-scan (25.6MB)
    us* ef_c  = xpart_bf;              // alias: xpart dead after tails
    float* outb = memb;                // alias: f32 mem dead post-scan
    us* pe_bf = te_bf;                 // alias: te dead after ef GEMM
    float* c1 = (float*)(te_bf + (size_t)PP * 256);

    const dim3 B(256);
    const int gE = (EE + 255) / 256;

    // ---- consolidated memsets ----
    hipMemsetAsync(roundcnt, 0, 64 * 4, stream);                          // rounds + tm + necnt
    hipMemsetAsync(hist, 0, (size_t)3 * NB * 4, stream);                  // hist/hbase/hcur
    hipMemsetAsync(mx, 0, (size_t)(zone_end - (char*)mx), stream);        // mx|denom|needed|scnt
    hipMemsetAsync(memb, 0, (size_t)NN * 256 * 6, stream);                // memb + memb_bf

    k_need<<<(PP + 255) / 256, B, 0, stream>>>(pm, needed);
    k_elist<<<gE, B, 0, stream>>>(dst, needed, necnt, eidx);

    // ---- ordering ----
    k_prep<<<gE, B, 0, stream>>>(t, src, hist, scnt, slist, tm);
    k_scan1<<<256, B, 0, stream>>>(hist, hbase, bsum);
    k_scan2<<<1, B, 0, stream>>>(bsum);
    k_scan3<<<256, B, 0, stream>>>(hbase, bsum);
    k_bscatter<<<gE, B, 0, stream>>>(t, hbase, hcur, blist);
    k_rank2<<<gE, B, 0, stream>>>(t, hbase, hist, blist, rank);
    k_chain<<<gE, B, 0, stream>>>(src, rank, scnt, slist, roundcnt, roundlist);

    // ---- conversions (te + nf + ea fused) ----
    k_conv<<<(EE * 128 + NN * 64 + EE * 32 + 255) / 256, B, 0, stream>>>(
        t, wt, bt, te_bf, nf, nf_bf, ea, ea_bf);

    // ---- fused weight transposes + gvec ----
    {
        WtAll wa;
        int o = 0;
        auto set = [&](int i, const float* W, us* dstp, int K, int N, int koff, int Ktot) {
            wa.d[i] = WtDesc{W, dstp, K, N, koff, Ktot, o};
            o += K * N;
        };
        set(0, Wm1, Wt_x, 256, 256, 0, 512);
        set(1, Wm1 + (size_t)512 * 256, Wt_x, 128, 256, 256, 512);
        set(2, Wm1 + (size_t)640 * 256, Wt_x, 128, 256, 384, 512);
        set(3, Wm1 + (size_t)256 * 256, Wt_a, 256, 256, 0, 256);
        set(4, Wm2, Wt_m2, 256, 256, 0, 256);
        set(5, Wi, Wt_i, 256, 768, 0, 256);
        set(6, Wh, Wt_h, 256, 768, 0, 256);
        set(7, Wg, Wt_g, 512, 256, 0, 512);
        set(8, We, Wt_e, 256, 256, 0, 256);
        set(9, Wc1, Wt_c, 256, 128, 0, 256);
        wa.total = o;
        int nb = (o + 255) / 256;
        k_wtall<<<nb + 1, B, 0, stream>>>(wa, nb, tm, wt, bt, Wg, gvec);
    }

    // xpart = bm1 + nf[src]@Wm1[0:256] + ea@Wm1[512:640] + te@Wm1[640:768]
    const int gxE = (EE + 127) / 128;
    k_mgemm<<<dim3(gxE, 4), B, 0, stream>>>(nf_bf, 256, src, nullptr, ea_bf, 128, nullptr,
        te_bf, 128, Wt_x, 512, 512, bm1, nullptr, nullptr, nullptr, xpart_bf, 256, EE, nullptr, 0, 0, 0);

    // ---- chain rounds 0..3 via MFMA GEMMs ----
    for (int j = 0; j < 4; ++j) {
        int bound = EE / (j + 1);
        for (int cb = 0; cb < bound; cb += CAPR) {
            int m = bound - cb; if (m > CAPR) m = CAPR;
            int gx = (m + 127) / 128;
            const int* rl = roundlist + (size_t)j * EE + cb;
            if (j == 0) {
                // h_prev == 0: msg = relu(relu(xpart[e]) @ Wm2 + bm2); gh = bh
                k_mgemm<<<dim3(gx, 4), B, 0, stream>>>(xpart_bf, 256, rl, nullptr, nullptr, 0, nullptr,
                    nullptr, 0, Wt_m2, 256, 256, bm2, nullptr, nullptr, nullptr, msg_bf, 256, m, roundcnt + j, cb, 1, 1);
                k_mgemm<<<dim3(gx, 12), B, 0, stream>>>(msg_bf, 256, nullptr, nullptr, nullptr, 0, nullptr,
                    nullptr, 0, Wt_i, 256, 256, bi, nullptr, nullptr, nullptr, gi_bf, 768, m, roundcnt + j, cb, 0, 0);
                k_gru<<<m, B, 0, stream>>>(roundcnt + j, cb, m, rl, src, gi_bf, nullptr, bh, memb, memb_bf);
            } else {
                k_mgemm<<<dim3(gx, 4), B, 0, stream>>>(memb_bf, 256, rl, src, nullptr, 0, nullptr,
                    nullptr, 0, Wt_a, 256, 256, nullptr, xpart_bf, rl, nullptr, xbuf_bf, 256, m, roundcnt + j, cb, 1, 0);
                k_mgemm<<<dim3(gx, 4), B, 0, stream>>>(xbuf_bf, 256, nullptr, nullptr, nullptr, 0, nullptr,
                    nullptr, 0, Wt_m2, 256, 256, bm2, nullptr, nullptr, nullptr, msg_bf, 256, m, roundcnt + j, cb, 1, 0);
                k_mgemm<<<dim3(gx, 12), B, 0, stream>>>(msg_bf, 256, nullptr, nullptr, nullptr, 0, nullptr,
                    nullptr, 0, Wt_i, 256, 256, bi, nullptr, nullptr, nullptr, gi_bf, 768, m, roundcnt + j, cb, 0, 0);
                k_mgemm<<<dim3(gx, 12), B, 0, stream>>>(memb_bf, 256, rl, src, nullptr, 0, nullptr,
                    nullptr, 0, Wt_h, 256, 256, bh, nullptr, nullptr, nullptr, gh_bf, 768, m, roundcnt + j, cb, 0, 0);
                k_gru<<<m, B, 0, stream>>>(roundcnt + j, cb, m, rl, src, gi_bf, gh_bf, bh, memb, memb_bf);
            }
        }
    }
    // tiny rounds: scalar per-row tail
    for (int j = 4; j < MAXR; ++j) {
        int bound = (EE + j) / (j + 1);
        k_tail<<<bound, B, 0, stream>>>(j, roundcnt, roundlist, src, xpart_bf, memb, memb_bf,
                                        Wm1, Wm2, bm2, Wi, Wh, bi, bh);
    }

    hipMemsetAsync(outb, 0, (size_t)NN * 256 * 4, stream);  // memb f32 dead -> attention accumulator

    // h = [nf | mem]@Wg + gte@Wg[512:640] (gvec bias)
    const int gxN = (NN + 127) / 128;
    k_mgemm<<<dim3(gxN, 4), B, 0, stream>>>(nf_bf, 256, nullptr, nullptr, memb_bf, 256, nullptr,
        nullptr, 0, Wt_g, 512, 512, gvec, nullptr, nullptr, nullptr, h_bf, 256, NN, nullptr, 0, 0, 0);

    // ef (compact, needed edges only) = [ea | te](eidx) @ We
    k_mgemm<<<dim3(gxE, 4), B, 0, stream>>>(ea_bf, 128, eidx, nullptr, te_bf, 128, eidx,
        nullptr, 0, Wt_e, 256, 256, nullptr, nullptr, nullptr, nullptr, ef_c, 256, EE, necnt, 0, 0, 0);

    k_dots<<<(NN + EE + 3) / 4, B, 0, stream>>>(h_bf, ef_c, necnt, a_src, a_dst, a_e, sdot, ddot, edot);

    k_logitc<<<gE, B, 0, stream>>>(necnt, eidx, sdot, ddot, edot, src, dst, logit, mx);
    k_alphac<<<gE, B, 0, stream>>>(necnt, eidx, logit, dst, mx, alpha, denom);
    k_scatc<<<(EE + 3) / 4, B, 0, stream>>>(necnt, eidx, alpha, src, dst, h_bf, ef_c, outb);

    k_pe<<<PP, B, 0, stream>>>(pm, outb, denom, pe_bf);
    k_mgemm<<<dim3((PP + 127) / 128, 2), B, 0, stream>>>(pe_bf, 256, nullptr, nullptr, nullptr, 0, nullptr,
        nullptr, 0, Wt_c, 256, 256, bc1, nullptr, nullptr, c1, nullptr, 128, PP, nullptr, 0, 1, 0);
    k_final<<<(PP + 3) / 4, B, 0, stream>>>(c1, Wc2, bc2, outp);
}

// Round 6
// 724.871 us; speedup vs baseline: 4.2396x; 1.1514x over previous
//
#include <hip/hip_runtime.h>

#define NN 50000
#define EE 40000
#define PP 4096
#define MAXR 12
#define SCAP 16
#define NB 65536

typedef unsigned short us;
typedef __attribute__((ext_vector_type(8))) short bf8v;
typedef __attribute__((ext_vector_type(4))) float f4v;

__device__ __forceinline__ us f2b(float x) {
    unsigned u = __float_as_uint(x);
    u = (u + 0x7fffu + ((u >> 16) & 1u)) >> 16;
    return (us)u;
}
__device__ __forceinline__ float b2f(us h) {
    return __uint_as_float(((unsigned)h) << 16);
}
__device__ __forceinline__ unsigned fkey(float f) {
    unsigned u = __float_as_uint(f);
    return (u & 0x80000000u) ? ~u : (u | 0x80000000u);
}
__device__ __forceinline__ float funkey(unsigned k) {
    unsigned u = (k & 0x80000000u) ? (k & 0x7fffffffu) : ~k;
    return __uint_as_float(u);
}
__device__ __forceinline__ int bucket_of(float tv) {
    int b = (int)(tv * 65536.0f);
    if (b < 0) b = 0;
    if (b > 65535) b = 65535;
    return b;
}
__device__ __forceinline__ unsigned relu2bf(unsigned u) {
    unsigned lo = (u & 0x8000u) ? 0u : (u & 0xFFFFu);
    unsigned hi = (u & 0x80000000u) ? 0u : (u & 0xFFFF0000u);
    return lo | hi;
}

// ---------------- needed nodes / edges / U-set ----------------

__global__ void k_need(const int* __restrict__ pm, int* __restrict__ needed)
{
    int i = blockIdx.x * 256 + threadIdx.x;
    if (i < PP) needed[pm[i]] = 1;
}

// LDS-aggregated: eidx list of needed edges + uneed mask (src/dst of needed edges)
__global__ void k_elist(const int* __restrict__ src, const int* __restrict__ dst,
                        const int* __restrict__ needed, int* __restrict__ necnt,
                        int* __restrict__ eidx, int* __restrict__ uneed)
{
    __shared__ int lc, lb;
    if (threadIdx.x == 0) lc = 0;
    __syncthreads();
    int e = blockIdx.x * 256 + threadIdx.x;
    int slot = -1;
    if (e < EE && needed[dst[e]]) {
        slot = atomicAdd(&lc, 1);
        uneed[dst[e]] = 1;
        uneed[src[e]] = 1;
    }
    __syncthreads();
    if (threadIdx.x == 0 && lc) lb = atomicAdd(necnt, lc);
    __syncthreads();
    if (slot >= 0) eidx[lb + slot] = e;
}

// LDS-aggregated compaction of U-set
__global__ void k_ulist(const int* __restrict__ uneed, int* __restrict__ ucnt,
                        int* __restrict__ ulist, int* __restrict__ nidx)
{
    __shared__ int lc, lb;
    if (threadIdx.x == 0) lc = 0;
    __syncthreads();
    int n = blockIdx.x * 256 + threadIdx.x;
    int slot = -1;
    if (n < NN && uneed[n]) slot = atomicAdd(&lc, 1);
    __syncthreads();
    if (threadIdx.x == 0 && lc) lb = atomicAdd(ucnt, lc);
    __syncthreads();
    if (slot >= 0) { ulist[lb + slot] = n; nidx[n] = lb + slot; }
}

// ---------------- ordering ----------------

__global__ __launch_bounds__(256) void k_prep(const float* __restrict__ t, const int* __restrict__ src,
                                              int* __restrict__ hist, int* __restrict__ scnt,
                                              int* __restrict__ slist, unsigned* __restrict__ tm)
{
    int e = blockIdx.x * 256 + threadIdx.x;
    float v = 0.f;
    if (e < EE) {
        float tv = t[e];
        v = tv;
        atomicAdd(&hist[bucket_of(tv)], 1);
        int s = src[e];
        int slot = atomicAdd(&scnt[s], 1);
        if (slot < SCAP) slist[s * SCAP + slot] = e;
    }
#pragma unroll
    for (int o = 32; o > 0; o >>= 1) v = fmaxf(v, __shfl_xor(v, o));
    if ((threadIdx.x & 63) == 0) atomicMax(tm, fkey(v));
}

__global__ void k_scan1(const int* __restrict__ hist, int* __restrict__ hbase, int* __restrict__ bsum)
{
    __shared__ int s[256];
    int i = blockIdx.x * 256 + threadIdx.x;
    int v = hist[i];
    s[threadIdx.x] = v;
    __syncthreads();
    for (int o = 1; o < 256; o <<= 1) {
        int x = (threadIdx.x >= o) ? s[threadIdx.x - o] : 0;
        __syncthreads();
        s[threadIdx.x] += x;
        __syncthreads();
    }
    hbase[i] = s[threadIdx.x] - v;
    if (threadIdx.x == 255) bsum[blockIdx.x] = s[255];
}

__global__ void k_scan2(int* __restrict__ bsum)
{
    __shared__ int s[256];
    int v = bsum[threadIdx.x];
    s[threadIdx.x] = v;
    __syncthreads();
    for (int o = 1; o < 256; o <<= 1) {
        int x = (threadIdx.x >= o) ? s[threadIdx.x - o] : 0;
        __syncthreads();
        s[threadIdx.x] += x;
        __syncthreads();
    }
    bsum[threadIdx.x] = s[threadIdx.x] - v;
}

__global__ void k_scan3(int* __restrict__ hbase, const int* __restrict__ bsum)
{
    int i = blockIdx.x * 256 + threadIdx.x;
    hbase[i] += bsum[blockIdx.x];
}

__global__ void k_bscatter(const float* __restrict__ t, const int* __restrict__ hbase,
                           int* __restrict__ hcur, int* __restrict__ blist)
{
    int e = blockIdx.x * 256 + threadIdx.x;
    if (e >= EE) return;
    int b = bucket_of(t[e]);
    int p = hbase[b] + atomicAdd(&hcur[b], 1);
    blist[p] = e;
}

__global__ void k_rank2(const float* __restrict__ t, const int* __restrict__ hbase,
                        const int* __restrict__ hist, const int* __restrict__ blist,
                        int* __restrict__ rank)
{
    int e = blockIdx.x * 256 + threadIdx.x;
    if (e >= EE) return;
    float te_ = t[e];
    int b = bucket_of(te_);
    int base = hbase[b], cnt = hist[b];
    int r = base;
    for (int i = 0; i < cnt; ++i) {
        int j = blist[base + i];
        float tj = t[j];
        r += (tj < te_ || (tj == te_ && j < e)) ? 1 : 0;
    }
    rank[e] = r;
}

// chain decomposition (filtered to uneed srcs) + round insert + xpart compaction
__global__ void k_chain(const int* __restrict__ src, const int* __restrict__ rank,
                        const int* __restrict__ scnt, const int* __restrict__ slist,
                        const int* __restrict__ uneed,
                        int* __restrict__ roundcnt, int* __restrict__ roundlist,
                        int* __restrict__ xcnt, int* __restrict__ xlist, int* __restrict__ xrow)
{
    __shared__ int lcnt[MAXR];
    __shared__ int lbase[MAXR];
    __shared__ int xl, xb;
    int tid = threadIdx.x;
    if (tid < MAXR) lcnt[tid] = 0;
    if (tid == 0) xl = 0;
    __syncthreads();
    int e = blockIdx.x * 256 + tid;
    int pos = -1, slot = 0, xs = 0;
    if (e < EE && uneed[src[e]]) {
        int s = src[e];
        int c = scnt[s]; if (c > SCAP) c = SCAP;
        int re = rank[e], be = re / 200;
        bool r_e = true;
        for (int i = 0; i < c; ++i) {
            int rj = rank[slist[s * SCAP + i]];
            if (rj / 200 == be && rj > re) { r_e = false; break; }
        }
        if (r_e) {
            int p = 0;
            for (int i = 0; i < c; ++i) {
                int rj = rank[slist[s * SCAP + i]];
                if (rj >= re) continue;
                int bj = rj / 200;
                bool r_j = true;
                for (int k2 = 0; k2 < c; ++k2) {
                    int rj2 = rank[slist[s * SCAP + k2]];
                    if (rj2 / 200 == bj && rj2 > rj) { r_j = false; break; }
                }
                p += r_j ? 1 : 0;
            }
            if (p < MAXR) { pos = p; slot = atomicAdd(&lcnt[p], 1); xs = atomicAdd(&xl, 1); }
        }
    }
    __syncthreads();
    if (tid < MAXR && lcnt[tid]) lbase[tid] = atomicAdd(&roundcnt[tid], lcnt[tid]);
    if (tid == 0 && xl) xb = atomicAdd(xcnt, xl);
    __syncthreads();
    if (pos >= 0) {
        roundlist[(size_t)pos * EE + lbase[pos] + slot] = e;
        int xr = xb + xs;
        xlist[xr] = e;
        xrow[e] = xr;
    }
}

// ---------------- targeted zero / conversions ----------------

// zero memb (f32) + memb_bf rows at U nodes
__global__ void k_zmem(const int* __restrict__ ucnt, const int* __restrict__ ulist,
                       float* __restrict__ memb, us* __restrict__ memb_bf)
{
    int total = *ucnt * 64;
    for (int i = blockIdx.x * 256 + threadIdx.x; i < total; i += gridDim.x * 256) {
        int n = ulist[i >> 6], q = i & 63;
        reinterpret_cast<float4*>(memb + (size_t)n * 256)[q] = make_float4(0.f, 0.f, 0.f, 0.f);
        reinterpret_cast<ushort4*>(memb_bf + (size_t)n * 256)[q] = make_ushort4(0, 0, 0, 0);
    }
}

// convert nf rows at U nodes (scatter into full nf_bf)
__global__ void k_cvtg(const int* __restrict__ ucnt, const int* __restrict__ ulist,
                       const float* __restrict__ nf, us* __restrict__ nf_bf)
{
    int total = *ucnt * 64;
    for (int i = blockIdx.x * 256 + threadIdx.x; i < total; i += gridDim.x * 256) {
        int n = ulist[i >> 6], q = i & 63;
        float4 v = reinterpret_cast<const float4*>(nf + (size_t)n * 256)[q];
        ushort4 o; o.x = f2b(v.x); o.y = f2b(v.y); o.z = f2b(v.z); o.w = f2b(v.w);
        reinterpret_cast<ushort4*>(nf_bf + (size_t)n * 256)[q] = o;
    }
}

// te (sin) + ea conversion at listed edges
__global__ void k_convL(const int* __restrict__ cnt, const int* __restrict__ list,
                        const float* __restrict__ t, const float* __restrict__ w,
                        const float* __restrict__ b, us* __restrict__ te,
                        const float* __restrict__ ea, us* __restrict__ ea_bf)
{
    int total = *cnt * 32;
    for (int i = blockIdx.x * 256 + threadIdx.x; i < total; i += gridDim.x * 256) {
        int e = list[i >> 5], q = (i & 31) * 4;
        float tv = t[e];
        ushort4 ot;
        ot.x = f2b(sinf(tv * w[q] + b[q]));
        ot.y = f2b(sinf(tv * w[q + 1] + b[q + 1]));
        ot.z = f2b(sinf(tv * w[q + 2] + b[q + 2]));
        ot.w = f2b(sinf(tv * w[q + 3] + b[q + 3]));
        *reinterpret_cast<ushort4*>(te + (size_t)e * 128 + q) = ot;
        float4 v = *reinterpret_cast<const float4*>(ea + (size_t)e * 128 + q);
        ushort4 oa; oa.x = f2b(v.x); oa.y = f2b(v.y); oa.z = f2b(v.z); oa.w = f2b(v.w);
        *reinterpret_cast<ushort4*>(ea_bf + (size_t)e * 128 + q) = oa;
    }
}

// zero outb rows + denom + mx at pm nodes
__global__ void k_zout(const int* __restrict__ pm, float* __restrict__ outb,
                       float* __restrict__ denom, unsigned* __restrict__ mx)
{
    int i = blockIdx.x * 256 + threadIdx.x;
    int p = i >> 6, q = i & 63;
    if (p >= PP) return;
    int n = pm[p];
    reinterpret_cast<float4*>(outb + (size_t)n * 256)[q] = make_float4(0.f, 0.f, 0.f, 0.f);
    if (q == 0) { denom[n] = 0.f; mx[n] = 0u; }
}

// ---------------- tiled weight transpose (+ gvec block) ----------------

struct WtD { const float* W; us* dst; int K, N, koff, Ktot, toff; };
struct WtA { WtD d[10]; int ntiles; };

__global__ __launch_bounds__(256) void k_wt2(WtA wa, const unsigned* __restrict__ tm,
                                             const float* __restrict__ wt, const float* __restrict__ bt,
                                             const float* __restrict__ Wg, float* __restrict__ gvec)
{
    if ((int)blockIdx.x == wa.ntiles) {
        __shared__ float sv[128];
        int c = threadIdx.x;
        float tmax = funkey(*tm);
        if (c < 128) sv[c] = sinf(tmax * wt[c] + bt[c]);
        __syncthreads();
        float acc = 0.f;
        for (int k = 0; k < 128; ++k) acc += sv[k] * Wg[(size_t)(512 + k) * 256 + c];
        gvec[c] = acc;
        return;
    }
    int bid = blockIdx.x;
    int di = 0;
#pragma unroll
    for (int i = 1; i < 10; ++i) if (bid >= wa.d[i].toff) di = i;
    WtD d = wa.d[di];
    int tt = bid - d.toff;
    int tn = d.N >> 5;
    int k0 = (tt / tn) << 5, n0 = (tt % tn) << 5;
    __shared__ float ld[32][33];
    int tx = threadIdx.x & 31, ty = threadIdx.x >> 5;
#pragma unroll
    for (int i = 0; i < 4; ++i)
        ld[ty + 8 * i][tx] = d.W[(size_t)(k0 + ty + 8 * i) * d.N + n0 + tx];
    __syncthreads();
#pragma unroll
    for (int i = 0; i < 4; ++i) {
        int n = n0 + ty + 8 * i;
        d.dst[(size_t)n * d.Ktot + d.koff + k0 + tx] = f2b(ld[tx][ty + 8 * i]);
    }
}

// ---------------- MFMA GEMM ----------------
// out = ACT( [A1|A2|A3](rows; per-source gathers) @ Wt^T + bias + Cin(gathered) )
__global__ __launch_bounds__(256) void k_mgemm(
    const us* __restrict__ A1, int K1, const int* __restrict__ idx1, const int* __restrict__ idx1b,
    const us* __restrict__ A2, int K2, const int* __restrict__ idx2,
    const us* __restrict__ A3, int K3, const int* __restrict__ idx3,
    const us* __restrict__ Wt, int Kloop, int ldw,
    const float* __restrict__ bias,
    const us* __restrict__ Cin, const int* __restrict__ cidx, const int* __restrict__ cidxb,
    float* __restrict__ outF, us* __restrict__ outB, int ldc,
    int Mhost, const int* __restrict__ mdev, int mbase, int relu, int relua)
{
    int M = Mhost;
    if (mdev) {
        int avail = *mdev - mbase;
        if (avail < 0) avail = 0;
        if (avail < M) M = avail;
    }
    const int row0 = blockIdx.x * 128;
    if (row0 >= M) return;
    const int col0 = blockIdx.y * 64;

    __shared__ us As[128 * 64];
    __shared__ us Bs[64 * 64];

    const int tid = threadIdx.x;
    const int l = tid & 63;
    const int wv = tid >> 6;

    f4v acc[2][4];
#pragma unroll
    for (int i = 0; i < 2; ++i)
#pragma unroll
        for (int j = 0; j < 4; ++j) acc[i][j] = (f4v){0.f, 0.f, 0.f, 0.f};

    for (int k0 = 0; k0 < Kloop; k0 += 64) {
#pragma unroll
        for (int it = 0; it < 4; ++it) {
            int idx = tid + it * 256;
            int r = idx >> 3, q = idx & 7;
            int gk = k0 + q * 8;
            int grow = row0 + r;
            uint4 v = make_uint4(0u, 0u, 0u, 0u);
            if (grow < M) {
                const us* sp; int st, krel, ar = grow;
                if (gk < K1) {
                    sp = A1; st = K1; krel = gk;
                    if (idx1) { ar = idx1[ar]; if (idx1b) ar = idx1b[ar]; }
                } else if (gk < K1 + K2) {
                    sp = A2; st = K2; krel = gk - K1;
                    if (idx2) ar = idx2[ar];
                } else {
                    sp = A3; st = K3; krel = gk - K1 - K2;
                    if (idx3) ar = idx3[ar];
                }
                v = *reinterpret_cast<const uint4*>(sp + (size_t)ar * st + krel);
                if (relua) { v.x = relu2bf(v.x); v.y = relu2bf(v.y); v.z = relu2bf(v.z); v.w = relu2bf(v.w); }
            }
            *reinterpret_cast<uint4*>(As + r * 64 + ((q ^ (r & 7)) << 3)) = v;
        }
#pragma unroll
        for (int it = 0; it < 2; ++it) {
            int idx = tid + it * 256;
            int c = idx >> 3, q = idx & 7;
            uint4 v = *reinterpret_cast<const uint4*>(Wt + (size_t)(col0 + c) * ldw + k0 + q * 8);
            *reinterpret_cast<uint4*>(Bs + c * 64 + ((q ^ (c & 7)) << 3)) = v;
        }
        __syncthreads();
#pragma unroll
        for (int ks = 0; ks < 2; ++ks) {
            bf8v af[2], bfr[4];
#pragma unroll
            for (int mf = 0; mf < 2; ++mf) {
                int r = wv * 32 + mf * 16 + (l & 15);
                int q = ks * 4 + (l >> 4);
                af[mf] = *reinterpret_cast<const bf8v*>(As + r * 64 + ((q ^ (r & 7)) << 3));
            }
#pragma unroll
            for (int nf = 0; nf < 4; ++nf) {
                int c = nf * 16 + (l & 15);
                int q = ks * 4 + (l >> 4);
                bfr[nf] = *reinterpret_cast<const bf8v*>(Bs + c * 64 + ((q ^ (c & 7)) << 3));
            }
#pragma unroll
            for (int mf = 0; mf < 2; ++mf)
#pragma unroll
                for (int nf = 0; nf < 4; ++nf)
                    acc[mf][nf] = __builtin_amdgcn_mfma_f32_16x16x32_bf16(af[mf], bfr[nf], acc[mf][nf], 0, 0, 0);
        }
        __syncthreads();
    }

#pragma unroll
    for (int mf = 0; mf < 2; ++mf) {
#pragma unroll
        for (int rr = 0; rr < 4; ++rr) {
            int row = row0 + wv * 32 + mf * 16 + ((l >> 4) * 4) + rr;
            if (row >= M) continue;
            size_t crow = 0;
            if (Cin) {
                int cr = cidx ? cidx[row] : row;
                if (cidxb) cr = cidxb[cr];
                crow = (size_t)cr * ldc;
            }
#pragma unroll
            for (int nf = 0; nf < 4; ++nf) {
                int col = col0 + nf * 16 + (l & 15);
                float v = acc[mf][nf][rr];
                if (bias) v += bias[col];
                if (Cin) v += b2f(Cin[crow + col]);
                if (relu) v = fmaxf(v, 0.f);
                if (outF) outF[(size_t)row * ldc + col] = v;
                if (outB) outB[(size_t)row * ldc + col] = f2b(v);
            }
        }
    }
}

// ---------------- fused GRU gate kernel ----------------
// per block: 128 rows x 64 gate channels; computes gi = msg@Wi+bi, gh = mem@Wh+bh
// (3 parts r/z/n each) fully in registers, applies gate, writes mem/mem_bf.
__global__ __launch_bounds__(256) void k_fgru(
    const int* __restrict__ rl, const int* __restrict__ src,
    const us* __restrict__ msg, const us* __restrict__ membr,
    const us* __restrict__ Wti, const us* __restrict__ Wth,
    const float* __restrict__ bi, const float* __restrict__ bh,
    float* __restrict__ mem, us* __restrict__ mem_bf,
    const int* __restrict__ mdev, int mbase, int m, int round0)
{
    int M = *mdev - mbase;
    if (M < 0) M = 0;
    if (M > m) M = m;
    const int row0 = blockIdx.x * 128;
    if (row0 >= M) return;
    const int col0 = blockIdx.y * 64;

    __shared__ us As[128 * 64];
    __shared__ us Bs[64 * 64];

    const int tid = threadIdx.x;
    const int l = tid & 63;
    const int wv = tid >> 6;

    f4v gs[4][2][4];
#pragma unroll
    for (int a = 0; a < 4; ++a)
#pragma unroll
        for (int i = 0; i < 2; ++i)
#pragma unroll
            for (int j = 0; j < 4; ++j) gs[a][i][j] = (f4v){0.f, 0.f, 0.f, 0.f};

#pragma unroll
    for (int part = 0; part < 3; ++part) {
#pragma unroll
        for (int hsel = 0; hsel < 2; ++hsel) {
            if (hsel == 1 && round0) continue;
            f4v acc[2][4];
#pragma unroll
            for (int i = 0; i < 2; ++i)
#pragma unroll
                for (int j = 0; j < 4; ++j) acc[i][j] = (f4v){0.f, 0.f, 0.f, 0.f};
            const us* Wt = hsel ? Wth : Wti;
            for (int k0 = 0; k0 < 256; k0 += 64) {
#pragma unroll
                for (int it = 0; it < 4; ++it) {
                    int idx = tid + it * 256;
                    int r = idx >> 3, q = idx & 7;
                    uint4 v = make_uint4(0u, 0u, 0u, 0u);
                    int grow = row0 + r;
                    if (grow < M) {
                        if (hsel == 0) {
                            v = *reinterpret_cast<const uint4*>(msg + (size_t)grow * 256 + k0 + q * 8);
                        } else {
                            int s = src[rl[grow]];
                            v = *reinterpret_cast<const uint4*>(membr + (size_t)s * 256 + k0 + q * 8);
                        }
                    }
                    *reinterpret_cast<uint4*>(As + r * 64 + ((q ^ (r & 7)) << 3)) = v;
                }
#pragma unroll
                for (int it = 0; it < 2; ++it) {
                    int idx = tid + it * 256;
                    int c = idx >> 3, q = idx & 7;
                    uint4 v = *reinterpret_cast<const uint4*>(Wt + (size_t)(part * 256 + col0 + c) * 256 + k0 + q * 8);
                    *reinterpret_cast<uint4*>(Bs + c * 64 + ((q ^ (c & 7)) << 3)) = v;
                }
                __syncthreads();
#pragma unroll
                for (int ks = 0; ks < 2; ++ks) {
                    bf8v af[2], bfr[4];
#pragma unroll
                    for (int mf = 0; mf < 2; ++mf) {
                        int r = wv * 32 + mf * 16 + (l & 15);
                        int q = ks * 4 + (l >> 4);
                        af[mf] = *reinterpret_cast<const bf8v*>(As + r * 64 + ((q ^ (r & 7)) << 3));
                    }
#pragma unroll
                    for (int nf = 0; nf < 4; ++nf) {
                        int c = nf * 16 + (l & 15);
                        int q = ks * 4 + (l >> 4);
                        bfr[nf] = *reinterpret_cast<const bf8v*>(Bs + c * 64 + ((q ^ (c & 7)) << 3));
                    }
#pragma unroll
                    for (int mf = 0; mf < 2; ++mf)
#pragma unroll
                        for (int nf = 0; nf < 4; ++nf)
                            acc[mf][nf] = __builtin_amdgcn_mfma_f32_16x16x32_bf16(af[mf], bfr[nf], acc[mf][nf], 0, 0, 0);
                }
                __syncthreads();
            }
            const int slot = (part < 2) ? part : (2 + hsel);
#pragma unroll
            for (int i = 0; i < 2; ++i)
#pragma unroll
                for (int j = 0; j < 4; ++j) gs[slot][i][j] += acc[i][j];
        }
    }

#pragma unroll
    for (int mf = 0; mf < 2; ++mf) {
#pragma unroll
        for (int rr = 0; rr < 4; ++rr) {
            int row = row0 + wv * 32 + mf * 16 + ((l >> 4) * 4) + rr;
            if (row >= M) continue;
            int s = src[rl[row]];
#pragma unroll
            for (int nf = 0; nf < 4; ++nf) {
                int col = col0 + nf * 16 + (l & 15);
                float hp = mem[(size_t)s * 256 + col];
                float g0 = gs[0][mf][nf][rr] + bi[col] + bh[col];
                float g1 = gs[1][mf][nf][rr] + bi[256 + col] + bh[256 + col];
                float g2i = gs[2][mf][nf][rr] + bi[512 + col];
                float g2h = gs[3][mf][nf][rr] + bh[512 + col];
                float r = 1.f / (1.f + expf(-g0));
                float z = 1.f / (1.f + expf(-g1));
                float n = tanhf(g2i + r * g2h);
                float hnew = (1.f - z) * n + z * hp;
                mem[(size_t)s * 256 + col] = hnew;
                mem_bf[(size_t)s * 256 + col] = f2b(hnew);
            }
        }
    }
}

// ---------------- scalar tail for tiny rounds (j >= 4) ----------------

__global__ void k_tail(int j, const int* __restrict__ roundcnt, const int* __restrict__ roundlist,
                       const int* __restrict__ src, const us* __restrict__ xpart_c,
                       const int* __restrict__ xrow,
                       float* __restrict__ mem, us* __restrict__ mem_bf,
                       const float* __restrict__ Wm1, const float* __restrict__ Wm2,
                       const float* __restrict__ bm2, const float* __restrict__ Wi,
                       const float* __restrict__ Wh, const float* __restrict__ bi,
                       const float* __restrict__ bh)
{
    int i = blockIdx.x;
    if (i >= roundcnt[j]) return;
    int e = roundlist[(size_t)j * EE + i];
    int s = src[e];
    int c = threadIdx.x;
    __shared__ float hs[256];
    __shared__ float xv[256];
    __shared__ float msgv[256];
    __shared__ float giv[768];
    __shared__ float ghv[768];
    hs[c] = mem[(size_t)s * 256 + c];
    __syncthreads();
    float a = b2f(xpart_c[(size_t)xrow[e] * 256 + c]);
    for (int k = 0; k < 256; ++k) a += hs[k] * Wm1[(size_t)(256 + k) * 256 + c];
    xv[c] = fmaxf(a, 0.f);
    __syncthreads();
    float m = bm2[c];
    for (int k = 0; k < 256; ++k) m += xv[k] * Wm2[(size_t)k * 256 + c];
    msgv[c] = fmaxf(m, 0.f);
    __syncthreads();
#pragma unroll
    for (int tpart = 0; tpart < 3; ++tpart) {
        int cc = c + tpart * 256;
        float gi_ = bi[cc], gh_ = bh[cc];
        for (int k = 0; k < 256; ++k) {
            gi_ += msgv[k] * Wi[(size_t)k * 768 + cc];
            gh_ += hs[k] * Wh[(size_t)k * 768 + cc];
        }
        giv[cc] = gi_;
        ghv[cc] = gh_;
    }
    __syncthreads();
    float r = 1.f / (1.f + expf(-(giv[c] + ghv[c])));
    float z = 1.f / (1.f + expf(-(giv[256 + c] + ghv[256 + c])));
    float n = tanhf(giv[512 + c] + r * ghv[512 + c]);
    float hnew = (1.f - z) * n + z * hs[c];
    mem[(size_t)s * 256 + c] = hnew;
    mem_bf[(size_t)s * 256 + c] = f2b(hnew);
}

// ---------------- attention / head ----------------

__global__ __launch_bounds__(256) void k_dots(const us* __restrict__ hc, const us* __restrict__ efc,
                                              const int* __restrict__ ucnt, const int* __restrict__ necnt,
                                              const float* __restrict__ v_s, const float* __restrict__ v_d,
                                              const float* __restrict__ v_e,
                                              float* __restrict__ sdot, float* __restrict__ ddot,
                                              float* __restrict__ edot)
{
    int lane = threadIdx.x & 63;
    int row = blockIdx.x * 4 + (threadIdx.x >> 6);
    if (row < NN) {
        if (row >= *ucnt) return;
        ushort4 q = reinterpret_cast<const ushort4*>(hc + (size_t)row * 256)[lane];
        int c = lane * 4;
        float x0 = b2f(q.x), x1 = b2f(q.y), x2 = b2f(q.z), x3 = b2f(q.w);
        float s1 = x0 * v_s[c] + x1 * v_s[c + 1] + x2 * v_s[c + 2] + x3 * v_s[c + 3];
        float s2 = x0 * v_d[c] + x1 * v_d[c + 1] + x2 * v_d[c + 2] + x3 * v_d[c + 3];
#pragma unroll
        for (int o = 32; o > 0; o >>= 1) { s1 += __shfl_xor(s1, o); s2 += __shfl_xor(s2, o); }
        if (lane == 0) { sdot[row] = s1; ddot[row] = s2; }
    } else {
        int i = row - NN;
        if (i >= *necnt) return;
        ushort4 q = reinterpret_cast<const ushort4*>(efc + (size_t)i * 256)[lane];
        int c = lane * 4;
        float s1 = b2f(q.x) * v_e[c] + b2f(q.y) * v_e[c + 1] + b2f(q.z) * v_e[c + 2] + b2f(q.w) * v_e[c + 3];
#pragma unroll
        for (int o = 32; o > 0; o >>= 1) s1 += __shfl_xor(s1, o);
        if (lane == 0) edot[i] = s1;
    }
}

__global__ void k_logitc(const int* __restrict__ necnt, const int* __restrict__ eidx,
                         const int* __restrict__ nidx,
                         const float* __restrict__ sdot, const float* __restrict__ ddot,
                         const float* __restrict__ edot, const int* __restrict__ src,
                         const int* __restrict__ dst, float* __restrict__ logit,
                         unsigned* __restrict__ mx)
{
    int i = blockIdx.x * 256 + threadIdx.x;
    if (i >= *necnt) return;
    int e = eidx[i];
    float l = sdot[nidx[src[e]]] + ddot[nidx[dst[e]]] + edot[i];
    l = (l > 0.f) ? l : 0.2f * l;
    logit[i] = l;
    atomicMax(&mx[dst[e]], fkey(l));
}

__global__ void k_alphac(const int* __restrict__ necnt, const int* __restrict__ eidx,
                         const float* __restrict__ logit, const int* __restrict__ dst,
                         const unsigned* __restrict__ mx, float* __restrict__ alpha,
                         float* __restrict__ denom)
{
    int i = blockIdx.x * 256 + threadIdx.x;
    if (i >= *necnt) return;
    int d = dst[eidx[i]];
    float a = expf(logit[i] - funkey(mx[d]));
    alpha[i] = a;
    atomicAdd(&denom[d], a);
}

__global__ void k_scatc(const int* __restrict__ necnt, const int* __restrict__ eidx,
                        const int* __restrict__ nidx,
                        const float* __restrict__ alpha, const int* __restrict__ src,
                        const int* __restrict__ dst, const us* __restrict__ hc,
                        const us* __restrict__ efc, float* __restrict__ outb)
{
    int i = blockIdx.x * 4 + (threadIdx.x >> 6);
    if (i >= *necnt) return;
    int c4 = threadIdx.x & 63;
    int e = eidx[i];
    float a = alpha[i];
    ushort4 hv = reinterpret_cast<const ushort4*>(hc + (size_t)nidx[src[e]] * 256)[c4];
    ushort4 ev = reinterpret_cast<const ushort4*>(efc + (size_t)i * 256)[c4];
    float* op = outb + (size_t)dst[e] * 256 + c4 * 4;
    atomicAdd(op + 0, a * (b2f(hv.x) + b2f(ev.x)));
    atomicAdd(op + 1, a * (b2f(hv.y) + b2f(ev.y)));
    atomicAdd(op + 2, a * (b2f(hv.z) + b2f(ev.z)));
    atomicAdd(op + 3, a * (b2f(hv.w) + b2f(ev.w)));
}

__global__ void k_pe(const int* __restrict__ pm, const float* __restrict__ outb,
                     const float* __restrict__ denom, us* __restrict__ pe)
{
    int p = blockIdx.x, c = threadIdx.x;
    int n = pm[p];
    pe[(size_t)p * 256 + c] = f2b(outb[(size_t)n * 256 + c] / (denom[n] + 1e-16f));
}

__global__ __launch_bounds__(256) void k_final(const float* __restrict__ c1, const float* __restrict__ Wc2,
                                               const float* __restrict__ bc2, float* __restrict__ out)
{
    int lane = threadIdx.x & 63;
    int row = blockIdx.x * 4 + (threadIdx.x >> 6);
    if (row >= PP) return;
    float s = 0.f;
    for (int c = lane; c < 128; c += 64) s += c1[(size_t)row * 128 + c] * Wc2[c];
#pragma unroll
    for (int off = 32; off > 0; off >>= 1) s += __shfl_xor(s, off);
    if (lane == 0) out[row] = 1.f / (1.f + expf(-(s + bc2[0])));
}

// ---------------- host ----------------

extern "C" void kernel_launch(void* const* d_in, const int* in_sizes, int n_in,
                              void* d_out, int out_size, void* d_ws, size_t ws_size,
                              hipStream_t stream)
{
    (void)in_sizes; (void)n_in; (void)out_size;
    const float* nf    = (const float*)d_in[0];
    const int*   ei    = (const int*)  d_in[1];
    const float* ea    = (const float*)d_in[2];
    const float* t     = (const float*)d_in[3];
    const int*   pm    = (const int*)  d_in[4];
    const float* wt    = (const float*)d_in[5];
    const float* bt    = (const float*)d_in[6];
    const float* Wm1   = (const float*)d_in[7];
    const float* bm1   = (const float*)d_in[8];
    const float* Wm2   = (const float*)d_in[9];
    const float* bm2   = (const float*)d_in[10];
    const float* Wi    = (const float*)d_in[11];
    const float* Wh    = (const float*)d_in[12];
    const float* bi    = (const float*)d_in[13];
    const float* bh    = (const float*)d_in[14];
    const float* Wg    = (const float*)d_in[15];
    const float* We    = (const float*)d_in[16];
    const float* a_src = (const float*)d_in[17];
    const float* a_dst = (const float*)d_in[18];
    const float* a_e   = (const float*)d_in[19];
    const float* Wc1   = (const float*)d_in[20];
    const float* bc1   = (const float*)d_in[21];
    const float* Wc2   = (const float*)d_in[22];
    const float* bc2   = (const float*)d_in[23];
    float* outp = (float*)d_out;
    const int* src = ei;
    const int* dst = ei + EE;

    char* base = (char*)d_ws;
    size_t off = 0;
    auto alloc = [&](size_t bytes) -> void* {
        void* p = base + off;
        off = (off + bytes + 255) & ~(size_t)255;
        return p;
    };
    int* rank      = (int*)alloc((size_t)EE * 4);
    int* roundcnt  = (int*)alloc(64 * 4);          // [0..11] rounds, [32]=tm, [33]=necnt, [34]=ucnt, [35]=xcnt
    int* roundlist = (int*)alloc((size_t)MAXR * EE * 4);
    int* bsum      = (int*)alloc(256 * 4);
    int* eidx      = (int*)alloc((size_t)EE * 4);
    int* xlist     = (int*)alloc((size_t)EE * 4);
    int* xrow      = (int*)alloc((size_t)EE * 4);
    int* ulist     = (int*)alloc((size_t)NN * 4);
    int* nidx      = (int*)alloc((size_t)NN * 4);
    us* te_bf    = (us*)alloc((size_t)EE * 128 * 2);
    us* nf_bf    = (us*)alloc((size_t)NN * 256 * 2);
    us* ea_bf    = (us*)alloc((size_t)EE * 128 * 2);
    us* xh       = (us*)alloc((size_t)NN * 256 * 2);   // slist -> xpart_c -> hc
    float* memb  = (float*)alloc((size_t)NN * 256 * 4);
    us* memb_bf  = (us*)alloc((size_t)NN * 256 * 2);
    us* Wt_x = (us*)alloc((size_t)256 * 512 * 2);
    us* Wt_a = (us*)alloc((size_t)256 * 256 * 2);
    us* Wt_m2= (us*)alloc((size_t)256 * 256 * 2);
    us* Wt_i = (us*)alloc((size_t)768 * 256 * 2);
    us* Wt_h = (us*)alloc((size_t)768 * 256 * 2);
    us* Wt_g = (us*)alloc((size_t)256 * 512 * 2);
    us* Wt_e = (us*)alloc((size_t)256 * 256 * 2);
    us* Wt_c = (us*)alloc((size_t)128 * 256 * 2);
    float* gvec  = (float*)alloc(256 * 4);
    float* sdot  = (float*)alloc((size_t)NN * 4);
    float* ddot  = (float*)alloc((size_t)NN * 4);
    float* edot  = (float*)alloc((size_t)EE * 4);
    float* logit = (float*)alloc((size_t)EE * 4);
    float* alpha = (float*)alloc((size_t)EE * 4);
    unsigned* mx = (unsigned*)alloc((size_t)NN * 4);
    float* denom = (float*)alloc((size_t)NN * 4);
    // zeroed mask zone (one memset): needed | uneed | scnt
    int* needed  = (int*)alloc((size_t)NN * 4);
    int* uneed   = (int*)alloc((size_t)NN * 4);
    int* scnt    = (int*)alloc((size_t)NN * 4);
    char* zone_end = base + off;

    size_t region = (ws_size > off + 4096) ? (ws_size - off - 4096) : 0;
    long capL = (long)(region / 1024);
    int CAPR = (int)(capL < 0 ? 0 : capL);
    CAPR = (CAPR / 128) * 128;
    if (CAPR > 40064) CAPR = 40064;
    if (CAPR < 1280) return;   // ws too small (visible failure)
    us* xbuf_bf = (us*)alloc((size_t)CAPR * 256 * 2);
    us* msg_bf  = (us*)alloc((size_t)CAPR * 256 * 2);
    if (off > ws_size) return;

    unsigned* tm = (unsigned*)&roundcnt[32];
    int* necnt   = &roundcnt[33];
    int* ucnt    = &roundcnt[34];
    int* xcnt    = &roundcnt[35];
    // bucket-sort scratch aliases roundlist (dead until k_chain)
    int* hist  = roundlist;
    int* hcur  = roundlist + NB;
    int* hbase = roundlist + 2 * NB;
    int* blist = roundlist + 3 * NB;
    // aliases in xh: slist (until k_chain) -> xpart_c (until tails) -> hc (after)
    int* slist = (int*)xh;
    us* xpart_c = xh;
    us* hc = xh;
    us* ef_c = nf_bf;                  // nf_bf dead after h-GEMM
    float* outb = memb;                // f32 mem dead post-scan
    us* pe_bf = te_bf;                 // te dead after ef GEMM
    float* c1 = (float*)(te_bf + (size_t)PP * 256);

    const dim3 B(256);
    const int gE = (EE + 255) / 256;
    const int gN = (NN + 255) / 256;

    hipMemsetAsync(roundcnt, 0, 64 * 4, stream);
    hipMemsetAsync(hist, 0, (size_t)2 * NB * 4, stream);                  // hist + hcur
    hipMemsetAsync(needed, 0, (size_t)(zone_end - (char*)needed), stream);

    k_need<<<(PP + 255) / 256, B, 0, stream>>>(pm, needed);
    k_elist<<<gE, B, 0, stream>>>(src, dst, needed, necnt, eidx, uneed);
    k_ulist<<<gN, B, 0, stream>>>(uneed, ucnt, ulist, nidx);

    k_prep<<<gE, B, 0, stream>>>(t, src, hist, scnt, slist, tm);
    k_scan1<<<256, B, 0, stream>>>(hist, hbase, bsum);
    k_scan2<<<1, B, 0, stream>>>(bsum);
    k_scan3<<<256, B, 0, stream>>>(hbase, bsum);
    k_bscatter<<<gE, B, 0, stream>>>(t, hbase, hcur, blist);
    k_rank2<<<gE, B, 0, stream>>>(t, hbase, hist, blist, rank);
    k_chain<<<gE, B, 0, stream>>>(src, rank, scnt, slist, uneed, roundcnt, roundlist, xcnt, xlist, xrow);

    k_zmem<<<1024, B, 0, stream>>>(ucnt, ulist, memb, memb_bf);
    k_cvtg<<<1024, B, 0, stream>>>(ucnt, ulist, nf, nf_bf);
    k_convL<<<1024, B, 0, stream>>>(xcnt, xlist, t, wt, bt, te_bf, ea, ea_bf);
    k_convL<<<1024, B, 0, stream>>>(necnt, eidx, t, wt, bt, te_bf, ea, ea_bf);

    // tiled weight transposes + gvec
    {
        WtA wa;
        int o = 0;
        auto set = [&](int i, const float* W, us* dstp, int K, int N, int koff, int Ktot) {
            wa.d[i] = WtD{W, dstp, K, N, koff, Ktot, o};
            o += (K >> 5) * (N >> 5);
        };
        set(0, Wm1, Wt_x, 256, 256, 0, 512);
        set(1, Wm1 + (size_t)512 * 256, Wt_x, 128, 256, 256, 512);
        set(2, Wm1 + (size_t)640 * 256, Wt_x, 128, 256, 384, 512);
        set(3, Wm1 + (size_t)256 * 256, Wt_a, 256, 256, 0, 256);
        set(4, Wm2, Wt_m2, 256, 256, 0, 256);
        set(5, Wi, Wt_i, 256, 768, 0, 256);
        set(6, Wh, Wt_h, 256, 768, 0, 256);
        set(7, Wg, Wt_g, 512, 256, 0, 512);
        set(8, We, Wt_e, 256, 256, 0, 256);
        set(9, Wc1, Wt_c, 256, 128, 0, 256);
        wa.ntiles = o;
        k_wt2<<<o + 1, B, 0, stream>>>(wa, tm, wt, bt, Wg, gvec);
    }

    // xpart (compact, scan edges) = bm1 + nf[src[e]]@Wm1[0:256] + ea[e]@.. + te[e]@..
    const int gxE = (EE + 127) / 128;
    k_mgemm<<<dim3(gxE, 4), B, 0, stream>>>(nf_bf, 256, xlist, src, ea_bf, 128, xlist,
        te_bf, 128, xlist, Wt_x, 512, 512, bm1, nullptr, nullptr, nullptr,
        nullptr, xpart_c, 256, EE, xcnt, 0, 0, 0);

    // chain rounds 0..3: MFMA GEMMs + fused GRU
    for (int j = 0; j < 4; ++j) {
        int bound = EE / (j + 1);
        for (int cb = 0; cb < bound; cb += CAPR) {
            int m = bound - cb; if (m > CAPR) m = CAPR;
            int gx = (m + 127) / 128;
            const int* rl = roundlist + (size_t)j * EE + cb;
            if (j == 0) {
                k_mgemm<<<dim3(gx, 4), B, 0, stream>>>(xpart_c, 256, rl, xrow, nullptr, 0, nullptr,
                    nullptr, 0, nullptr, Wt_m2, 256, 256, bm2, nullptr, nullptr, nullptr,
                    nullptr, msg_bf, 256, m, roundcnt + j, cb, 1, 1);
                k_fgru<<<dim3(gx, 4), B, 0, stream>>>(rl, src, msg_bf, memb_bf, Wt_i, Wt_h,
                    bi, bh, memb, memb_bf, roundcnt + j, cb, m, 1);
            } else {
                k_mgemm<<<dim3(gx, 4), B, 0, stream>>>(memb_bf, 256, rl, src, nullptr, 0, nullptr,
                    nullptr, 0, nullptr, Wt_a, 256, 256, nullptr, xpart_c, rl, xrow,
                    nullptr, xbuf_bf, 256, m, roundcnt + j, cb, 1, 0);
                k_mgemm<<<dim3(gx, 4), B, 0, stream>>>(xbuf_bf, 256, nullptr, nullptr, nullptr, 0, nullptr,
                    nullptr, 0, nullptr, Wt_m2, 256, 256, bm2, nullptr, nullptr, nullptr,
                    nullptr, msg_bf, 256, m, roundcnt + j, cb, 1, 0);
                k_fgru<<<dim3(gx, 4), B, 0, stream>>>(rl, src, msg_bf, memb_bf, Wt_i, Wt_h,
                    bi, bh, memb, memb_bf, roundcnt + j, cb, m, 0);
            }
        }
    }
    for (int j = 4; j < MAXR; ++j) {
        int bound = (EE + j) / (j + 1);
        k_tail<<<bound, B, 0, stream>>>(j, roundcnt, roundlist, src, xpart_c, xrow, memb, memb_bf,
                                        Wm1, Wm2, bm2, Wi, Wh, bi, bh);
    }

    k_zout<<<(PP * 64 + 255) / 256, B, 0, stream>>>(pm, outb, denom, mx);

    // h (compact U rows) = [nf | mem]@Wg + gvec bias
    const int gxN = (NN + 127) / 128;
    k_mgemm<<<dim3(gxN, 4), B, 0, stream>>>(nf_bf, 256, ulist, nullptr, memb_bf, 256, ulist,
        nullptr, 0, nullptr, Wt_g, 512, 512, gvec, nullptr, nullptr, nullptr,
        nullptr, hc, 256, NN, ucnt, 0, 0, 0);

    // ef (compact needed edges) = [ea | te](eidx) @ We   (into nf_bf region, now dead)
    k_mgemm<<<dim3(gxE, 4), B, 0, stream>>>(ea_bf, 128, eidx, nullptr, te_bf, 128, eidx,
        nullptr, 0, nullptr, Wt_e, 256, 256, nullptr, nullptr, nullptr, nullptr,
        nullptr, ef_c, 256, EE, necnt, 0, 0, 0);

    k_dots<<<(NN + EE + 3) / 4, B, 0, stream>>>(hc, ef_c, ucnt, necnt, a_src, a_dst, a_e, sdot, ddot, edot);

    k_logitc<<<gE, B, 0, stream>>>(necnt, eidx, nidx, sdot, ddot, edot, src, dst, logit, mx);
    k_alphac<<<gE, B, 0, stream>>>(necnt, eidx, logit, dst, mx, alpha, denom);
    k_scatc<<<(EE + 3) / 4, B, 0, stream>>>(necnt, eidx, nidx, alpha, src, dst, hc, ef_c, outb);

    k_pe<<<PP, B, 0, stream>>>(pm, outb, denom, pe_bf);
    k_mgemm<<<dim3((PP + 127) / 128, 2), B, 0, stream>>>(pe_bf, 256, nullptr, nullptr, nullptr, 0, nullptr,
        nullptr, 0, nullptr, Wt_c, 256, 256, bc1, nullptr, nullptr, nullptr,
        c1, nullptr, 128, PP, nullptr, 0, 1, 0);
    k_final<<<(PP + 3) / 4, B, 0, stream>>>(c1, Wc2, bc2, outp);
}

// Round 7
// 628.142 us; speedup vs baseline: 4.8925x; 1.1540x over previous
//
#include <hip/hip_runtime.h>

#define NN 50000
#define EE 40000
#define PP 4096
#define MAXR 12
#define SCAP 16
#define NB 65536

typedef unsigned short us;
typedef __attribute__((ext_vector_type(8))) short bf8v;
typedef __attribute__((ext_vector_type(4))) float f4v;

__device__ __forceinline__ us f2b(float x) {
    unsigned u = __float_as_uint(x);
    u = (u + 0x7fffu + ((u >> 16) & 1u)) >> 16;
    return (us)u;
}
__device__ __forceinline__ float b2f(us h) {
    return __uint_as_float(((unsigned)h) << 16);
}
__device__ __forceinline__ unsigned fkey(float f) {
    unsigned u = __float_as_uint(f);
    return (u & 0x80000000u) ? ~u : (u | 0x80000000u);
}
__device__ __forceinline__ float funkey(unsigned k) {
    unsigned u = (k & 0x80000000u) ? (k & 0x7fffffffu) : ~k;
    return __uint_as_float(u);
}
__device__ __forceinline__ int bucket_of(float tv) {
    int b = (int)(tv * 65536.0f);
    if (b < 0) b = 0;
    if (b > 65535) b = 65535;
    return b;
}
__device__ __forceinline__ unsigned relu2bf(unsigned u) {
    unsigned lo = (u & 0x8000u) ? 0u : (u & 0xFFFFu);
    unsigned hi = (u & 0x80000000u) ? 0u : (u & 0xFFFF0000u);
    return lo | hi;
}

// ---------------- needed nodes / edges / U-set ----------------

__global__ void k_need(const int* __restrict__ pm, int* __restrict__ needed)
{
    int i = blockIdx.x * 256 + threadIdx.x;
    if (i < PP) needed[pm[i]] = 1;
}

__global__ void k_elist(const int* __restrict__ src, const int* __restrict__ dst,
                        const int* __restrict__ needed, int* __restrict__ necnt,
                        int* __restrict__ eidx, int* __restrict__ uneed)
{
    __shared__ int lc, lb;
    if (threadIdx.x == 0) lc = 0;
    __syncthreads();
    int e = blockIdx.x * 256 + threadIdx.x;
    int slot = -1;
    if (e < EE && needed[dst[e]]) {
        slot = atomicAdd(&lc, 1);
        uneed[dst[e]] = 1;
        uneed[src[e]] = 1;
    }
    __syncthreads();
    if (threadIdx.x == 0 && lc) lb = atomicAdd(necnt, lc);
    __syncthreads();
    if (slot >= 0) eidx[lb + slot] = e;
}

__global__ void k_ulist(const int* __restrict__ uneed, int* __restrict__ ucnt,
                        int* __restrict__ ulist, int* __restrict__ nidx)
{
    __shared__ int lc, lb;
    if (threadIdx.x == 0) lc = 0;
    __syncthreads();
    int n = blockIdx.x * 256 + threadIdx.x;
    int slot = -1;
    if (n < NN && uneed[n]) slot = atomicAdd(&lc, 1);
    __syncthreads();
    if (threadIdx.x == 0 && lc) lb = atomicAdd(ucnt, lc);
    __syncthreads();
    if (slot >= 0) { ulist[lb + slot] = n; nidx[n] = lb + slot; }
}

// ---------------- ordering ----------------

__global__ __launch_bounds__(256) void k_prep(const float* __restrict__ t, const int* __restrict__ src,
                                              int* __restrict__ hist, int* __restrict__ scnt,
                                              int* __restrict__ slist, unsigned* __restrict__ tm)
{
    int e = blockIdx.x * 256 + threadIdx.x;
    float v = 0.f;
    if (e < EE) {
        float tv = t[e];
        v = tv;
        atomicAdd(&hist[bucket_of(tv)], 1);
        int s = src[e];
        int slot = atomicAdd(&scnt[s], 1);
        if (slot < SCAP) slist[s * SCAP + slot] = e;
    }
#pragma unroll
    for (int o = 32; o > 0; o >>= 1) v = fmaxf(v, __shfl_xor(v, o));
    if ((threadIdx.x & 63) == 0) atomicMax(tm, fkey(v));
}

__global__ void k_scan1(const int* __restrict__ hist, int* __restrict__ hbase, int* __restrict__ bsum)
{
    __shared__ int s[256];
    int i = blockIdx.x * 256 + threadIdx.x;
    int v = hist[i];
    s[threadIdx.x] = v;
    __syncthreads();
    for (int o = 1; o < 256; o <<= 1) {
        int x = (threadIdx.x >= o) ? s[threadIdx.x - o] : 0;
        __syncthreads();
        s[threadIdx.x] += x;
        __syncthreads();
    }
    hbase[i] = s[threadIdx.x] - v;
    if (threadIdx.x == 255) bsum[blockIdx.x] = s[255];
}

__global__ void k_scan2(int* __restrict__ bsum)
{
    __shared__ int s[256];
    int v = bsum[threadIdx.x];
    s[threadIdx.x] = v;
    __syncthreads();
    for (int o = 1; o < 256; o <<= 1) {
        int x = (threadIdx.x >= o) ? s[threadIdx.x - o] : 0;
        __syncthreads();
        s[threadIdx.x] += x;
        __syncthreads();
    }
    bsum[threadIdx.x] = s[threadIdx.x] - v;
}

__global__ void k_scan3(int* __restrict__ hbase, const int* __restrict__ bsum)
{
    int i = blockIdx.x * 256 + threadIdx.x;
    hbase[i] += bsum[blockIdx.x];
}

__global__ void k_bscatter(const float* __restrict__ t, const int* __restrict__ hbase,
                           int* __restrict__ hcur, int* __restrict__ blist)
{
    int e = blockIdx.x * 256 + threadIdx.x;
    if (e >= EE) return;
    int b = bucket_of(t[e]);
    int p = hbase[b] + atomicAdd(&hcur[b], 1);
    blist[p] = e;
}

__global__ void k_rank2(const float* __restrict__ t, const int* __restrict__ hbase,
                        const int* __restrict__ hist, const int* __restrict__ blist,
                        int* __restrict__ rank)
{
    int e = blockIdx.x * 256 + threadIdx.x;
    if (e >= EE) return;
    float te_ = t[e];
    int b = bucket_of(te_);
    int base = hbase[b], cnt = hist[b];
    int r = base;
    for (int i = 0; i < cnt; ++i) {
        int j = blist[base + i];
        float tj = t[j];
        r += (tj < te_ || (tj == te_ && j < e)) ? 1 : 0;
    }
    rank[e] = r;
}

// chain decomposition (filtered) + round insert + xpart compaction.
// emits per-slot xpart-row (roundx) and source node (roundsrc): no chained gathers later.
__global__ void k_chain(const int* __restrict__ src, const int* __restrict__ rank,
                        const int* __restrict__ scnt, const int* __restrict__ slist,
                        const int* __restrict__ uneed,
                        int* __restrict__ roundcnt, int* __restrict__ roundx, int* __restrict__ roundsrc,
                        int* __restrict__ xcnt, int* __restrict__ xlist, int* __restrict__ xsrc)
{
    __shared__ int lcnt[MAXR];
    __shared__ int lbase[MAXR];
    __shared__ int xl, xb;
    int tid = threadIdx.x;
    if (tid < MAXR) lcnt[tid] = 0;
    if (tid == 0) xl = 0;
    __syncthreads();
    int e = blockIdx.x * 256 + tid;
    int pos = -1, slot = 0, xs = 0, ssave = 0;
    if (e < EE && uneed[src[e]]) {
        int s = src[e];
        int c = scnt[s]; if (c > SCAP) c = SCAP;
        int re = rank[e], be = re / 200;
        bool r_e = true;
        for (int i = 0; i < c; ++i) {
            int rj = rank[slist[s * SCAP + i]];
            if (rj / 200 == be && rj > re) { r_e = false; break; }
        }
        if (r_e) {
            int p = 0;
            for (int i = 0; i < c; ++i) {
                int rj = rank[slist[s * SCAP + i]];
                if (rj >= re) continue;
                int bj = rj / 200;
                bool r_j = true;
                for (int k2 = 0; k2 < c; ++k2) {
                    int rj2 = rank[slist[s * SCAP + k2]];
                    if (rj2 / 200 == bj && rj2 > rj) { r_j = false; break; }
                }
                p += r_j ? 1 : 0;
            }
            if (p < MAXR) { pos = p; ssave = s; slot = atomicAdd(&lcnt[p], 1); xs = atomicAdd(&xl, 1); }
        }
    }
    __syncthreads();
    if (tid < MAXR && lcnt[tid]) lbase[tid] = atomicAdd(&roundcnt[tid], lcnt[tid]);
    if (tid == 0 && xl) xb = atomicAdd(xcnt, xl);
    __syncthreads();
    if (pos >= 0) {
        int xr = xb + xs;
        xlist[xr] = e;
        xsrc[xr] = ssave;
        size_t o = (size_t)pos * EE + lbase[pos] + slot;
        roundx[o] = xr;
        roundsrc[o] = ssave;
    }
}

// ---------------- targeted zero / conversions ----------------

__global__ void k_zmem(const int* __restrict__ ucnt, const int* __restrict__ ulist,
                       float* __restrict__ memb, us* __restrict__ memb_bf)
{
    int total = *ucnt * 64;
    for (int i = blockIdx.x * 256 + threadIdx.x; i < total; i += gridDim.x * 256) {
        int n = ulist[i >> 6], q = i & 63;
        reinterpret_cast<float4*>(memb + (size_t)n * 256)[q] = make_float4(0.f, 0.f, 0.f, 0.f);
        reinterpret_cast<ushort4*>(memb_bf + (size_t)n * 256)[q] = make_ushort4(0, 0, 0, 0);
    }
}

__global__ void k_cvtg(const int* __restrict__ ucnt, const int* __restrict__ ulist,
                       const float* __restrict__ nf, us* __restrict__ nf_bf)
{
    int total = *ucnt * 64;
    for (int i = blockIdx.x * 256 + threadIdx.x; i < total; i += gridDim.x * 256) {
        int n = ulist[i >> 6], q = i & 63;
        float4 v = reinterpret_cast<const float4*>(nf + (size_t)n * 256)[q];
        ushort4 o; o.x = f2b(v.x); o.y = f2b(v.y); o.z = f2b(v.z); o.w = f2b(v.w);
        reinterpret_cast<ushort4*>(nf_bf + (size_t)n * 256)[q] = o;
    }
}

__global__ void k_convL(const int* __restrict__ cnt, const int* __restrict__ list,
                        const float* __restrict__ t, const float* __restrict__ w,
                        const float* __restrict__ b, us* __restrict__ te,
                        const float* __restrict__ ea, us* __restrict__ ea_bf)
{
    int total = *cnt * 32;
    for (int i = blockIdx.x * 256 + threadIdx.x; i < total; i += gridDim.x * 256) {
        int e = list[i >> 5], q = (i & 31) * 4;
        float tv = t[e];
        ushort4 ot;
        ot.x = f2b(sinf(tv * w[q] + b[q]));
        ot.y = f2b(sinf(tv * w[q + 1] + b[q + 1]));
        ot.z = f2b(sinf(tv * w[q + 2] + b[q + 2]));
        ot.w = f2b(sinf(tv * w[q + 3] + b[q + 3]));
        *reinterpret_cast<ushort4*>(te + (size_t)e * 128 + q) = ot;
        float4 v = *reinterpret_cast<const float4*>(ea + (size_t)e * 128 + q);
        ushort4 oa; oa.x = f2b(v.x); oa.y = f2b(v.y); oa.z = f2b(v.z); oa.w = f2b(v.w);
        *reinterpret_cast<ushort4*>(ea_bf + (size_t)e * 128 + q) = oa;
    }
}

__global__ void k_zout(const int* __restrict__ pm, float* __restrict__ outb,
                       float* __restrict__ denom, unsigned* __restrict__ mx)
{
    int i = blockIdx.x * 256 + threadIdx.x;
    int p = i >> 6, q = i & 63;
    if (p >= PP) return;
    int n = pm[p];
    reinterpret_cast<float4*>(outb + (size_t)n * 256)[q] = make_float4(0.f, 0.f, 0.f, 0.f);
    if (q == 0) { denom[n] = 0.f; mx[n] = 0u; }
}

// ---------------- tiled weight transpose (+ gvec block) ----------------

struct WtD { const float* W; us* dst; int K, N, ld, koff, Ktot, toff; };
struct WtA { WtD d[12]; int ntiles; };

__global__ __launch_bounds__(256) void k_wt2(WtA wa, const unsigned* __restrict__ tm,
                                             const float* __restrict__ wt, const float* __restrict__ bt,
                                             const float* __restrict__ Wg, float* __restrict__ gvec)
{
    if ((int)blockIdx.x == wa.ntiles) {
        __shared__ float sv[128];
        int c = threadIdx.x;
        float tmax = funkey(*tm);
        if (c < 128) sv[c] = sinf(tmax * wt[c] + bt[c]);
        __syncthreads();
        float acc = 0.f;
        for (int k = 0; k < 128; ++k) acc += sv[k] * Wg[(size_t)(512 + k) * 256 + c];
        gvec[c] = acc;
        return;
    }
    int bid = blockIdx.x;
    int di = 0;
#pragma unroll
    for (int i = 1; i < 12; ++i) if (bid >= wa.d[i].toff) di = i;
    WtD d = wa.d[di];
    int tt = bid - d.toff;
    int tn = d.N >> 5;
    int k0 = (tt / tn) << 5, n0 = (tt % tn) << 5;
    __shared__ float ld[32][33];
    int tx = threadIdx.x & 31, ty = threadIdx.x >> 5;
#pragma unroll
    for (int i = 0; i < 4; ++i)
        ld[ty + 8 * i][tx] = d.W[(size_t)(k0 + ty + 8 * i) * d.ld + n0 + tx];
    __syncthreads();
#pragma unroll
    for (int i = 0; i < 4; ++i) {
        int n = n0 + ty + 8 * i;
        d.dst[(size_t)n * d.Ktot + d.koff + k0 + tx] = f2b(ld[tx][ty + 8 * i]);
    }
}

// ---------------- MFMA GEMM ----------------
__global__ __launch_bounds__(256) void k_mgemm(
    const us* __restrict__ A1, int K1, const int* __restrict__ idx1,
    const us* __restrict__ A2, int K2, const int* __restrict__ idx2,
    const us* __restrict__ A3, int K3, const int* __restrict__ idx3,
    const us* __restrict__ Wt, int Kloop, int ldw,
    const float* __restrict__ bias,
    const us* __restrict__ Cin, const int* __restrict__ cidx,
    float* __restrict__ outF, us* __restrict__ outB, int ldc,
    int Mhost, const int* __restrict__ mdev, int mbase, int relu, int relua)
{
    int M = Mhost;
    if (mdev) {
        int avail = *mdev - mbase;
        if (avail < 0) avail = 0;
        if (avail < M) M = avail;
    }
    const int row0 = blockIdx.x * 128;
    if (row0 >= M) return;
    const int col0 = blockIdx.y * 64;

    __shared__ us As[128 * 64];
    __shared__ us Bs[64 * 64];

    const int tid = threadIdx.x;
    const int l = tid & 63;
    const int wv = tid >> 6;

    f4v acc[2][4];
#pragma unroll
    for (int i = 0; i < 2; ++i)
#pragma unroll
        for (int j = 0; j < 4; ++j) acc[i][j] = (f4v){0.f, 0.f, 0.f, 0.f};

    for (int k0 = 0; k0 < Kloop; k0 += 64) {
#pragma unroll
        for (int it = 0; it < 4; ++it) {
            int idx = tid + it * 256;
            int r = idx >> 3, q = idx & 7;
            int gk = k0 + q * 8;
            int grow = row0 + r;
            uint4 v = make_uint4(0u, 0u, 0u, 0u);
            if (grow < M) {
                const us* sp; int st, krel, ar = grow;
                if (gk < K1) {
                    sp = A1; st = K1; krel = gk;
                    if (idx1) ar = idx1[ar];
                } else if (gk < K1 + K2) {
                    sp = A2; st = K2; krel = gk - K1;
                    if (idx2) ar = idx2[ar];
                } else {
                    sp = A3; st = K3; krel = gk - K1 - K2;
                    if (idx3) ar = idx3[ar];
                }
                v = *reinterpret_cast<const uint4*>(sp + (size_t)ar * st + krel);
                if (relua) { v.x = relu2bf(v.x); v.y = relu2bf(v.y); v.z = relu2bf(v.z); v.w = relu2bf(v.w); }
            }
            *reinterpret_cast<uint4*>(As + r * 64 + ((q ^ (r & 7)) << 3)) = v;
        }
#pragma unroll
        for (int it = 0; it < 2; ++it) {
            int idx = tid + it * 256;
            int c = idx >> 3, q = idx & 7;
            uint4 v = *reinterpret_cast<const uint4*>(Wt + (size_t)(col0 + c) * ldw + k0 + q * 8);
            *reinterpret_cast<uint4*>(Bs + c * 64 + ((q ^ (c & 7)) << 3)) = v;
        }
        __syncthreads();
#pragma unroll
        for (int ks = 0; ks < 2; ++ks) {
            bf8v af[2], bfr[4];
#pragma unroll
            for (int mf = 0; mf < 2; ++mf) {
                int r = wv * 32 + mf * 16 + (l & 15);
                int q = ks * 4 + (l >> 4);
                af[mf] = *reinterpret_cast<const bf8v*>(As + r * 64 + ((q ^ (r & 7)) << 3));
            }
#pragma unroll
            for (int nf = 0; nf < 4; ++nf) {
                int c = nf * 16 + (l & 15);
                int q = ks * 4 + (l >> 4);
                bfr[nf] = *reinterpret_cast<const bf8v*>(Bs + c * 64 + ((q ^ (c & 7)) << 3));
            }
#pragma unroll
            for (int mf = 0; mf < 2; ++mf)
#pragma unroll
                for (int nf = 0; nf < 4; ++nf)
                    acc[mf][nf] = __builtin_amdgcn_mfma_f32_16x16x32_bf16(af[mf], bfr[nf], acc[mf][nf], 0, 0, 0);
        }
        __syncthreads();
    }

#pragma unroll
    for (int mf = 0; mf < 2; ++mf) {
#pragma unroll
        for (int rr = 0; rr < 4; ++rr) {
            int row = row0 + wv * 32 + mf * 16 + ((l >> 4) * 4) + rr;
            if (row >= M) continue;
            size_t crow = 0;
            if (Cin) crow = (size_t)(cidx ? cidx[row] : row) * ldc;
#pragma unroll
            for (int nf = 0; nf < 4; ++nf) {
                int col = col0 + nf * 16 + (l & 15);
                float v = acc[mf][nf][rr];
                if (bias) v += bias[col];
                if (Cin) v += b2f(Cin[crow + col]);
                if (relu) v = fmaxf(v, 0.f);
                if (outF) outF[(size_t)row * ldc + col] = v;
                if (outB) outB[(size_t)row * ldc + col] = f2b(v);
            }
        }
    }
}

// ---------------- scan helpers ----------------

// contiguous pre-gather of h_prev rows (kills dependent-gather latency in GEMMs)
__global__ void k_hgather(const int* __restrict__ cnt, int cb, int m, const int* __restrict__ rs,
                          const us* __restrict__ mem_bf, us* __restrict__ hprev)
{
    int idx = blockIdx.x * 256 + threadIdx.x;
    int i = idx >> 6, q = idx & 63;
    int avail = *cnt - cb;
    if (avail > m) avail = m;
    if (i >= avail) return;
    int s = rs[i];
    reinterpret_cast<ushort4*>(hprev + (size_t)i * 256)[q] =
        reinterpret_cast<const ushort4*>(mem_bf + (size_t)s * 256)[q];
}

// apply GRU gate from fused gate pre-activations [g0|g1|g2i|g2h] (1024 bf16/row)
__global__ void k_gate(const int* __restrict__ cnt, int cb, int m, const int* __restrict__ rs,
                       const us* __restrict__ gates, const float* __restrict__ bi,
                       const float* __restrict__ bh,
                       float* __restrict__ mem, us* __restrict__ mem_bf)
{
    int i = blockIdx.x;
    int avail = *cnt - cb;
    if (i >= m || i >= avail) return;
    int c = threadIdx.x;
    int s = rs[i];
    float hp = mem[(size_t)s * 256 + c];
    const us* g = gates + (size_t)i * 1024;
    float g0 = b2f(g[c]) + bi[c] + bh[c];
    float g1 = b2f(g[256 + c]) + bi[256 + c] + bh[256 + c];
    float g2i = b2f(g[512 + c]) + bi[512 + c];
    float g2h = b2f(g[768 + c]) + bh[512 + c];
    float r = 1.f / (1.f + expf(-g0));
    float z = 1.f / (1.f + expf(-g1));
    float n = tanhf(g2i + r * g2h);
    float hnew = (1.f - z) * n + z * hp;
    mem[(size_t)s * 256 + c] = hnew;
    mem_bf[(size_t)s * 256 + c] = f2b(hnew);
}

// scalar tail for tiny rounds (j >= 4)
__global__ void k_tail(int j, const int* __restrict__ roundcnt, const int* __restrict__ roundx,
                       const int* __restrict__ roundsrc, const us* __restrict__ xpart_c,
                       float* __restrict__ mem, us* __restrict__ mem_bf,
                       const float* __restrict__ Wm1, const float* __restrict__ Wm2,
                       const float* __restrict__ bm2, const float* __restrict__ Wi,
                       const float* __restrict__ Wh, const float* __restrict__ bi,
                       const float* __restrict__ bh)
{
    int i = blockIdx.x;
    if (i >= roundcnt[j]) return;
    int xr = roundx[(size_t)j * EE + i];
    int s = roundsrc[(size_t)j * EE + i];
    int c = threadIdx.x;
    __shared__ float hs[256];
    __shared__ float xv[256];
    __shared__ float msgv[256];
    __shared__ float giv[768];
    __shared__ float ghv[768];
    hs[c] = mem[(size_t)s * 256 + c];
    __syncthreads();
    float a = b2f(xpart_c[(size_t)xr * 256 + c]);
    for (int k = 0; k < 256; ++k) a += hs[k] * Wm1[(size_t)(256 + k) * 256 + c];
    xv[c] = fmaxf(a, 0.f);
    __syncthreads();
    float m = bm2[c];
    for (int k = 0; k < 256; ++k) m += xv[k] * Wm2[(size_t)k * 256 + c];
    msgv[c] = fmaxf(m, 0.f);
    __syncthreads();
#pragma unroll
    for (int tpart = 0; tpart < 3; ++tpart) {
        int cc = c + tpart * 256;
        float gi_ = bi[cc], gh_ = bh[cc];
        for (int k = 0; k < 256; ++k) {
            gi_ += msgv[k] * Wi[(size_t)k * 768 + cc];
            gh_ += hs[k] * Wh[(size_t)k * 768 + cc];
        }
        giv[cc] = gi_;
        ghv[cc] = gh_;
    }
    __syncthreads();
    float r = 1.f / (1.f + expf(-(giv[c] + ghv[c])));
    float z = 1.f / (1.f + expf(-(giv[256 + c] + ghv[256 + c])));
    float n = tanhf(giv[512 + c] + r * ghv[512 + c]);
    float hnew = (1.f - z) * n + z * hs[c];
    mem[(size_t)s * 256 + c] = hnew;
    mem_bf[(size_t)s * 256 + c] = f2b(hnew);
}

// ---------------- attention / head ----------------

__global__ __launch_bounds__(256) void k_dots(const us* __restrict__ hc, const us* __restrict__ efc,
                                              const int* __restrict__ ucnt, const int* __restrict__ necnt,
                                              const float* __restrict__ v_s, const float* __restrict__ v_d,
                                              const float* __restrict__ v_e,
                                              float* __restrict__ sdot, float* __restrict__ ddot,
                                              float* __restrict__ edot)
{
    int lane = threadIdx.x & 63;
    int row = blockIdx.x * 4 + (threadIdx.x >> 6);
    if (row < NN) {
        if (row >= *ucnt) return;
        ushort4 q = reinterpret_cast<const ushort4*>(hc + (size_t)row * 256)[lane];
        int c = lane * 4;
        float x0 = b2f(q.x), x1 = b2f(q.y), x2 = b2f(q.z), x3 = b2f(q.w);
        float s1 = x0 * v_s[c] + x1 * v_s[c + 1] + x2 * v_s[c + 2] + x3 * v_s[c + 3];
        float s2 = x0 * v_d[c] + x1 * v_d[c + 1] + x2 * v_d[c + 2] + x3 * v_d[c + 3];
#pragma unroll
        for (int o = 32; o > 0; o >>= 1) { s1 += __shfl_xor(s1, o); s2 += __shfl_xor(s2, o); }
        if (lane == 0) { sdot[row] = s1; ddot[row] = s2; }
    } else {
        int i = row - NN;
        if (i >= *necnt) return;
        ushort4 q = reinterpret_cast<const ushort4*>(efc + (size_t)i * 256)[lane];
        int c = lane * 4;
        float s1 = b2f(q.x) * v_e[c] + b2f(q.y) * v_e[c + 1] + b2f(q.z) * v_e[c + 2] + b2f(q.w) * v_e[c + 3];
#pragma unroll
        for (int o = 32; o > 0; o >>= 1) s1 += __shfl_xor(s1, o);
        if (lane == 0) edot[i] = s1;
    }
}

__global__ void k_logitc(const int* __restrict__ necnt, const int* __restrict__ eidx,
                         const int* __restrict__ nidx,
                         const float* __restrict__ sdot, const float* __restrict__ ddot,
                         const float* __restrict__ edot, const int* __restrict__ src,
                         const int* __restrict__ dst, float* __restrict__ logit,
                         unsigned* __restrict__ mx)
{
    int i = blockIdx.x * 256 + threadIdx.x;
    if (i >= *necnt) return;
    int e = eidx[i];
    float l = sdot[nidx[src[e]]] + ddot[nidx[dst[e]]] + edot[i];
    l = (l > 0.f) ? l : 0.2f * l;
    logit[i] = l;
    atomicMax(&mx[dst[e]], fkey(l));
}

__global__ void k_alphac(const int* __restrict__ necnt, const int* __restrict__ eidx,
                         const float* __restrict__ logit, const int* __restrict__ dst,
                         const unsigned* __restrict__ mx, float* __restrict__ alpha,
                         float* __restrict__ denom)
{
    int i = blockIdx.x * 256 + threadIdx.x;
    if (i >= *necnt) return;
    int d = dst[eidx[i]];
    float a = expf(logit[i] - funkey(mx[d]));
    alpha[i] = a;
    atomicAdd(&denom[d], a);
}

__global__ void k_scatc(const int* __restrict__ necnt, const int* __restrict__ eidx,
                        const int* __restrict__ nidx,
                        const float* __restrict__ alpha, const int* __restrict__ src,
                        const int* __restrict__ dst, const us* __restrict__ hc,
                        const us* __restrict__ efc, float* __restrict__ outb)
{
    int i = blockIdx.x * 4 + (threadIdx.x >> 6);
    if (i >= *necnt) return;
    int c4 = threadIdx.x & 63;
    int e = eidx[i];
    float a = alpha[i];
    ushort4 hv = reinterpret_cast<const ushort4*>(hc + (size_t)nidx[src[e]] * 256)[c4];
    ushort4 ev = reinterpret_cast<const ushort4*>(efc + (size_t)i * 256)[c4];
    float* op = outb + (size_t)dst[e] * 256 + c4 * 4;
    atomicAdd(op + 0, a * (b2f(hv.x) + b2f(ev.x)));
    atomicAdd(op + 1, a * (b2f(hv.y) + b2f(ev.y)));
    atomicAdd(op + 2, a * (b2f(hv.z) + b2f(ev.z)));
    atomicAdd(op + 3, a * (b2f(hv.w) + b2f(ev.w)));
}

__global__ void k_pe(const int* __restrict__ pm, const float* __restrict__ outb,
                     const float* __restrict__ denom, us* __restrict__ pe)
{
    int p = blockIdx.x, c = threadIdx.x;
    int n = pm[p];
    pe[(size_t)p * 256 + c] = f2b(outb[(size_t)n * 256 + c] / (denom[n] + 1e-16f));
}

__global__ __launch_bounds__(256) void k_final(const float* __restrict__ c1, const float* __restrict__ Wc2,
                                               const float* __restrict__ bc2, float* __restrict__ out)
{
    int lane = threadIdx.x & 63;
    int row = blockIdx.x * 4 + (threadIdx.x >> 6);
    if (row >= PP) return;
    float s = 0.f;
    for (int c = lane; c < 128; c += 64) s += c1[(size_t)row * 128 + c] * Wc2[c];
#pragma unroll
    for (int off = 32; off > 0; off >>= 1) s += __shfl_xor(s, off);
    if (lane == 0) out[row] = 1.f / (1.f + expf(-(s + bc2[0])));
}

// ---------------- host ----------------

extern "C" void kernel_launch(void* const* d_in, const int* in_sizes, int n_in,
                              void* d_out, int out_size, void* d_ws, size_t ws_size,
                              hipStream_t stream)
{
    (void)in_sizes; (void)n_in; (void)out_size;
    const float* nf    = (const float*)d_in[0];
    const int*   ei    = (const int*)  d_in[1];
    const float* ea    = (const float*)d_in[2];
    const float* t     = (const float*)d_in[3];
    const int*   pm    = (const int*)  d_in[4];
    const float* wt    = (const float*)d_in[5];
    const float* bt    = (const float*)d_in[6];
    const float* Wm1   = (const float*)d_in[7];
    const float* bm1   = (const float*)d_in[8];
    const float* Wm2   = (const float*)d_in[9];
    const float* bm2   = (const float*)d_in[10];
    const float* Wi    = (const float*)d_in[11];
    const float* Wh    = (const float*)d_in[12];
    const float* bi    = (const float*)d_in[13];
    const float* bh    = (const float*)d_in[14];
    const float* Wg    = (const float*)d_in[15];
    const float* We    = (const float*)d_in[16];
    const float* a_src = (const float*)d_in[17];
    const float* a_dst = (const float*)d_in[18];
    const float* a_e   = (const float*)d_in[19];
    const float* Wc1   = (const float*)d_in[20];
    const float* bc1   = (const float*)d_in[21];
    const float* Wc2   = (const float*)d_in[22];
    const float* bc2   = (const float*)d_in[23];
    float* outp = (float*)d_out;
    const int* src = ei;
    const int* dst = ei + EE;

    char* base = (char*)d_ws;
    size_t off = 0;
    auto alloc = [&](size_t bytes) -> void* {
        void* p = base + off;
        off = (off + bytes + 255) & ~(size_t)255;
        return p;
    };
    int* rank      = (int*)alloc((size_t)EE * 4);
    int* roundcnt  = (int*)alloc(64 * 4);          // [0..11] rounds, [32]=tm, [33]=necnt, [34]=ucnt, [35]=xcnt
    int* roundx    = (int*)alloc((size_t)MAXR * EE * 4);
    int* roundsrc  = (int*)alloc((size_t)MAXR * EE * 4);
    int* bsum      = (int*)alloc(256 * 4);
    int* eidx      = (int*)alloc((size_t)EE * 4);
    int* xlist     = (int*)alloc((size_t)EE * 4);
    int* xsrc      = (int*)alloc((size_t)EE * 4);
    int* ulist     = (int*)alloc((size_t)NN * 4);
    int* nidx      = (int*)alloc((size_t)NN * 4);
    us* te_bf    = (us*)alloc((size_t)EE * 128 * 2);
    us* nf_bf    = (us*)alloc((size_t)NN * 256 * 2);
    us* ea_bf    = (us*)alloc((size_t)EE * 128 * 2);
    us* xh       = (us*)alloc((size_t)NN * 256 * 2);   // slist -> xpart_c -> hc
    float* memb  = (float*)alloc((size_t)NN * 256 * 4);
    us* memb_bf  = (us*)alloc((size_t)NN * 256 * 2);
    us* Wt_x    = (us*)alloc((size_t)256 * 512 * 2);
    us* Wt_a    = (us*)alloc((size_t)256 * 256 * 2);
    us* Wt_m2   = (us*)alloc((size_t)256 * 256 * 2);
    us* Wt_gate = (us*)alloc((size_t)1024 * 512 * 2);
    us* Wt_g    = (us*)alloc((size_t)256 * 512 * 2);
    us* Wt_e    = (us*)alloc((size_t)256 * 256 * 2);
    us* Wt_c    = (us*)alloc((size_t)128 * 256 * 2);
    float* gvec  = (float*)alloc(256 * 4);
    float* sdot  = (float*)alloc((size_t)NN * 4);
    float* ddot  = (float*)alloc((size_t)NN * 4);
    float* edot  = (float*)alloc((size_t)EE * 4);
    float* logit = (float*)alloc((size_t)EE * 4);
    float* alpha = (float*)alloc((size_t)EE * 4);
    unsigned* mx = (unsigned*)alloc((size_t)NN * 4);
    float* denom = (float*)alloc((size_t)NN * 4);
    // zeroed mask zone (one memset): needed | uneed | scnt
    int* needed  = (int*)alloc((size_t)NN * 4);
    int* uneed   = (int*)alloc((size_t)NN * 4);
    int* scnt    = (int*)alloc((size_t)NN * 4);
    char* zone_end = base + off;

    size_t region = (ws_size > off + 4096) ? (ws_size - off - 4096) : 0;
    long capL = (long)(region / 3584);
    int CAPR = (int)(capL < 0 ? 0 : capL);
    CAPR = (CAPR / 128) * 128;
    if (CAPR > 28160) CAPR = 28160;
    if (CAPR < 1280) return;   // ws too small (visible failure)
    us* xbuf_bf  = (us*)alloc((size_t)CAPR * 256 * 2);
    us* msg_bf   = (us*)alloc((size_t)CAPR * 256 * 2);
    us* hprev_c  = (us*)alloc((size_t)CAPR * 256 * 2);
    us* gates_bf = (us*)alloc((size_t)CAPR * 1024 * 2);
    if (off > ws_size) return;

    unsigned* tm = (unsigned*)&roundcnt[32];
    int* necnt   = &roundcnt[33];
    int* ucnt    = &roundcnt[34];
    int* xcnt    = &roundcnt[35];
    // bucket-sort scratch aliases roundx (dead until k_chain)
    int* hist  = roundx;
    int* hcur  = roundx + NB;
    int* hbase = roundx + 2 * NB;
    int* blist = roundx + 3 * NB;
    // aliases in xh: slist (until k_chain) -> xpart_c (until tails) -> hc (after)
    int* slist = (int*)xh;
    us* xpart_c = xh;
    us* hc = xh;
    us* ef_c = nf_bf;                  // nf_bf dead after h-GEMM
    float* outb = memb;                // f32 mem dead post-scan
    us* pe_bf = te_bf;                 // te dead after ef GEMM
    float* c1 = (float*)(te_bf + (size_t)PP * 256);

    const dim3 B(256);
    const int gE = (EE + 255) / 256;
    const int gN = (NN + 255) / 256;

    hipMemsetAsync(roundcnt, 0, 64 * 4, stream);
    hipMemsetAsync(hist, 0, (size_t)2 * NB * 4, stream);                  // hist + hcur
    hipMemsetAsync(needed, 0, (size_t)(zone_end - (char*)needed), stream);
    hipMemsetAsync(Wt_gate, 0, (size_t)1024 * 512 * 2, stream);           // zero-pad for g2i/g2h halves

    k_need<<<(PP + 255) / 256, B, 0, stream>>>(pm, needed);
    k_elist<<<gE, B, 0, stream>>>(src, dst, needed, necnt, eidx, uneed);
    k_ulist<<<gN, B, 0, stream>>>(uneed, ucnt, ulist, nidx);

    k_prep<<<gE, B, 0, stream>>>(t, src, hist, scnt, slist, tm);
    k_scan1<<<256, B, 0, stream>>>(hist, hbase, bsum);
    k_scan2<<<1, B, 0, stream>>>(bsum);
    k_scan3<<<256, B, 0, stream>>>(hbase, bsum);
    k_bscatter<<<gE, B, 0, stream>>>(t, hbase, hcur, blist);
    k_rank2<<<gE, B, 0, stream>>>(t, hbase, hist, blist, rank);
    k_chain<<<gE, B, 0, stream>>>(src, rank, scnt, slist, uneed, roundcnt, roundx, roundsrc,
                                  xcnt, xlist, xsrc);

    k_zmem<<<1024, B, 0, stream>>>(ucnt, ulist, memb, memb_bf);
    k_cvtg<<<1024, B, 0, stream>>>(ucnt, ulist, nf, nf_bf);
    k_convL<<<1024, B, 0, stream>>>(xcnt, xlist, t, wt, bt, te_bf, ea, ea_bf);
    k_convL<<<1024, B, 0, stream>>>(necnt, eidx, t, wt, bt, te_bf, ea, ea_bf);

    // tiled weight transposes + gvec; Wt_gate = [Wi;Wh | g2i(Wi,0) | g2h(0,Wh)] (1024 x 512)
    {
        WtA wa;
        int o = 0;
        auto set = [&](int i, const float* W, us* dstp, int K, int N, int ld, int koff, int Ktot) {
            wa.d[i] = WtD{W, dstp, K, N, ld, koff, Ktot, o};
            o += (K >> 5) * (N >> 5);
        };
        set(0, Wm1, Wt_x, 256, 256, 256, 0, 512);
        set(1, Wm1 + (size_t)512 * 256, Wt_x, 128, 256, 256, 256, 512);
        set(2, Wm1 + (size_t)640 * 256, Wt_x, 128, 256, 256, 384, 512);
        set(3, Wm1 + (size_t)256 * 256, Wt_a, 256, 256, 256, 0, 256);
        set(4, Wm2, Wt_m2, 256, 256, 256, 0, 256);
        set(5, Wi, Wt_gate, 256, 512, 768, 0, 512);
        set(6, Wh, Wt_gate, 256, 512, 768, 256, 512);
        set(7, Wi + 512, Wt_gate + (size_t)512 * 512, 256, 256, 768, 0, 512);
        set(8, Wh + 512, Wt_gate + (size_t)768 * 512, 256, 256, 768, 256, 512);
        set(9, Wg, Wt_g, 512, 256, 256, 0, 512);
        set(10, We, Wt_e, 256, 256, 256, 0, 256);
        set(11, Wc1, Wt_c, 256, 128, 128, 0, 256);
        wa.ntiles = o;
        k_wt2<<<o + 1, B, 0, stream>>>(wa, tm, wt, bt, Wg, gvec);
    }

    // xpart (compact) = bm1 + nf[xsrc]@Wm1[0:256] + ea[xlist]@.. + te[xlist]@..
    const int gxE = (EE + 127) / 128;
    k_mgemm<<<dim3(gxE, 4), B, 0, stream>>>(nf_bf, 256, xsrc, ea_bf, 128, xlist,
        te_bf, 128, xlist, Wt_x, 512, 512, bm1, nullptr, nullptr,
        nullptr, xpart_c, 256, EE, xcnt, 0, 0, 0);

    // chain rounds 0..3: msg GEMM + fused gate GEMM + elementwise gate
    for (int j = 0; j < 4; ++j) {
        int bound = EE / (j + 1);
        for (int cb = 0; cb < bound; cb += CAPR) {
            int m = bound - cb; if (m > CAPR) m = CAPR;
            int gx = (m + 127) / 128;
            const int* rx = roundx + (size_t)j * EE + cb;
            const int* rs = roundsrc + (size_t)j * EE + cb;
            if (j == 0) {
                // h_prev == 0: msg = relu(relu(xpart)@Wm2+bm2); gates = msg@Wt_gate (K=256 half)
                k_mgemm<<<dim3(gx, 4), B, 0, stream>>>(xpart_c, 256, rx, nullptr, 0, nullptr,
                    nullptr, 0, nullptr, Wt_m2, 256, 256, bm2, nullptr, nullptr,
                    nullptr, msg_bf, 256, m, roundcnt + j, cb, 1, 1);
                k_mgemm<<<dim3(gx, 16), B, 0, stream>>>(msg_bf, 256, nullptr, nullptr, 0, nullptr,
                    nullptr, 0, nullptr, Wt_gate, 256, 512, nullptr, nullptr, nullptr,
                    nullptr, gates_bf, 1024, m, roundcnt + j, cb, 0, 0);
            } else {
                k_hgather<<<(m * 64 + 255) / 256, B, 0, stream>>>(roundcnt + j, cb, m, rs, memb_bf, hprev_c);
                k_mgemm<<<dim3(gx, 4), B, 0, stream>>>(hprev_c, 256, nullptr, nullptr, 0, nullptr,
                    nullptr, 0, nullptr, Wt_a, 256, 256, nullptr, xpart_c, rx,
                    nullptr, xbuf_bf, 256, m, roundcnt + j, cb, 1, 0);
                k_mgemm<<<dim3(gx, 4), B, 0, stream>>>(xbuf_bf, 256, nullptr, nullptr, 0, nullptr,
                    nullptr, 0, nullptr, Wt_m2, 256, 256, bm2, nullptr, nullptr,
                    nullptr, msg_bf, 256, m, roundcnt + j, cb, 1, 0);
                k_mgemm<<<dim3(gx, 16), B, 0, stream>>>(msg_bf, 256, nullptr, hprev_c, 256, nullptr,
                    nullptr, 0, nullptr, Wt_gate, 512, 512, nullptr, nullptr, nullptr,
                    nullptr, gates_bf, 1024, m, roundcnt + j, cb, 0, 0);
            }
            k_gate<<<m, B, 0, stream>>>(roundcnt + j, cb, m, rs, gates_bf, bi, bh, memb, memb_bf);
        }
    }
    for (int j = 4; j < MAXR; ++j) {
        int bound = (EE + j) / (j + 1);
        k_tail<<<bound, B, 0, stream>>>(j, roundcnt, roundx, roundsrc, xpart_c, memb, memb_bf,
                                        Wm1, Wm2, bm2, Wi, Wh, bi, bh);
    }

    k_zout<<<(PP * 64 + 255) / 256, B, 0, stream>>>(pm, outb, denom, mx);

    // h (compact U rows) = [nf | mem]@Wg + gvec bias
    const int gxN = (NN + 127) / 128;
    k_mgemm<<<dim3(gxN, 4), B, 0, stream>>>(nf_bf, 256, ulist, memb_bf, 256, ulist,
        nullptr, 0, nullptr, Wt_g, 512, 512, gvec, nullptr, nullptr,
        nullptr, hc, 256, NN, ucnt, 0, 0, 0);

    // ef (compact needed edges) = [ea | te](eidx) @ We
    k_mgemm<<<dim3(gxE, 4), B, 0, stream>>>(ea_bf, 128, eidx, te_bf, 128, eidx,
        nullptr, 0, nullptr, Wt_e, 256, 256, nullptr, nullptr, nullptr,
        nullptr, ef_c, 256, EE, necnt, 0, 0, 0);

    k_dots<<<(NN + EE + 3) / 4, B, 0, stream>>>(hc, ef_c, ucnt, necnt, a_src, a_dst, a_e, sdot, ddot, edot);

    k_logitc<<<gE, B, 0, stream>>>(necnt, eidx, nidx, sdot, ddot, edot, src, dst, logit, mx);
    k_alphac<<<gE, B, 0, stream>>>(necnt, eidx, logit, dst, mx, alpha, denom);
    k_scatc<<<(EE + 3) / 4, B, 0, stream>>>(necnt, eidx, nidx, alpha, src, dst, hc, ef_c, outb);

    k_pe<<<PP, B, 0, stream>>>(pm, outb, denom, pe_bf);
    k_mgemm<<<dim3((PP + 127) / 128, 2), B, 0, stream>>>(pe_bf, 256, nullptr, nullptr, 0, nullptr,
        nullptr, 0, nullptr, Wt_c, 256, 256, bc1, nullptr, nullptr,
        c1, nullptr, 128, PP, nullptr, 0, 1, 0);
    k_final<<<(PP + 3) / 4, B, 0, stream>>>(c1, Wc2, bc2, outp);
}

// Round 8
// 581.770 us; speedup vs baseline: 5.2825x; 1.0797x over previous
//
#include <hip/hip_runtime.h>

#define NN 50000
#define EE 40000
#define PP 4096
#define MAXR 12
#define SCAP 16
#define NB 65536

typedef unsigned short us;
typedef __attribute__((ext_vector_type(8))) short bf8v;
typedef __attribute__((ext_vector_type(4))) float f4v;

__device__ __forceinline__ us f2b(float x) {
    unsigned u = __float_as_uint(x);
    u = (u + 0x7fffu + ((u >> 16) & 1u)) >> 16;
    return (us)u;
}
__device__ __forceinline__ float b2f(us h) {
    return __uint_as_float(((unsigned)h) << 16);
}
__device__ __forceinline__ unsigned fkey(float f) {
    unsigned u = __float_as_uint(f);
    return (u & 0x80000000u) ? ~u : (u | 0x80000000u);
}
__device__ __forceinline__ float funkey(unsigned k) {
    unsigned u = (k & 0x80000000u) ? (k & 0x7fffffffu) : ~k;
    return __uint_as_float(u);
}
__device__ __forceinline__ int bucket_of(float tv) {
    int b = (int)(tv * 65536.0f);
    if (b < 0) b = 0;
    if (b > 65535) b = 65535;
    return b;
}
__device__ __forceinline__ unsigned relu2bf(unsigned u) {
    unsigned lo = (u & 0x8000u) ? 0u : (u & 0xFFFFu);
    unsigned hi = (u & 0x80000000u) ? 0u : (u & 0xFFFF0000u);
    return lo | hi;
}
__device__ __forceinline__ float dot8u(uint4 w, const us* __restrict__ v, int k2) {
    return b2f((us)(w.x & 0xffffu)) * b2f(v[k2])     + b2f((us)(w.x >> 16)) * b2f(v[k2 + 1])
         + b2f((us)(w.y & 0xffffu)) * b2f(v[k2 + 2]) + b2f((us)(w.y >> 16)) * b2f(v[k2 + 3])
         + b2f((us)(w.z & 0xffffu)) * b2f(v[k2 + 4]) + b2f((us)(w.z >> 16)) * b2f(v[k2 + 5])
         + b2f((us)(w.w & 0xffffu)) * b2f(v[k2 + 6]) + b2f((us)(w.w >> 16)) * b2f(v[k2 + 7]);
}

// ---------------- needed nodes / edges / U-set ----------------

__global__ void k_need(const int* __restrict__ pm, int* __restrict__ needed)
{
    int i = blockIdx.x * 256 + threadIdx.x;
    if (i < PP) needed[pm[i]] = 1;
}

__global__ void k_elist(const int* __restrict__ src, const int* __restrict__ dst,
                        const int* __restrict__ needed, int* __restrict__ necnt,
                        int* __restrict__ eidx, int* __restrict__ uneed)
{
    __shared__ int lc, lb;
    if (threadIdx.x == 0) lc = 0;
    __syncthreads();
    int e = blockIdx.x * 256 + threadIdx.x;
    int slot = -1;
    if (e < EE && needed[dst[e]]) {
        slot = atomicAdd(&lc, 1);
        uneed[dst[e]] = 1;
        uneed[src[e]] = 1;
    }
    __syncthreads();
    if (threadIdx.x == 0 && lc) lb = atomicAdd(necnt, lc);
    __syncthreads();
    if (slot >= 0) eidx[lb + slot] = e;
}

__global__ void k_ulist(const int* __restrict__ uneed, int* __restrict__ ucnt,
                        int* __restrict__ ulist, int* __restrict__ nidx)
{
    __shared__ int lc, lb;
    if (threadIdx.x == 0) lc = 0;
    __syncthreads();
    int n = blockIdx.x * 256 + threadIdx.x;
    int slot = -1;
    if (n < NN && uneed[n]) slot = atomicAdd(&lc, 1);
    __syncthreads();
    if (threadIdx.x == 0 && lc) lb = atomicAdd(ucnt, lc);
    __syncthreads();
    if (slot >= 0) { ulist[lb + slot] = n; nidx[n] = lb + slot; }
}

// ---------------- ordering ----------------

__global__ __launch_bounds__(256) void k_prep(const float* __restrict__ t, const int* __restrict__ src,
                                              int* __restrict__ hist, int* __restrict__ scnt,
                                              int* __restrict__ slist, unsigned* __restrict__ tm)
{
    int e = blockIdx.x * 256 + threadIdx.x;
    float v = 0.f;
    if (e < EE) {
        float tv = t[e];
        v = tv;
        atomicAdd(&hist[bucket_of(tv)], 1);
        int s = src[e];
        int slot = atomicAdd(&scnt[s], 1);
        if (slot < SCAP) slist[s * SCAP + slot] = e;
    }
#pragma unroll
    for (int o = 32; o > 0; o >>= 1) v = fmaxf(v, __shfl_xor(v, o));
    if ((threadIdx.x & 63) == 0) atomicMax(tm, fkey(v));
}

__global__ void k_scan1(const int* __restrict__ hist, int* __restrict__ hbase, int* __restrict__ bsum)
{
    __shared__ int s[256];
    int i = blockIdx.x * 256 + threadIdx.x;
    int v = hist[i];
    s[threadIdx.x] = v;
    __syncthreads();
    for (int o = 1; o < 256; o <<= 1) {
        int x = (threadIdx.x >= o) ? s[threadIdx.x - o] : 0;
        __syncthreads();
        s[threadIdx.x] += x;
        __syncthreads();
    }
    hbase[i] = s[threadIdx.x] - v;
    if (threadIdx.x == 255) bsum[blockIdx.x] = s[255];
}

__global__ void k_scan2(int* __restrict__ bsum)
{
    __shared__ int s[256];
    int v = bsum[threadIdx.x];
    s[threadIdx.x] = v;
    __syncthreads();
    for (int o = 1; o < 256; o <<= 1) {
        int x = (threadIdx.x >= o) ? s[threadIdx.x - o] : 0;
        __syncthreads();
        s[threadIdx.x] += x;
        __syncthreads();
    }
    bsum[threadIdx.x] = s[threadIdx.x] - v;
}

__global__ void k_scan3(int* __restrict__ hbase, const int* __restrict__ bsum)
{
    int i = blockIdx.x * 256 + threadIdx.x;
    hbase[i] += bsum[blockIdx.x];
}

__global__ void k_bscatter(const float* __restrict__ t, const int* __restrict__ hbase,
                           int* __restrict__ hcur, int* __restrict__ blist)
{
    int e = blockIdx.x * 256 + threadIdx.x;
    if (e >= EE) return;
    int b = bucket_of(t[e]);
    int p = hbase[b] + atomicAdd(&hcur[b], 1);
    blist[p] = e;
}

__global__ void k_rank2(const float* __restrict__ t, const int* __restrict__ hbase,
                        const int* __restrict__ hist, const int* __restrict__ blist,
                        int* __restrict__ rank)
{
    int e = blockIdx.x * 256 + threadIdx.x;
    if (e >= EE) return;
    float te_ = t[e];
    int b = bucket_of(te_);
    int base = hbase[b], cnt = hist[b];
    int r = base;
    for (int i = 0; i < cnt; ++i) {
        int j = blist[base + i];
        float tj = t[j];
        r += (tj < te_ || (tj == te_ && j < e)) ? 1 : 0;
    }
    rank[e] = r;
}

// chain decomposition (filtered) + round insert + xpart compaction
__global__ void k_chain(const int* __restrict__ src, const int* __restrict__ rank,
                        const int* __restrict__ scnt, const int* __restrict__ slist,
                        const int* __restrict__ uneed,
                        int* __restrict__ roundcnt, int* __restrict__ roundx, int* __restrict__ roundsrc,
                        int* __restrict__ xcnt, int* __restrict__ xlist, int* __restrict__ xsrc)
{
    __shared__ int lcnt[MAXR];
    __shared__ int lbase[MAXR];
    __shared__ int xl, xb;
    int tid = threadIdx.x;
    if (tid < MAXR) lcnt[tid] = 0;
    if (tid == 0) xl = 0;
    __syncthreads();
    int e = blockIdx.x * 256 + tid;
    int pos = -1, slot = 0, xs = 0, ssave = 0;
    if (e < EE && uneed[src[e]]) {
        int s = src[e];
        int c = scnt[s]; if (c > SCAP) c = SCAP;
        int re = rank[e], be = re / 200;
        bool r_e = true;
        for (int i = 0; i < c; ++i) {
            int rj = rank[slist[s * SCAP + i]];
            if (rj / 200 == be && rj > re) { r_e = false; break; }
        }
        if (r_e) {
            int p = 0;
            for (int i = 0; i < c; ++i) {
                int rj = rank[slist[s * SCAP + i]];
                if (rj >= re) continue;
                int bj = rj / 200;
                bool r_j = true;
                for (int k2 = 0; k2 < c; ++k2) {
                    int rj2 = rank[slist[s * SCAP + k2]];
                    if (rj2 / 200 == bj && rj2 > rj) { r_j = false; break; }
                }
                p += r_j ? 1 : 0;
            }
            if (p < MAXR) { pos = p; ssave = s; slot = atomicAdd(&lcnt[p], 1); xs = atomicAdd(&xl, 1); }
        }
    }
    __syncthreads();
    if (tid < MAXR && lcnt[tid]) lbase[tid] = atomicAdd(&roundcnt[tid], lcnt[tid]);
    if (tid == 0 && xl) xb = atomicAdd(xcnt, xl);
    __syncthreads();
    if (pos >= 0) {
        int xr = xb + xs;
        xlist[xr] = e;
        xsrc[xr] = ssave;
        size_t o = (size_t)pos * EE + lbase[pos] + slot;
        roundx[o] = xr;
        roundsrc[o] = ssave;
    }
}

// ---------------- targeted zero / conversions ----------------

__global__ void k_zmem(const int* __restrict__ ucnt, const int* __restrict__ ulist,
                       float* __restrict__ memb, us* __restrict__ memb_bf)
{
    int total = *ucnt * 64;
    for (int i = blockIdx.x * 256 + threadIdx.x; i < total; i += gridDim.x * 256) {
        int n = ulist[i >> 6], q = i & 63;
        reinterpret_cast<float4*>(memb + (size_t)n * 256)[q] = make_float4(0.f, 0.f, 0.f, 0.f);
        reinterpret_cast<ushort4*>(memb_bf + (size_t)n * 256)[q] = make_ushort4(0, 0, 0, 0);
    }
}

__global__ void k_cvtg(const int* __restrict__ ucnt, const int* __restrict__ ulist,
                       const float* __restrict__ nf, us* __restrict__ nf_bf)
{
    int total = *ucnt * 64;
    for (int i = blockIdx.x * 256 + threadIdx.x; i < total; i += gridDim.x * 256) {
        int n = ulist[i >> 6], q = i & 63;
        float4 v = reinterpret_cast<const float4*>(nf + (size_t)n * 256)[q];
        ushort4 o; o.x = f2b(v.x); o.y = f2b(v.y); o.z = f2b(v.z); o.w = f2b(v.w);
        reinterpret_cast<ushort4*>(nf_bf + (size_t)n * 256)[q] = o;
    }
}

__global__ void k_convL(const int* __restrict__ cnt, const int* __restrict__ list,
                        const float* __restrict__ t, const float* __restrict__ w,
                        const float* __restrict__ b, us* __restrict__ te,
                        const float* __restrict__ ea, us* __restrict__ ea_bf)
{
    int total = *cnt * 32;
    for (int i = blockIdx.x * 256 + threadIdx.x; i < total; i += gridDim.x * 256) {
        int e = list[i >> 5], q = (i & 31) * 4;
        float tv = t[e];
        ushort4 ot;
        ot.x = f2b(sinf(tv * w[q] + b[q]));
        ot.y = f2b(sinf(tv * w[q + 1] + b[q + 1]));
        ot.z = f2b(sinf(tv * w[q + 2] + b[q + 2]));
        ot.w = f2b(sinf(tv * w[q + 3] + b[q + 3]));
        *reinterpret_cast<ushort4*>(te + (size_t)e * 128 + q) = ot;
        float4 v = *reinterpret_cast<const float4*>(ea + (size_t)e * 128 + q);
        ushort4 oa; oa.x = f2b(v.x); oa.y = f2b(v.y); oa.z = f2b(v.z); oa.w = f2b(v.w);
        *reinterpret_cast<ushort4*>(ea_bf + (size_t)e * 128 + q) = oa;
    }
}

__global__ void k_zout(const int* __restrict__ pm, float* __restrict__ outb,
                       float* __restrict__ denom, unsigned* __restrict__ mx)
{
    int i = blockIdx.x * 256 + threadIdx.x;
    int p = i >> 6, q = i & 63;
    if (p >= PP) return;
    int n = pm[p];
    reinterpret_cast<float4*>(outb + (size_t)n * 256)[q] = make_float4(0.f, 0.f, 0.f, 0.f);
    if (q == 0) { denom[n] = 0.f; mx[n] = 0u; }
}

// ---------------- tiled weight transpose (+ gvec block) ----------------

struct WtD { const float* W; us* dst; int K, N, ld, koff, Ktot, toff; };
struct WtA { WtD d[12]; int ntiles; };

__global__ __launch_bounds__(256) void k_wt2(WtA wa, const unsigned* __restrict__ tm,
                                             const float* __restrict__ wt, const float* __restrict__ bt,
                                             const float* __restrict__ Wg, float* __restrict__ gvec)
{
    if ((int)blockIdx.x == wa.ntiles) {
        __shared__ float sv[128];
        int c = threadIdx.x;
        float tmax = funkey(*tm);
        if (c < 128) sv[c] = sinf(tmax * wt[c] + bt[c]);
        __syncthreads();
        float acc = 0.f;
        for (int k = 0; k < 128; ++k) acc += sv[k] * Wg[(size_t)(512 + k) * 256 + c];
        gvec[c] = acc;
        return;
    }
    int bid = blockIdx.x;
    int di = 0;
#pragma unroll
    for (int i = 1; i < 12; ++i) if (bid >= wa.d[i].toff) di = i;
    WtD d = wa.d[di];
    int tt = bid - d.toff;
    int tn = d.N >> 5;
    int k0 = (tt / tn) << 5, n0 = (tt % tn) << 5;
    __shared__ float ld[32][33];
    int tx = threadIdx.x & 31, ty = threadIdx.x >> 5;
#pragma unroll
    for (int i = 0; i < 4; ++i)
        ld[ty + 8 * i][tx] = d.W[(size_t)(k0 + ty + 8 * i) * d.ld + n0 + tx];
    __syncthreads();
#pragma unroll
    for (int i = 0; i < 4; ++i) {
        int n = n0 + ty + 8 * i;
        d.dst[(size_t)n * d.Ktot + d.koff + k0 + tx] = f2b(ld[tx][ty + 8 * i]);
    }
}

// ---------------- MFMA GEMM ----------------
__global__ __launch_bounds__(256) void k_mgemm(
    const us* __restrict__ A1, int K1, const int* __restrict__ idx1,
    const us* __restrict__ A2, int K2, const int* __restrict__ idx2,
    const us* __restrict__ A3, int K3, const int* __restrict__ idx3,
    const us* __restrict__ Wt, int Kloop, int ldw,
    const float* __restrict__ bias,
    const us* __restrict__ Cin, const int* __restrict__ cidx,
    float* __restrict__ outF, us* __restrict__ outB, int ldc,
    int Mhost, const int* __restrict__ mdev, int mbase, int relu, int relua)
{
    int M = Mhost;
    if (mdev) {
        int avail = *mdev - mbase;
        if (avail < 0) avail = 0;
        if (avail < M) M = avail;
    }
    const int row0 = blockIdx.x * 128;
    if (row0 >= M) return;
    const int col0 = blockIdx.y * 64;

    __shared__ us As[128 * 64];
    __shared__ us Bs[64 * 64];

    const int tid = threadIdx.x;
    const int l = tid & 63;
    const int wv = tid >> 6;

    f4v acc[2][4];
#pragma unroll
    for (int i = 0; i < 2; ++i)
#pragma unroll
        for (int j = 0; j < 4; ++j) acc[i][j] = (f4v){0.f, 0.f, 0.f, 0.f};

    for (int k0 = 0; k0 < Kloop; k0 += 64) {
#pragma unroll
        for (int it = 0; it < 4; ++it) {
            int idx = tid + it * 256;
            int r = idx >> 3, q = idx & 7;
            int gk = k0 + q * 8;
            int grow = row0 + r;
            uint4 v = make_uint4(0u, 0u, 0u, 0u);
            if (grow < M) {
                const us* sp; int st, krel, ar = grow;
                if (gk < K1) {
                    sp = A1; st = K1; krel = gk;
                    if (idx1) ar = idx1[ar];
                } else if (gk < K1 + K2) {
                    sp = A2; st = K2; krel = gk - K1;
                    if (idx2) ar = idx2[ar];
                } else {
                    sp = A3; st = K3; krel = gk - K1 - K2;
                    if (idx3) ar = idx3[ar];
                }
                v = *reinterpret_cast<const uint4*>(sp + (size_t)ar * st + krel);
                if (relua) { v.x = relu2bf(v.x); v.y = relu2bf(v.y); v.z = relu2bf(v.z); v.w = relu2bf(v.w); }
            }
            *reinterpret_cast<uint4*>(As + r * 64 + ((q ^ (r & 7)) << 3)) = v;
        }
#pragma unroll
        for (int it = 0; it < 2; ++it) {
            int idx = tid + it * 256;
            int c = idx >> 3, q = idx & 7;
            uint4 v = *reinterpret_cast<const uint4*>(Wt + (size_t)(col0 + c) * ldw + k0 + q * 8);
            *reinterpret_cast<uint4*>(Bs + c * 64 + ((q ^ (c & 7)) << 3)) = v;
        }
        __syncthreads();
#pragma unroll
        for (int ks = 0; ks < 2; ++ks) {
            bf8v af[2], bfr[4];
#pragma unroll
            for (int mf = 0; mf < 2; ++mf) {
                int r = wv * 32 + mf * 16 + (l & 15);
                int q = ks * 4 + (l >> 4);
                af[mf] = *reinterpret_cast<const bf8v*>(As + r * 64 + ((q ^ (r & 7)) << 3));
            }
#pragma unroll
            for (int nf = 0; nf < 4; ++nf) {
                int c = nf * 16 + (l & 15);
                int q = ks * 4 + (l >> 4);
                bfr[nf] = *reinterpret_cast<const bf8v*>(Bs + c * 64 + ((q ^ (c & 7)) << 3));
            }
#pragma unroll
            for (int mf = 0; mf < 2; ++mf)
#pragma unroll
                for (int nf = 0; nf < 4; ++nf)
                    acc[mf][nf] = __builtin_amdgcn_mfma_f32_16x16x32_bf16(af[mf], bfr[nf], acc[mf][nf], 0, 0, 0);
        }
        __syncthreads();
    }

#pragma unroll
    for (int mf = 0; mf < 2; ++mf) {
#pragma unroll
        for (int rr = 0; rr < 4; ++rr) {
            int row = row0 + wv * 32 + mf * 16 + ((l >> 4) * 4) + rr;
            if (row >= M) continue;
            size_t crow = 0;
            if (Cin) crow = (size_t)(cidx ? cidx[row] : row) * ldc;
#pragma unroll
            for (int nf = 0; nf < 4; ++nf) {
                int col = col0 + nf * 16 + (l & 15);
                float v = acc[mf][nf][rr];
                if (bias) v += bias[col];
                if (Cin) v += b2f(Cin[crow + col]);
                if (relu) v = fmaxf(v, 0.f);
                if (outF) outF[(size_t)row * ldc + col] = v;
                if (outB) outB[(size_t)row * ldc + col] = f2b(v);
            }
        }
    }
}

// ---------------- scan helpers ----------------

__global__ void k_hgather(const int* __restrict__ cnt, int cb, int m, const int* __restrict__ rs,
                          const us* __restrict__ mem_bf, us* __restrict__ hprev)
{
    int idx = blockIdx.x * 256 + threadIdx.x;
    int i = idx >> 6, q = idx & 63;
    int avail = *cnt - cb;
    if (avail > m) avail = m;
    if (i >= avail) return;
    int s = rs[i];
    reinterpret_cast<ushort4*>(hprev + (size_t)i * 256)[q] =
        reinterpret_cast<const ushort4*>(mem_bf + (size_t)s * 256)[q];
}

__global__ void k_gate(const int* __restrict__ cnt, int cb, int m, const int* __restrict__ rs,
                       const us* __restrict__ gates, const float* __restrict__ bi,
                       const float* __restrict__ bh,
                       float* __restrict__ mem, us* __restrict__ mem_bf)
{
    int i = blockIdx.x;
    int avail = *cnt - cb;
    if (i >= m || i >= avail) return;
    int c = threadIdx.x;
    int s = rs[i];
    float hp = mem[(size_t)s * 256 + c];
    const us* g = gates + (size_t)i * 1024;
    float g0 = b2f(g[c]) + bi[c] + bh[c];
    float g1 = b2f(g[256 + c]) + bi[256 + c] + bh[256 + c];
    float g2i = b2f(g[512 + c]) + bi[512 + c];
    float g2h = b2f(g[768 + c]) + bh[512 + c];
    float r = 1.f / (1.f + expf(-g0));
    float z = 1.f / (1.f + expf(-g1));
    float n = tanhf(g2i + r * g2h);
    float hnew = (1.f - z) * n + z * hp;
    mem[(size_t)s * 256 + c] = hnew;
    mem_bf[(size_t)s * 256 + c] = f2b(hnew);
}

// build per-source tail chains: tx[i][k] = xpart row of round-(4+k) edge of source i (round-4 anchor)
__global__ void k_tbuild(const int* __restrict__ roundcnt, const int* __restrict__ roundx,
                         const int* __restrict__ roundsrc, int* __restrict__ tx)
{
    int i = blockIdx.x * 256 + threadIdx.x;
    if (i >= roundcnt[4]) return;
    int s = roundsrc[(size_t)4 * EE + i];
    tx[i * 8 + 0] = roundx[(size_t)4 * EE + i];
#pragma unroll
    for (int k = 1; k < 8; ++k) tx[i * 8 + k] = -1;
    for (int j = 5; j < MAXR; ++j) {
        int cj = roundcnt[j];
        for (int m2 = 0; m2 < cj; ++m2) {
            if (roundsrc[(size_t)j * EE + m2] == s) {
                tx[i * 8 + (j - 4)] = roundx[(size_t)j * EE + m2];
                break;
            }
        }
    }
}

// one block per tail source; walks chain positions 4..11 sequentially (bf16 weights, L2-hot)
__global__ __launch_bounds__(256) void k_tailchain(
    const int* __restrict__ roundcnt, const int* __restrict__ roundsrc, const int* __restrict__ tx,
    const us* __restrict__ xpart_c, const us* __restrict__ Wt_a, const us* __restrict__ Wt_m2,
    const us* __restrict__ Wt_gate, const float* __restrict__ bm2,
    const float* __restrict__ bi, const float* __restrict__ bh,
    float* __restrict__ mem, us* __restrict__ mem_bf)
{
    int i = blockIdx.x;
    if (i >= roundcnt[4]) return;
    int s = roundsrc[(size_t)4 * EE + i];
    int c = threadIdx.x;
    __shared__ us hb[256];
    __shared__ us xv[256];
    __shared__ us msgv[256];
    float hp = mem[(size_t)s * 256 + c];
    hb[c] = mem_bf[(size_t)s * 256 + c];
    for (int k = 0; k < 8; ++k) {
        int xr = tx[i * 8 + k];
        if (xr < 0) break;
        __syncthreads();
        // phase1: xv = relu(xpart + h@Wm1a)
        float a = b2f(xpart_c[(size_t)xr * 256 + c]);
        const us* wa = Wt_a + (size_t)c * 256;
#pragma unroll 4
        for (int k2 = 0; k2 < 256; k2 += 8)
            a += dot8u(*reinterpret_cast<const uint4*>(wa + k2), hb, k2);
        xv[c] = f2b(fmaxf(a, 0.f));
        __syncthreads();
        // phase2: msg = relu(xv@Wm2 + bm2)
        float m = bm2[c];
        const us* wm = Wt_m2 + (size_t)c * 256;
#pragma unroll 4
        for (int k2 = 0; k2 < 256; k2 += 8)
            m += dot8u(*reinterpret_cast<const uint4*>(wm + k2), xv, k2);
        msgv[c] = f2b(fmaxf(m, 0.f));
        __syncthreads();
        // phase3: gates from Wt_gate ([Wi;Wh] for r,z; Wi-only g2i; Wh-only g2h)
        const us* w0 = Wt_gate + (size_t)c * 512;
        const us* w1 = Wt_gate + (size_t)(256 + c) * 512;
        const us* w2 = Wt_gate + (size_t)(512 + c) * 512;
        const us* w3 = Wt_gate + (size_t)(768 + c) * 512;
        float g0 = bi[c] + bh[c];
        float g1 = bi[256 + c] + bh[256 + c];
        float g2i = bi[512 + c];
        float g2h = bh[512 + c];
#pragma unroll 2
        for (int k2 = 0; k2 < 256; k2 += 8) {
            g0  += dot8u(*reinterpret_cast<const uint4*>(w0 + k2), msgv, k2);
            g1  += dot8u(*reinterpret_cast<const uint4*>(w1 + k2), msgv, k2);
            g2i += dot8u(*reinterpret_cast<const uint4*>(w2 + k2), msgv, k2);
            g0  += dot8u(*reinterpret_cast<const uint4*>(w0 + 256 + k2), hb, k2);
            g1  += dot8u(*reinterpret_cast<const uint4*>(w1 + 256 + k2), hb, k2);
            g2h += dot8u(*reinterpret_cast<const uint4*>(w3 + 256 + k2), hb, k2);
        }
        float r = 1.f / (1.f + expf(-g0));
        float z = 1.f / (1.f + expf(-g1));
        float n = tanhf(g2i + r * g2h);
        float hnew = (1.f - z) * n + z * hp;
        __syncthreads();
        hb[c] = f2b(hnew);
        hp = hnew;
    }
    mem[(size_t)s * 256 + c] = hp;
    mem_bf[(size_t)s * 256 + c] = f2b(hp);
}

// ---------------- attention / head ----------------

__global__ __launch_bounds__(256) void k_dots(const us* __restrict__ hc, const us* __restrict__ efc,
                                              const int* __restrict__ ucnt, const int* __restrict__ necnt,
                                              const float* __restrict__ v_s, const float* __restrict__ v_d,
                                              const float* __restrict__ v_e,
                                              float* __restrict__ sdot, float* __restrict__ ddot,
                                              float* __restrict__ edot)
{
    int lane = threadIdx.x & 63;
    int row = blockIdx.x * 4 + (threadIdx.x >> 6);
    if (row < NN) {
        if (row >= *ucnt) return;
        ushort4 q = reinterpret_cast<const ushort4*>(hc + (size_t)row * 256)[lane];
        int c = lane * 4;
        float x0 = b2f(q.x), x1 = b2f(q.y), x2 = b2f(q.z), x3 = b2f(q.w);
        float s1 = x0 * v_s[c] + x1 * v_s[c + 1] + x2 * v_s[c + 2] + x3 * v_s[c + 3];
        float s2 = x0 * v_d[c] + x1 * v_d[c + 1] + x2 * v_d[c + 2] + x3 * v_d[c + 3];
#pragma unroll
        for (int o = 32; o > 0; o >>= 1) { s1 += __shfl_xor(s1, o); s2 += __shfl_xor(s2, o); }
        if (lane == 0) { sdot[row] = s1; ddot[row] = s2; }
    } else {
        int i = row - NN;
        if (i >= *necnt) return;
        ushort4 q = reinterpret_cast<const ushort4*>(efc + (size_t)i * 256)[lane];
        int c = lane * 4;
        float s1 = b2f(q.x) * v_e[c] + b2f(q.y) * v_e[c + 1] + b2f(q.z) * v_e[c + 2] + b2f(q.w) * v_e[c + 3];
#pragma unroll
        for (int o = 32; o > 0; o >>= 1) s1 += __shfl_xor(s1, o);
        if (lane == 0) edot[i] = s1;
    }
}

__global__ void k_logitc(const int* __restrict__ necnt, const int* __restrict__ eidx,
                         const int* __restrict__ nidx,
                         const float* __restrict__ sdot, const float* __restrict__ ddot,
                         const float* __restrict__ edot, const int* __restrict__ src,
                         const int* __restrict__ dst, float* __restrict__ logit,
                         unsigned* __restrict__ mx)
{
    int i = blockIdx.x * 256 + threadIdx.x;
    if (i >= *necnt) return;
    int e = eidx[i];
    float l = sdot[nidx[src[e]]] + ddot[nidx[dst[e]]] + edot[i];
    l = (l > 0.f) ? l : 0.2f * l;
    logit[i] = l;
    atomicMax(&mx[dst[e]], fkey(l));
}

__global__ void k_alphac(const int* __restrict__ necnt, const int* __restrict__ eidx,
                         const float* __restrict__ logit, const int* __restrict__ dst,
                         const unsigned* __restrict__ mx, float* __restrict__ alpha,
                         float* __restrict__ denom)
{
    int i = blockIdx.x * 256 + threadIdx.x;
    if (i >= *necnt) return;
    int d = dst[eidx[i]];
    float a = expf(logit[i] - funkey(mx[d]));
    alpha[i] = a;
    atomicAdd(&denom[d], a);
}

__global__ void k_scatc(const int* __restrict__ necnt, const int* __restrict__ eidx,
                        const int* __restrict__ nidx,
                        const float* __restrict__ alpha, const int* __restrict__ src,
                        const int* __restrict__ dst, const us* __restrict__ hc,
                        const us* __restrict__ efc, float* __restrict__ outb)
{
    int i = blockIdx.x * 4 + (threadIdx.x >> 6);
    if (i >= *necnt) return;
    int c4 = threadIdx.x & 63;
    int e = eidx[i];
    float a = alpha[i];
    ushort4 hv = reinterpret_cast<const ushort4*>(hc + (size_t)nidx[src[e]] * 256)[c4];
    ushort4 ev = reinterpret_cast<const ushort4*>(efc + (size_t)i * 256)[c4];
    float* op = outb + (size_t)dst[e] * 256 + c4 * 4;
    atomicAdd(op + 0, a * (b2f(hv.x) + b2f(ev.x)));
    atomicAdd(op + 1, a * (b2f(hv.y) + b2f(ev.y)));
    atomicAdd(op + 2, a * (b2f(hv.z) + b2f(ev.z)));
    atomicAdd(op + 3, a * (b2f(hv.w) + b2f(ev.w)));
}

__global__ void k_pe(const int* __restrict__ pm, const float* __restrict__ outb,
                     const float* __restrict__ denom, us* __restrict__ pe)
{
    int p = blockIdx.x, c = threadIdx.x;
    int n = pm[p];
    pe[(size_t)p * 256 + c] = f2b(outb[(size_t)n * 256 + c] / (denom[n] + 1e-16f));
}

__global__ __launch_bounds__(256) void k_final(const float* __restrict__ c1, const float* __restrict__ Wc2,
                                               const float* __restrict__ bc2, float* __restrict__ out)
{
    int lane = threadIdx.x & 63;
    int row = blockIdx.x * 4 + (threadIdx.x >> 6);
    if (row >= PP) return;
    float s = 0.f;
    for (int c = lane; c < 128; c += 64) s += c1[(size_t)row * 128 + c] * Wc2[c];
#pragma unroll
    for (int off = 32; off > 0; off >>= 1) s += __shfl_xor(s, off);
    if (lane == 0) out[row] = 1.f / (1.f + expf(-(s + bc2[0])));
}

// ---------------- host ----------------

extern "C" void kernel_launch(void* const* d_in, const int* in_sizes, int n_in,
                              void* d_out, int out_size, void* d_ws, size_t ws_size,
                              hipStream_t stream)
{
    (void)in_sizes; (void)n_in; (void)out_size;
    const float* nf    = (const float*)d_in[0];
    const int*   ei    = (const int*)  d_in[1];
    const float* ea    = (const float*)d_in[2];
    const float* t     = (const float*)d_in[3];
    const int*   pm    = (const int*)  d_in[4];
    const float* wt    = (const float*)d_in[5];
    const float* bt    = (const float*)d_in[6];
    const float* Wm1   = (const float*)d_in[7];
    const float* bm1   = (const float*)d_in[8];
    const float* Wm2   = (const float*)d_in[9];
    const float* bm2   = (const float*)d_in[10];
    const float* Wi    = (const float*)d_in[11];
    const float* Wh    = (const float*)d_in[12];
    const float* bi    = (const float*)d_in[13];
    const float* bh    = (const float*)d_in[14];
    const float* Wg    = (const float*)d_in[15];
    const float* We    = (const float*)d_in[16];
    const float* a_src = (const float*)d_in[17];
    const float* a_dst = (const float*)d_in[18];
    const float* a_e   = (const float*)d_in[19];
    const float* Wc1   = (const float*)d_in[20];
    const float* bc1   = (const float*)d_in[21];
    const float* Wc2   = (const float*)d_in[22];
    const float* bc2   = (const float*)d_in[23];
    float* outp = (float*)d_out;
    const int* src = ei;
    const int* dst = ei + EE;

    char* base = (char*)d_ws;
    size_t off = 0;
    auto alloc = [&](size_t bytes) -> void* {
        void* p = base + off;
        off = (off + bytes + 255) & ~(size_t)255;
        return p;
    };
    int* rank      = (int*)alloc((size_t)EE * 4);
    int* roundcnt  = (int*)alloc(64 * 4);          // [0..11] rounds, [32]=tm, [33]=necnt, [34]=ucnt, [35]=xcnt
    int* roundx    = (int*)alloc((size_t)MAXR * EE * 4);
    int* roundsrc  = (int*)alloc((size_t)MAXR * EE * 4);
    int* bsum      = (int*)alloc(256 * 4);
    int* eidx      = (int*)alloc((size_t)EE * 4);
    int* xlist     = (int*)alloc((size_t)EE * 4);
    int* xsrc      = (int*)alloc((size_t)EE * 4);
    int* tx        = (int*)alloc((size_t)8 * (EE / 5 + 256) * 4);
    int* ulist     = (int*)alloc((size_t)NN * 4);
    int* nidx      = (int*)alloc((size_t)NN * 4);
    us* te_bf    = (us*)alloc((size_t)EE * 128 * 2);
    us* nf_bf    = (us*)alloc((size_t)NN * 256 * 2);
    us* ea_bf    = (us*)alloc((size_t)EE * 128 * 2);
    us* xh       = (us*)alloc((size_t)NN * 256 * 2);   // slist -> xpart_c -> hc
    float* memb  = (float*)alloc((size_t)NN * 256 * 4);
    us* memb_bf  = (us*)alloc((size_t)NN * 256 * 2);
    us* Wt_x    = (us*)alloc((size_t)256 * 512 * 2);
    us* Wt_a    = (us*)alloc((size_t)256 * 256 * 2);
    us* Wt_m2   = (us*)alloc((size_t)256 * 256 * 2);
    us* Wt_gate = (us*)alloc((size_t)1024 * 512 * 2);
    us* Wt_g    = (us*)alloc((size_t)256 * 512 * 2);
    us* Wt_e    = (us*)alloc((size_t)256 * 256 * 2);
    us* Wt_c    = (us*)alloc((size_t)128 * 256 * 2);
    float* gvec  = (float*)alloc(256 * 4);
    float* sdot  = (float*)alloc((size_t)NN * 4);
    float* ddot  = (float*)alloc((size_t)NN * 4);
    float* edot  = (float*)alloc((size_t)EE * 4);
    float* logit = (float*)alloc((size_t)EE * 4);
    float* alpha = (float*)alloc((size_t)EE * 4);
    unsigned* mx = (unsigned*)alloc((size_t)NN * 4);
    float* denom = (float*)alloc((size_t)NN * 4);
    // zeroed mask zone (one memset): needed | uneed | scnt
    int* needed  = (int*)alloc((size_t)NN * 4);
    int* uneed   = (int*)alloc((size_t)NN * 4);
    int* scnt    = (int*)alloc((size_t)NN * 4);
    char* zone_end = base + off;

    size_t region = (ws_size > off + 4096) ? (ws_size - off - 4096) : 0;
    long capL = (long)(region / 3584);
    int CAPR = (int)(capL < 0 ? 0 : capL);
    CAPR = (CAPR / 128) * 128;
    if (CAPR > 28160) CAPR = 28160;
    if (CAPR < 1280) return;   // ws too small (visible failure)
    us* xbuf_bf  = (us*)alloc((size_t)CAPR * 256 * 2);
    us* msg_bf   = (us*)alloc((size_t)CAPR * 256 * 2);
    us* hprev_c  = (us*)alloc((size_t)CAPR * 256 * 2);
    us* gates_bf = (us*)alloc((size_t)CAPR * 1024 * 2);
    if (off > ws_size) return;

    unsigned* tm = (unsigned*)&roundcnt[32];
    int* necnt   = &roundcnt[33];
    int* ucnt    = &roundcnt[34];
    int* xcnt    = &roundcnt[35];
    // bucket-sort scratch aliases roundx (dead until k_chain)
    int* hist  = roundx;
    int* hcur  = roundx + NB;
    int* hbase = roundx + 2 * NB;
    int* blist = roundx + 3 * NB;
    // aliases in xh: slist (until k_chain) -> xpart_c (until tails) -> hc (after)
    int* slist = (int*)xh;
    us* xpart_c = xh;
    us* hc = xh;
    us* ef_c = nf_bf;                  // nf_bf dead after h-GEMM
    float* outb = memb;                // f32 mem dead post-scan
    us* pe_bf = te_bf;                 // te dead after ef GEMM
    float* c1 = (float*)(te_bf + (size_t)PP * 256);

    const dim3 B(256);
    const int gE = (EE + 255) / 256;
    const int gN = (NN + 255) / 256;

    hipMemsetAsync(roundcnt, 0, 64 * 4, stream);
    hipMemsetAsync(hist, 0, (size_t)2 * NB * 4, stream);                  // hist + hcur
    hipMemsetAsync(needed, 0, (size_t)(zone_end - (char*)needed), stream);
    hipMemsetAsync(Wt_gate, 0, (size_t)1024 * 512 * 2, stream);           // zero-pad for g2i/g2h halves

    k_need<<<(PP + 255) / 256, B, 0, stream>>>(pm, needed);
    k_elist<<<gE, B, 0, stream>>>(src, dst, needed, necnt, eidx, uneed);
    k_ulist<<<gN, B, 0, stream>>>(uneed, ucnt, ulist, nidx);

    k_prep<<<gE, B, 0, stream>>>(t, src, hist, scnt, slist, tm);
    k_scan1<<<256, B, 0, stream>>>(hist, hbase, bsum);
    k_scan2<<<1, B, 0, stream>>>(bsum);
    k_scan3<<<256, B, 0, stream>>>(hbase, bsum);
    k_bscatter<<<gE, B, 0, stream>>>(t, hbase, hcur, blist);
    k_rank2<<<gE, B, 0, stream>>>(t, hbase, hist, blist, rank);
    k_chain<<<gE, B, 0, stream>>>(src, rank, scnt, slist, uneed, roundcnt, roundx, roundsrc,
                                  xcnt, xlist, xsrc);

    k_zmem<<<1024, B, 0, stream>>>(ucnt, ulist, memb, memb_bf);
    k_cvtg<<<1024, B, 0, stream>>>(ucnt, ulist, nf, nf_bf);
    k_convL<<<1024, B, 0, stream>>>(xcnt, xlist, t, wt, bt, te_bf, ea, ea_bf);
    k_convL<<<1024, B, 0, stream>>>(necnt, eidx, t, wt, bt, te_bf, ea, ea_bf);

    // tiled weight transposes + gvec; Wt_gate = [Wi;Wh | g2i(Wi,0) | g2h(0,Wh)] (1024 x 512)
    {
        WtA wa;
        int o = 0;
        auto set = [&](int i, const float* W, us* dstp, int K, int N, int ld, int koff, int Ktot) {
            wa.d[i] = WtD{W, dstp, K, N, ld, koff, Ktot, o};
            o += (K >> 5) * (N >> 5);
        };
        set(0, Wm1, Wt_x, 256, 256, 256, 0, 512);
        set(1, Wm1 + (size_t)512 * 256, Wt_x, 128, 256, 256, 256, 512);
        set(2, Wm1 + (size_t)640 * 256, Wt_x, 128, 256, 256, 384, 512);
        set(3, Wm1 + (size_t)256 * 256, Wt_a, 256, 256, 256, 0, 256);
        set(4, Wm2, Wt_m2, 256, 256, 256, 0, 256);
        set(5, Wi, Wt_gate, 256, 512, 768, 0, 512);
        set(6, Wh, Wt_gate, 256, 512, 768, 256, 512);
        set(7, Wi + 512, Wt_gate + (size_t)512 * 512, 256, 256, 768, 0, 512);
        set(8, Wh + 512, Wt_gate + (size_t)768 * 512, 256, 256, 768, 256, 512);
        set(9, Wg, Wt_g, 512, 256, 256, 0, 512);
        set(10, We, Wt_e, 256, 256, 256, 0, 256);
        set(11, Wc1, Wt_c, 256, 128, 128, 0, 256);
        wa.ntiles = o;
        k_wt2<<<o + 1, B, 0, stream>>>(wa, tm, wt, bt, Wg, gvec);
    }

    // xpart (compact) = bm1 + nf[xsrc]@Wm1[0:256] + ea[xlist]@.. + te[xlist]@..
    const int gxE = (EE + 127) / 128;
    k_mgemm<<<dim3(gxE, 4), B, 0, stream>>>(nf_bf, 256, xsrc, ea_bf, 128, xlist,
        te_bf, 128, xlist, Wt_x, 512, 512, bm1, nullptr, nullptr,
        nullptr, xpart_c, 256, EE, xcnt, 0, 0, 0);

    // chain rounds 0..3: msg GEMM + fused gate GEMM + elementwise gate
    for (int j = 0; j < 4; ++j) {
        int bound = EE / (j + 1);
        for (int cb = 0; cb < bound; cb += CAPR) {
            int m = bound - cb; if (m > CAPR) m = CAPR;
            int gx = (m + 127) / 128;
            const int* rx = roundx + (size_t)j * EE + cb;
            const int* rs = roundsrc + (size_t)j * EE + cb;
            if (j == 0) {
                k_mgemm<<<dim3(gx, 4), B, 0, stream>>>(xpart_c, 256, rx, nullptr, 0, nullptr,
                    nullptr, 0, nullptr, Wt_m2, 256, 256, bm2, nullptr, nullptr,
                    nullptr, msg_bf, 256, m, roundcnt + j, cb, 1, 1);
                k_mgemm<<<dim3(gx, 16), B, 0, stream>>>(msg_bf, 256, nullptr, nullptr, 0, nullptr,
                    nullptr, 0, nullptr, Wt_gate, 256, 512, nullptr, nullptr, nullptr,
                    nullptr, gates_bf, 1024, m, roundcnt + j, cb, 0, 0);
            } else {
                k_hgather<<<(m * 64 + 255) / 256, B, 0, stream>>>(roundcnt + j, cb, m, rs, memb_bf, hprev_c);
                k_mgemm<<<dim3(gx, 4), B, 0, stream>>>(hprev_c, 256, nullptr, nullptr, 0, nullptr,
                    nullptr, 0, nullptr, Wt_a, 256, 256, nullptr, xpart_c, rx,
                    nullptr, xbuf_bf, 256, m, roundcnt + j, cb, 1, 0);
                k_mgemm<<<dim3(gx, 4), B, 0, stream>>>(xbuf_bf, 256, nullptr, nullptr, 0, nullptr,
                    nullptr, 0, nullptr, Wt_m2, 256, 256, bm2, nullptr, nullptr,
                    nullptr, msg_bf, 256, m, roundcnt + j, cb, 1, 0);
                k_mgemm<<<dim3(gx, 16), B, 0, stream>>>(msg_bf, 256, nullptr, hprev_c, 256, nullptr,
                    nullptr, 0, nullptr, Wt_gate, 512, 512, nullptr, nullptr, nullptr,
                    nullptr, gates_bf, 1024, m, roundcnt + j, cb, 0, 0);
            }
            k_gate<<<m, B, 0, stream>>>(roundcnt + j, cb, m, rs, gates_bf, bi, bh, memb, memb_bf);
        }
    }
    // tail rounds 4..11: one chain-walking launch (blocks = independent sources)
    k_tbuild<<<(EE / 5 + 255) / 256, B, 0, stream>>>(roundcnt, roundx, roundsrc, tx);
    k_tailchain<<<EE / 5, B, 0, stream>>>(roundcnt, roundsrc, tx, xpart_c, Wt_a, Wt_m2,
                                          Wt_gate, bm2, bi, bh, memb, memb_bf);

    k_zout<<<(PP * 64 + 255) / 256, B, 0, stream>>>(pm, outb, denom, mx);

    // h (compact U rows) = [nf | mem]@Wg + gvec bias
    const int gxN = (NN + 127) / 128;
    k_mgemm<<<dim3(gxN, 4), B, 0, stream>>>(nf_bf, 256, ulist, memb_bf, 256, ulist,
        nullptr, 0, nullptr, Wt_g, 512, 512, gvec, nullptr, nullptr,
        nullptr, hc, 256, NN, ucnt, 0, 0, 0);

    // ef (compact needed edges) = [ea | te](eidx) @ We
    k_mgemm<<<dim3(gxE, 4), B, 0, stream>>>(ea_bf, 128, eidx, te_bf, 128, eidx,
        nullptr, 0, nullptr, Wt_e, 256, 256, nullptr, nullptr, nullptr,
        nullptr, ef_c, 256, EE, necnt, 0, 0, 0);

    k_dots<<<(NN + EE + 3) / 4, B, 0, stream>>>(hc, ef_c, ucnt, necnt, a_src, a_dst, a_e, sdot, ddot, edot);

    k_logitc<<<gE, B, 0, stream>>>(necnt, eidx, nidx, sdot, ddot, edot, src, dst, logit, mx);
    k_alphac<<<gE, B, 0, stream>>>(necnt, eidx, logit, dst, mx, alpha, denom);
    k_scatc<<<(EE + 3) / 4, B, 0, stream>>>(necnt, eidx, nidx, alpha, src, dst, hc, ef_c, outb);

    k_pe<<<PP, B, 0, stream>>>(pm, outb, denom, pe_bf);
    k_mgemm<<<dim3((PP + 127) / 128, 2), B, 0, stream>>>(pe_bf, 256, nullptr, nullptr, 0, nullptr,
        nullptr, 0, nullptr, Wt_c, 256, 256, bc1, nullptr, nullptr,
        c1, nullptr, 128, PP, nullptr, 0, 1, 0);
    k_final<<<(PP + 3) / 4, B, 0, stream>>>(c1, Wc2, bc2, outp);
}